// Round 1
// baseline (2579.211 us; speedup 1.0000x reference)
//
#include <hip/hip_runtime.h>
#include <hip/hip_bf16.h>
#include <math.h>

// Problem constants
#define B_  2
#define T_  1024
#define D_  1024
#define H_  16
#define DK_ 64
#define DV_ 128
#define FH_ 2816
#define M_  (B_ * T_)   // 2048 tokens

// ---------------------------------------------------------------------------
// rmsnorm: out[row] = x[row] * rsqrt(mean(x^2) + eps) * w
// grid = M rows, block = 256
__global__ __launch_bounds__(256) void rmsnorm_k(
    const float* __restrict__ x, const float* __restrict__ w,
    float* __restrict__ out, int D, float eps) {
  const int row = blockIdx.x;
  const float* xr = x + (size_t)row * D;
  float ss = 0.f;
  for (int i = threadIdx.x; i < D; i += blockDim.x) { float v = xr[i]; ss += v * v; }
  for (int off = 32; off > 0; off >>= 1) ss += __shfl_xor(ss, off, 64);
  __shared__ float wsum[4];
  __shared__ float s_scale;
  const int lane = threadIdx.x & 63, wid = threadIdx.x >> 6;
  if (lane == 0) wsum[wid] = ss;
  __syncthreads();
  if (threadIdx.x == 0) {
    float tot = 0.f;
    const int nw = blockDim.x >> 6;
    for (int i = 0; i < nw; ++i) tot += wsum[i];
    s_scale = rsqrtf(tot / (float)D + eps);
  }
  __syncthreads();
  const float sc = s_scale;
  for (int i = threadIdx.x; i < D; i += blockDim.x)
    out[(size_t)row * D + i] = xr[i] * sc * w[i];
}

// ---------------------------------------------------------------------------
// fp32 SIMT GEMM: C[M,N] = A[M,K] @ Bw[K,N] (+ res). 64x64 tile, BK=16,
// 256 threads, 4x4 per thread. M%64==0, N%64==0, K%16==0 (all shapes here).
#define BM 64
#define BN 64
#define BK 16
__global__ __launch_bounds__(256) void gemm_k(
    const float* __restrict__ A, const float* __restrict__ Bw,
    const float* __restrict__ res, float* __restrict__ C,
    int M, int N, int K) {
  __shared__ float As[BK][68];   // padded: rows 272B (16B-aligned), 2-way banks only
  __shared__ float Bs[BK][BN];
  const int tid = threadIdx.x;
  const int bx = blockIdx.x, by = blockIdx.y;
  const int tx = tid & 15, ty = tid >> 4;
  const int arow = tid >> 2;          // 0..63
  const int akc  = (tid & 3) * 4;     // 0,4,8,12
  const int bcol = (tid & 15) * 4;    // 0..60
  const int brow = tid >> 4;          // 0..15
  const float* Ab = A + (size_t)(by * BM + arow) * K + akc;
  const float* Bb = Bw + (size_t)brow * N + (size_t)bx * BN + bcol;
  float acc[4][4] = {};
  for (int k0 = 0; k0 < K; k0 += BK) {
    const float4 av = *(const float4*)(Ab + k0);
    const float4 bv = *(const float4*)(Bb + (size_t)k0 * N);
    As[akc + 0][arow] = av.x; As[akc + 1][arow] = av.y;
    As[akc + 2][arow] = av.z; As[akc + 3][arow] = av.w;
    *(float4*)&Bs[brow][bcol] = bv;
    __syncthreads();
#pragma unroll
    for (int kk = 0; kk < BK; ++kk) {
      const float4 a = *(const float4*)&As[kk][ty * 4];
      const float4 b = *(const float4*)&Bs[kk][tx * 4];
      const float ar[4] = {a.x, a.y, a.z, a.w};
      const float br[4] = {b.x, b.y, b.z, b.w};
#pragma unroll
      for (int i = 0; i < 4; ++i)
#pragma unroll
        for (int j = 0; j < 4; ++j) acc[i][j] += ar[i] * br[j];
    }
    __syncthreads();
  }
  const int crow = by * BM + ty * 4, ccol = bx * BN + tx * 4;
#pragma unroll
  for (int i = 0; i < 4; ++i) {
    const size_t off = (size_t)(crow + i) * N + ccol;
    float4 r = make_float4(acc[i][0], acc[i][1], acc[i][2], acc[i][3]);
    if (res) {
      const float4 rv = *(const float4*)(res + off);
      r.x += rv.x; r.y += rv.y; r.z += rv.z; r.w += rv.w;
    }
    *(float4*)(C + off) = r;
  }
}

// ---------------------------------------------------------------------------
// Skinny GEMM for Wa/Wb (N=16 each): one block per row; row staged in LDS.
__global__ __launch_bounds__(256) void skinny_k(
    const float* __restrict__ h, const float* __restrict__ Wa,
    const float* __restrict__ Wb, float* __restrict__ pa,
    float* __restrict__ pb, int K) {
  __shared__ float hl[D_];
  const int row = blockIdx.x;
  for (int i = threadIdx.x; i < K; i += blockDim.x) hl[i] = h[(size_t)row * K + i];
  __syncthreads();
  const int t = threadIdx.x;
  if (t < 32) {
    const float* W = (t < 16) ? Wa : Wb;
    const int col = t & 15;
    float s = 0.f;
    for (int k = 0; k < K; ++k) s += hl[k] * W[k * H_ + col];
    if (t < 16) pa[(size_t)row * H_ + col] = s;
    else        pb[(size_t)row * H_ + col] = s;
  }
}

// ---------------------------------------------------------------------------
// Causal depthwise conv1d (K=4, zero left-pad per batch) + SiLU.
// y[b,t,c] = silu(sum_j x[b,t-3+j,c] * w[c,j]);  grid = B*T, block = 256.
__global__ __launch_bounds__(256) void conv_silu_k(
    const float* __restrict__ src, const float* __restrict__ w,
    float* __restrict__ dst, int C) {
  const int bt = blockIdx.x;
  const int b = bt / T_, t = bt % T_;
  const float* s = src + (size_t)b * T_ * C;
  for (int c = threadIdx.x; c < C; c += blockDim.x) {
    const float w0 = w[c * 4 + 0], w1 = w[c * 4 + 1],
                w2 = w[c * 4 + 2], w3 = w[c * 4 + 3];
    float acc = s[(size_t)t * C + c] * w3;
    if (t >= 1) acc += s[(size_t)(t - 1) * C + c] * w2;
    if (t >= 2) acc += s[(size_t)(t - 2) * C + c] * w1;
    if (t >= 3) acc += s[(size_t)(t - 3) * C + c] * w0;
    dst[(size_t)bt * C + c] = acc * (1.f / (1.f + __expf(-acc)));
  }
}

// ---------------------------------------------------------------------------
// beta = sigmoid(pb); g = -exp(A_log[h]) * softplus(pa + dt_bias[h])
__global__ void beta_g_k(const float* __restrict__ pa, const float* __restrict__ pb,
                         const float* __restrict__ dtb, const float* __restrict__ Alog,
                         float* __restrict__ g, float* __restrict__ beta, int n) {
  const int i = blockIdx.x * blockDim.x + threadIdx.x;
  if (i >= n) return;
  const int h = i & (H_ - 1);
  const float xx = pa[i] + dtb[h];
  const float sp = (xx > 20.f) ? xx : log1pf(expf(xx));
  g[i] = -expf(Alog[h]) * sp;
  beta[i] = 1.f / (1.f + expf(-pb[i]));
}

// ---------------------------------------------------------------------------
// l2norm over rows of 64 (one wave per row), in place, with optional scale.
__global__ __launch_bounds__(64) void l2norm_k(float* __restrict__ q, float scale) {
  const size_t row = blockIdx.x;
  const int lane = threadIdx.x;
  const float v = q[row * 64 + lane];
  float ss = v * v;
  for (int off = 32; off > 0; off >>= 1) ss += __shfl_xor(ss, off, 64);
  q[row * 64 + lane] = v * rsqrtf(ss + 1e-6f) * scale;
}

// ---------------------------------------------------------------------------
// Gated delta rule scan. One WG per (b,h); 128 threads; thread v owns S[:,v]
// (64 regs). Per step: err = eg*(k.S); vn = (v-err)*beta; S = eg*S + k vn^T;
// o = q.S.
__global__ __launch_bounds__(128) void scan_k(
    const float* __restrict__ q, const float* __restrict__ k,
    const float* __restrict__ v, const float* __restrict__ g,
    const float* __restrict__ beta, float* __restrict__ o) {
  const int bh = blockIdx.x;
  const int b = bh >> 4, hh = bh & 15;
  const int vv = threadIdx.x;
  float S[64];
#pragma unroll
  for (int i = 0; i < 64; ++i) S[i] = 0.f;
  __shared__ __align__(16) float lk[64];
  __shared__ __align__(16) float lq[64];
  const size_t qk0 = ((size_t)b * T_ * H_ + hh) * DK_;
  const size_t v0  = ((size_t)b * T_ * H_ + hh) * DV_;
  const size_t gb0 = (size_t)b * T_ * H_ + hh;
  for (int t = 0; t < T_; ++t) {
    const size_t qoff = qk0 + (size_t)t * H_ * DK_;
    const size_t voff = v0 + (size_t)t * H_ * DV_;
    if (vv < 64) lk[vv] = k[qoff + vv];
    else         lq[vv - 64] = q[qoff + vv - 64];
    const float vt = v[voff + vv];
    const float gt = g[gb0 + (size_t)t * H_];
    const float bt = beta[gb0 + (size_t)t * H_];
    __syncthreads();
    const float eg = __expf(gt);
    const float4* k4 = (const float4*)lk;
    const float4* q4 = (const float4*)lq;
    float e0 = 0.f, e1 = 0.f, e2 = 0.f, e3 = 0.f;
#pragma unroll
    for (int i = 0; i < 16; ++i) {
      const float4 kk = k4[i];
      e0 += kk.x * S[4 * i + 0];
      e1 += kk.y * S[4 * i + 1];
      e2 += kk.z * S[4 * i + 2];
      e3 += kk.w * S[4 * i + 3];
    }
    const float vn = (vt - eg * ((e0 + e1) + (e2 + e3))) * bt;
    float o0 = 0.f, o1 = 0.f, o2 = 0.f, o3 = 0.f;
#pragma unroll
    for (int i = 0; i < 16; ++i) {
      const float4 kk = k4[i];
      const float4 qq = q4[i];
      float s0 = eg * S[4 * i + 0] + kk.x * vn; S[4 * i + 0] = s0; o0 += qq.x * s0;
      float s1 = eg * S[4 * i + 1] + kk.y * vn; S[4 * i + 1] = s1; o1 += qq.y * s1;
      float s2 = eg * S[4 * i + 2] + kk.z * vn; S[4 * i + 2] = s2; o2 += qq.z * s2;
      float s3 = eg * S[4 * i + 3] + kk.w * vn; S[4 * i + 3] = s3; o3 += qq.w * s3;
    }
    o[voff + vv] = (o0 + o1) + (o2 + o3);
    __syncthreads();
  }
}

// ---------------------------------------------------------------------------
// go = rmsnorm(o, onw, 1e-5) * silu(gate); rows of DV=128 per (b,t,h).
__global__ __launch_bounds__(128) void gatenorm_k(
    const float* __restrict__ o, const float* __restrict__ onw,
    const float* __restrict__ gate, float* __restrict__ go) {
  const size_t row = blockIdx.x;
  const int i = threadIdx.x;
  const float x = o[row * DV_ + i];
  float ss = x * x;
  for (int off = 32; off > 0; off >>= 1) ss += __shfl_xor(ss, off, 64);
  __shared__ float w2[2];
  if ((i & 63) == 0) w2[i >> 6] = ss;
  __syncthreads();
  const float r = rsqrtf((w2[0] + w2[1]) / (float)DV_ + 1e-5f);
  const float gg = gate[row * DV_ + i];
  go[row * DV_ + i] = x * r * onw[i] * gg * (1.f / (1.f + __expf(-gg)));
}

// ---------------------------------------------------------------------------
// out = silu(a1) * a3 (elementwise, float4); out may alias a1.
__global__ void silumul_k(const float4* a1, const float4* a3, float4* outp, int n4) {
  const int i = blockIdx.x * blockDim.x + threadIdx.x;
  if (i >= n4) return;
  const float4 a = a1[i], c = a3[i];
  float4 r;
  r.x = a.x * (1.f / (1.f + __expf(-a.x))) * c.x;
  r.y = a.y * (1.f / (1.f + __expf(-a.y))) * c.y;
  r.z = a.z * (1.f / (1.f + __expf(-a.z))) * c.z;
  r.w = a.w * (1.f / (1.f + __expf(-a.w))) * c.w;
  outp[i] = r;
}

// ---------------------------------------------------------------------------
extern "C" void kernel_launch(void* const* d_in, const int* in_sizes, int n_in,
                              void* d_out, int out_size, void* d_ws, size_t ws_size,
                              hipStream_t stream) {
  const float* x    = (const float*)d_in[0];
  const float* n1w  = (const float*)d_in[1];
  const float* n2w  = (const float*)d_in[2];
  const float* Wq   = (const float*)d_in[3];
  const float* Wk   = (const float*)d_in[4];
  const float* Wv   = (const float*)d_in[5];
  const float* cq   = (const float*)d_in[6];
  const float* ck   = (const float*)d_in[7];
  const float* cv   = (const float*)d_in[8];
  const float* Wa   = (const float*)d_in[9];
  const float* Wb   = (const float*)d_in[10];
  const float* dtb  = (const float*)d_in[11];
  const float* Alog = (const float*)d_in[12];
  const float* Wg   = (const float*)d_in[13];
  const float* onw  = (const float*)d_in[14];
  const float* Wo   = (const float*)d_in[15];
  const float* W1   = (const float*)d_in[16];
  const float* W3   = (const float*)d_in[17];
  const float* W2   = (const float*)d_in[18];
  float* out = (float*)d_out;
  float* ws  = (float*)d_ws;

  const size_t SZ_MD = (size_t)M_ * D_;          // 2M floats
  const size_t SZ_MV = (size_t)M_ * H_ * DV_;    // 4M floats
  // Workspace layout (floats); total 22M + 128K floats ≈ 88.6 MB.
  float* h    = ws;                               // [0,2M)
  float* pq   = ws + SZ_MD;                       // [2M,4M)
  float* pk   = ws + 2 * SZ_MD;                   // [4M,6M)
  float* pv   = ws + 3 * SZ_MD;                   // [6M,10M)
  float* gate = ws + 3 * SZ_MD + SZ_MV;           // [10M,14M)
  float* qb   = ws + 3 * SZ_MD + 2 * SZ_MV;       // [14M,16M)
  float* kb   = ws + 4 * SZ_MD + 2 * SZ_MV;       // [16M,18M)
  float* vb   = ws + 5 * SZ_MD + 2 * SZ_MV;       // [18M,22M)
  float* ob   = pv;    // o reuses pv (free after conv v)
  float* go   = vb;    // gated out reuses v (free after scan)
  float* y1   = pq;    // reuses pq (free after conv q)
  float* h2   = pk;    // reuses pk (free after conv k)
  float* a1   = pv;    // [6M,11.77M): pv+gate free by then
  float* a3   = qb;    // [14M,19.77M): q,k,go free by then
  float* smalls = ws + 5 * SZ_MD + 3 * SZ_MV;     // 22M
  float* pa = smalls;
  float* pb = pa + (size_t)M_ * H_;
  float* gv = pb + (size_t)M_ * H_;
  float* bv = gv + (size_t)M_ * H_;

  const dim3 blk256(256);

  // 1) h = rmsnorm(x, norm1_w)
  rmsnorm_k<<<dim3(M_), blk256, 0, stream>>>(x, n1w, h, D_, 1e-6f);
  // 2) projections from h
  gemm_k<<<dim3(D_ / BN, M_ / BM), blk256, 0, stream>>>(h, Wq, (const float*)nullptr, pq, M_, D_, D_);
  gemm_k<<<dim3(D_ / BN, M_ / BM), blk256, 0, stream>>>(h, Wk, (const float*)nullptr, pk, M_, D_, D_);
  gemm_k<<<dim3((H_ * DV_) / BN, M_ / BM), blk256, 0, stream>>>(h, Wv, (const float*)nullptr, pv, M_, H_ * DV_, D_);
  gemm_k<<<dim3((H_ * DV_) / BN, M_ / BM), blk256, 0, stream>>>(h, Wg, (const float*)nullptr, gate, M_, H_ * DV_, D_);
  skinny_k<<<dim3(M_), blk256, 0, stream>>>(h, Wa, Wb, pa, pb, D_);
  // 3) short conv + silu
  conv_silu_k<<<dim3(M_), blk256, 0, stream>>>(pq, cq, qb, H_ * DK_);
  conv_silu_k<<<dim3(M_), blk256, 0, stream>>>(pk, ck, kb, H_ * DK_);
  conv_silu_k<<<dim3(M_), blk256, 0, stream>>>(pv, cv, vb, H_ * DV_);
  // 4) beta, g
  beta_g_k<<<dim3((M_ * H_ + 255) / 256), blk256, 0, stream>>>(pa, pb, dtb, Alog, gv, bv, M_ * H_);
  // 5) l2norm q (with 1/sqrt(DK) scale) and k
  l2norm_k<<<dim3(M_ * H_), dim3(64), 0, stream>>>(qb, 0.125f);
  l2norm_k<<<dim3(M_ * H_), dim3(64), 0, stream>>>(kb, 1.0f);
  // 6) gated delta rule scan
  scan_k<<<dim3(B_ * H_), dim3(128), 0, stream>>>(qb, kb, vb, gv, bv, ob);
  // 7) gated RMSNorm
  gatenorm_k<<<dim3(M_ * H_), dim3(128), 0, stream>>>(ob, onw, gate, go);
  // 8) y1 = x + go @ Wo
  gemm_k<<<dim3(D_ / BN, M_ / BM), blk256, 0, stream>>>(go, Wo, x, y1, M_, D_, H_ * DV_);
  // 9) h2 = rmsnorm(y1, norm2_w)
  rmsnorm_k<<<dim3(M_), blk256, 0, stream>>>(y1, n2w, h2, D_, 1e-6f);
  // 10) FFN
  gemm_k<<<dim3(FH_ / BN, M_ / BM), blk256, 0, stream>>>(h2, W1, (const float*)nullptr, a1, M_, FH_, D_);
  gemm_k<<<dim3(FH_ / BN, M_ / BM), blk256, 0, stream>>>(h2, W3, (const float*)nullptr, a3, M_, FH_, D_);
  const int n4 = (M_ * FH_) / 4;
  silumul_k<<<dim3((n4 + 255) / 256), blk256, 0, stream>>>((const float4*)a1, (const float4*)a3, (float4*)a1, n4);
  // 11) out = y1 + (silu(a1)*a3) @ W2
  gemm_k<<<dim3(D_ / BN, M_ / BM), blk256, 0, stream>>>(a1, W2, y1, out, M_, D_, FH_);
}

// Round 2
// 2285.172 us; speedup vs baseline: 1.1287x; 1.1287x over previous
//
#include <hip/hip_runtime.h>
#include <hip/hip_bf16.h>
#include <math.h>

// Problem constants
#define B_  2
#define T_  1024
#define D_  1024
#define H_  16
#define DK_ 64
#define DV_ 128
#define FH_ 2816
#define M_  (B_ * T_)   // 2048 tokens

// ---------------------------------------------------------------------------
// rmsnorm: out[row] = x[row] * rsqrt(mean(x^2) + eps) * w
// grid = M rows, block = 256
__global__ __launch_bounds__(256) void rmsnorm_k(
    const float* __restrict__ x, const float* __restrict__ w,
    float* __restrict__ out, int D, float eps) {
  const int row = blockIdx.x;
  const float* xr = x + (size_t)row * D;
  float ss = 0.f;
  for (int i = threadIdx.x; i < D; i += blockDim.x) { float v = xr[i]; ss += v * v; }
  for (int off = 32; off > 0; off >>= 1) ss += __shfl_xor(ss, off, 64);
  __shared__ float wsum[4];
  __shared__ float s_scale;
  const int lane = threadIdx.x & 63, wid = threadIdx.x >> 6;
  if (lane == 0) wsum[wid] = ss;
  __syncthreads();
  if (threadIdx.x == 0) {
    float tot = 0.f;
    const int nw = blockDim.x >> 6;
    for (int i = 0; i < nw; ++i) tot += wsum[i];
    s_scale = rsqrtf(tot / (float)D + eps);
  }
  __syncthreads();
  const float sc = s_scale;
  for (int i = threadIdx.x; i < D; i += blockDim.x)
    out[(size_t)row * D + i] = xr[i] * sc * w[i];
}

// ---------------------------------------------------------------------------
// fp32 SIMT GEMM: C[M,N] = A[M,K] @ Bw[K,N] (+ res). 64x64 tile, BK=16,
// 256 threads, 4x4 per thread. M%64==0, N%64==0, K%16==0 (all shapes here).
#define BM 64
#define BN 64
#define BK 16
__global__ __launch_bounds__(256) void gemm_k(
    const float* __restrict__ A, const float* __restrict__ Bw,
    const float* __restrict__ res, float* __restrict__ C,
    int M, int N, int K) {
  __shared__ float As[BK][68];   // padded: rows 272B (16B-aligned), 2-way banks only
  __shared__ float Bs[BK][BN];
  const int tid = threadIdx.x;
  const int bx = blockIdx.x, by = blockIdx.y;
  const int tx = tid & 15, ty = tid >> 4;
  const int arow = tid >> 2;          // 0..63
  const int akc  = (tid & 3) * 4;     // 0,4,8,12
  const int bcol = (tid & 15) * 4;    // 0..60
  const int brow = tid >> 4;          // 0..15
  const float* Ab = A + (size_t)(by * BM + arow) * K + akc;
  const float* Bb = Bw + (size_t)brow * N + (size_t)bx * BN + bcol;
  float acc[4][4] = {};
  for (int k0 = 0; k0 < K; k0 += BK) {
    const float4 av = *(const float4*)(Ab + k0);
    const float4 bv = *(const float4*)(Bb + (size_t)k0 * N);
    As[akc + 0][arow] = av.x; As[akc + 1][arow] = av.y;
    As[akc + 2][arow] = av.z; As[akc + 3][arow] = av.w;
    *(float4*)&Bs[brow][bcol] = bv;
    __syncthreads();
#pragma unroll
    for (int kk = 0; kk < BK; ++kk) {
      const float4 a = *(const float4*)&As[kk][ty * 4];
      const float4 b = *(const float4*)&Bs[kk][tx * 4];
      const float ar[4] = {a.x, a.y, a.z, a.w};
      const float br[4] = {b.x, b.y, b.z, b.w};
#pragma unroll
      for (int i = 0; i < 4; ++i)
#pragma unroll
        for (int j = 0; j < 4; ++j) acc[i][j] += ar[i] * br[j];
    }
    __syncthreads();
  }
  const int crow = by * BM + ty * 4, ccol = bx * BN + tx * 4;
#pragma unroll
  for (int i = 0; i < 4; ++i) {
    const size_t off = (size_t)(crow + i) * N + ccol;
    float4 r = make_float4(acc[i][0], acc[i][1], acc[i][2], acc[i][3]);
    if (res) {
      const float4 rv = *(const float4*)(res + off);
      r.x += rv.x; r.y += rv.y; r.z += rv.z; r.w += rv.w;
    }
    *(float4*)(C + off) = r;
  }
}

// ---------------------------------------------------------------------------
// Skinny GEMM for Wa/Wb (N=16 each): one block per row; row staged in LDS.
__global__ __launch_bounds__(256) void skinny_k(
    const float* __restrict__ h, const float* __restrict__ Wa,
    const float* __restrict__ Wb, float* __restrict__ pa,
    float* __restrict__ pb, int K) {
  __shared__ float hl[D_];
  const int row = blockIdx.x;
  for (int i = threadIdx.x; i < K; i += blockDim.x) hl[i] = h[(size_t)row * K + i];
  __syncthreads();
  const int t = threadIdx.x;
  if (t < 32) {
    const float* W = (t < 16) ? Wa : Wb;
    const int col = t & 15;
    float s = 0.f;
    for (int k = 0; k < K; ++k) s += hl[k] * W[k * H_ + col];
    if (t < 16) pa[(size_t)row * H_ + col] = s;
    else        pb[(size_t)row * H_ + col] = s;
  }
}

// ---------------------------------------------------------------------------
// Causal depthwise conv1d (K=4, zero left-pad per batch) + SiLU.
__global__ __launch_bounds__(256) void conv_silu_k(
    const float* __restrict__ src, const float* __restrict__ w,
    float* __restrict__ dst, int C) {
  const int bt = blockIdx.x;
  const int b = bt / T_, t = bt % T_;
  const float* s = src + (size_t)b * T_ * C;
  for (int c = threadIdx.x; c < C; c += blockDim.x) {
    const float w0 = w[c * 4 + 0], w1 = w[c * 4 + 1],
                w2 = w[c * 4 + 2], w3 = w[c * 4 + 3];
    float acc = s[(size_t)t * C + c] * w3;
    if (t >= 1) acc += s[(size_t)(t - 1) * C + c] * w2;
    if (t >= 2) acc += s[(size_t)(t - 2) * C + c] * w1;
    if (t >= 3) acc += s[(size_t)(t - 3) * C + c] * w0;
    dst[(size_t)bt * C + c] = acc * (1.f / (1.f + __expf(-acc)));
  }
}

// ---------------------------------------------------------------------------
// beta = sigmoid(pb); g = -exp(A_log[h]) * softplus(pa + dt_bias[h])
__global__ void beta_g_k(const float* __restrict__ pa, const float* __restrict__ pb,
                         const float* __restrict__ dtb, const float* __restrict__ Alog,
                         float* __restrict__ g, float* __restrict__ beta, int n) {
  const int i = blockIdx.x * blockDim.x + threadIdx.x;
  if (i >= n) return;
  const int h = i & (H_ - 1);
  const float xx = pa[i] + dtb[h];
  const float sp = (xx > 20.f) ? xx : log1pf(expf(xx));
  g[i] = -expf(Alog[h]) * sp;
  beta[i] = 1.f / (1.f + expf(-pb[i]));
}

// ---------------------------------------------------------------------------
// l2norm over rows of 64 (one wave per row), in place, with optional scale.
__global__ __launch_bounds__(64) void l2norm_k(float* __restrict__ q, float scale) {
  const size_t row = blockIdx.x;
  const int lane = threadIdx.x;
  const float v = q[row * 64 + lane];
  float ss = v * v;
  for (int off = 32; off > 0; off >>= 1) ss += __shfl_xor(ss, off, 64);
  q[row * 64 + lane] = v * rsqrtf(ss + 1e-6f) * scale;
}

// ---------------------------------------------------------------------------
// Gated delta rule scan, v2: latency-optimized sequential scan.
// Grid = 32 (b,h) x 4 column-groups = 128 WGs; block = 64 (ONE wave -> no
// s_barrier; LDS write->read ordering within the wave is lgkmcnt-enforced).
// Lane layout: colloc = lane&31, kh = lane>>5. Thread owns S[kh*32 + i][col],
// i in [0,32), col = cg*32 + colloc  -> 32 VGPRs of state.
// Per step: err = k·S (2-way shfl reduce), vn = (v - eg*err)*beta,
// S = eg*S + k*vn, o = q·S (2-way shfl reduce). Next step's k/q/v/g/beta are
// prefetched into registers during compute (double-buffered LDS for k/q).
__global__ __launch_bounds__(64) void scan2_k(
    const float* __restrict__ q, const float* __restrict__ k,
    const float* __restrict__ v, const float* __restrict__ g,
    const float* __restrict__ beta, float* __restrict__ o) {
  const int bh = blockIdx.x >> 2;     // 0..31
  const int cg = blockIdx.x & 3;      // column group 0..3
  const int b = bh >> 4, hh = bh & 15;
  const int lane = threadIdx.x;
  const int colloc = lane & 31;
  const int kh = lane >> 5;           // k-half 0/1
  const int col = cg * 32 + colloc;
  float S[32];
#pragma unroll
  for (int i = 0; i < 32; ++i) S[i] = 0.f;
  __shared__ __align__(16) float lk[2][64];
  __shared__ __align__(16) float lq[2][64];
  const size_t qk0 = ((size_t)b * T_ * H_ + hh) * DK_;
  const size_t v0  = ((size_t)b * T_ * H_ + hh) * DV_;
  const size_t gb0 = (size_t)b * T_ * H_ + hh;
  // preload t = 0
  float kr = k[qk0 + lane];
  float qr = q[qk0 + lane];
  float vr = v[v0 + col];
  float gr = g[gb0];
  float br = beta[gb0];
  for (int t = 0; t < T_; ++t) {
    const int buf = t & 1;
    lk[buf][lane] = kr;
    lq[buf][lane] = qr;
    const float vt = vr, gt = gr, bt = br;
    // prefetch t+1 (clamped) — latency hidden behind this step's compute
    const int tn = (t + 1 < T_) ? t + 1 : t;
    const size_t qoffn = qk0 + (size_t)tn * H_ * DK_;
    kr = k[qoffn + lane];
    qr = q[qoffn + lane];
    vr = v[v0 + (size_t)tn * H_ * DV_ + col];
    gr = g[gb0 + (size_t)tn * H_];
    br = beta[gb0 + (size_t)tn * H_];
    const float eg = __expf(gt);
    const float4* k4 = (const float4*)&lk[buf][kh * 32];
    const float4* q4 = (const float4*)&lq[buf][kh * 32];
    float e0 = 0.f, e1 = 0.f, e2 = 0.f, e3 = 0.f;
#pragma unroll
    for (int i = 0; i < 8; ++i) {
      const float4 kk = k4[i];
      e0 += kk.x * S[4 * i + 0];
      e1 += kk.y * S[4 * i + 1];
      e2 += kk.z * S[4 * i + 2];
      e3 += kk.w * S[4 * i + 3];
    }
    float e = (e0 + e1) + (e2 + e3);
    e += __shfl_xor(e, 32, 64);        // combine the two k-halves
    const float vn = (vt - eg * e) * bt;
    float o0 = 0.f, o1 = 0.f, o2 = 0.f, o3 = 0.f;
#pragma unroll
    for (int i = 0; i < 8; ++i) {
      const float4 kk = k4[i];
      const float4 qq = q4[i];
      float s0 = eg * S[4 * i + 0] + kk.x * vn; S[4 * i + 0] = s0; o0 += qq.x * s0;
      float s1 = eg * S[4 * i + 1] + kk.y * vn; S[4 * i + 1] = s1; o1 += qq.y * s1;
      float s2 = eg * S[4 * i + 2] + kk.z * vn; S[4 * i + 2] = s2; o2 += qq.z * s2;
      float s3 = eg * S[4 * i + 3] + kk.w * vn; S[4 * i + 3] = s3; o3 += qq.w * s3;
    }
    float oo = (o0 + o1) + (o2 + o3);
    oo += __shfl_xor(oo, 32, 64);
    if (kh == 0) o[v0 + (size_t)t * H_ * DV_ + col] = oo;
  }
}

// ---------------------------------------------------------------------------
// go = rmsnorm(o, onw, 1e-5) * silu(gate); rows of DV=128 per (b,t,h).
__global__ __launch_bounds__(128) void gatenorm_k(
    const float* __restrict__ o, const float* __restrict__ onw,
    const float* __restrict__ gate, float* __restrict__ go) {
  const size_t row = blockIdx.x;
  const int i = threadIdx.x;
  const float x = o[row * DV_ + i];
  float ss = x * x;
  for (int off = 32; off > 0; off >>= 1) ss += __shfl_xor(ss, off, 64);
  __shared__ float w2[2];
  if ((i & 63) == 0) w2[i >> 6] = ss;
  __syncthreads();
  const float r = rsqrtf((w2[0] + w2[1]) / (float)DV_ + 1e-5f);
  const float gg = gate[row * DV_ + i];
  go[row * DV_ + i] = x * r * onw[i] * gg * (1.f / (1.f + __expf(-gg)));
}

// ---------------------------------------------------------------------------
// out = silu(a1) * a3 (elementwise, float4); out may alias a1.
__global__ void silumul_k(const float4* a1, const float4* a3, float4* outp, int n4) {
  const int i = blockIdx.x * blockDim.x + threadIdx.x;
  if (i >= n4) return;
  const float4 a = a1[i], c = a3[i];
  float4 r;
  r.x = a.x * (1.f / (1.f + __expf(-a.x))) * c.x;
  r.y = a.y * (1.f / (1.f + __expf(-a.y))) * c.y;
  r.z = a.z * (1.f / (1.f + __expf(-a.z))) * c.z;
  r.w = a.w * (1.f / (1.f + __expf(-a.w))) * c.w;
  outp[i] = r;
}

// ---------------------------------------------------------------------------
extern "C" void kernel_launch(void* const* d_in, const int* in_sizes, int n_in,
                              void* d_out, int out_size, void* d_ws, size_t ws_size,
                              hipStream_t stream) {
  const float* x    = (const float*)d_in[0];
  const float* n1w  = (const float*)d_in[1];
  const float* n2w  = (const float*)d_in[2];
  const float* Wq   = (const float*)d_in[3];
  const float* Wk   = (const float*)d_in[4];
  const float* Wv   = (const float*)d_in[5];
  const float* cq   = (const float*)d_in[6];
  const float* ck   = (const float*)d_in[7];
  const float* cv   = (const float*)d_in[8];
  const float* Wa   = (const float*)d_in[9];
  const float* Wb   = (const float*)d_in[10];
  const float* dtb  = (const float*)d_in[11];
  const float* Alog = (const float*)d_in[12];
  const float* Wg   = (const float*)d_in[13];
  const float* onw  = (const float*)d_in[14];
  const float* Wo   = (const float*)d_in[15];
  const float* W1   = (const float*)d_in[16];
  const float* W3   = (const float*)d_in[17];
  const float* W2   = (const float*)d_in[18];
  float* out = (float*)d_out;
  float* ws  = (float*)d_ws;

  const size_t SZ_MD = (size_t)M_ * D_;          // 2M floats
  const size_t SZ_MV = (size_t)M_ * H_ * DV_;    // 4M floats
  float* h    = ws;                               // [0,2M)
  float* pq   = ws + SZ_MD;                       // [2M,4M)
  float* pk   = ws + 2 * SZ_MD;                   // [4M,6M)
  float* pv   = ws + 3 * SZ_MD;                   // [6M,10M)
  float* gate = ws + 3 * SZ_MD + SZ_MV;           // [10M,14M)
  float* qb   = ws + 3 * SZ_MD + 2 * SZ_MV;       // [14M,16M)
  float* kb   = ws + 4 * SZ_MD + 2 * SZ_MV;       // [16M,18M)
  float* vb   = ws + 5 * SZ_MD + 2 * SZ_MV;       // [18M,22M)
  float* ob   = pv;    // o reuses pv (free after conv v)
  float* go   = vb;    // gated out reuses v (free after scan)
  float* y1   = pq;    // reuses pq (free after conv q)
  float* h2   = pk;    // reuses pk (free after conv k)
  float* a1   = pv;    // pv+gate free by FFN time
  float* a3   = qb;    // q,k,go free by FFN time
  float* smalls = ws + 5 * SZ_MD + 3 * SZ_MV;     // 22M
  float* pa = smalls;
  float* pb = pa + (size_t)M_ * H_;
  float* gv = pb + (size_t)M_ * H_;
  float* bv = gv + (size_t)M_ * H_;

  const dim3 blk256(256);

  rmsnorm_k<<<dim3(M_), blk256, 0, stream>>>(x, n1w, h, D_, 1e-6f);
  gemm_k<<<dim3(D_ / BN, M_ / BM), blk256, 0, stream>>>(h, Wq, (const float*)nullptr, pq, M_, D_, D_);
  gemm_k<<<dim3(D_ / BN, M_ / BM), blk256, 0, stream>>>(h, Wk, (const float*)nullptr, pk, M_, D_, D_);
  gemm_k<<<dim3((H_ * DV_) / BN, M_ / BM), blk256, 0, stream>>>(h, Wv, (const float*)nullptr, pv, M_, H_ * DV_, D_);
  gemm_k<<<dim3((H_ * DV_) / BN, M_ / BM), blk256, 0, stream>>>(h, Wg, (const float*)nullptr, gate, M_, H_ * DV_, D_);
  skinny_k<<<dim3(M_), blk256, 0, stream>>>(h, Wa, Wb, pa, pb, D_);
  conv_silu_k<<<dim3(M_), blk256, 0, stream>>>(pq, cq, qb, H_ * DK_);
  conv_silu_k<<<dim3(M_), blk256, 0, stream>>>(pk, ck, kb, H_ * DK_);
  conv_silu_k<<<dim3(M_), blk256, 0, stream>>>(pv, cv, vb, H_ * DV_);
  beta_g_k<<<dim3((M_ * H_ + 255) / 256), blk256, 0, stream>>>(pa, pb, dtb, Alog, gv, bv, M_ * H_);
  l2norm_k<<<dim3(M_ * H_), dim3(64), 0, stream>>>(qb, 0.125f);
  l2norm_k<<<dim3(M_ * H_), dim3(64), 0, stream>>>(kb, 1.0f);
  scan2_k<<<dim3(B_ * H_ * 4), dim3(64), 0, stream>>>(qb, kb, vb, gv, bv, ob);
  gatenorm_k<<<dim3(M_ * H_), dim3(128), 0, stream>>>(ob, onw, gate, go);
  gemm_k<<<dim3(D_ / BN, M_ / BM), blk256, 0, stream>>>(go, Wo, x, y1, M_, D_, H_ * DV_);
  rmsnorm_k<<<dim3(M_), blk256, 0, stream>>>(y1, n2w, h2, D_, 1e-6f);
  gemm_k<<<dim3(FH_ / BN, M_ / BM), blk256, 0, stream>>>(h2, W1, (const float*)nullptr, a1, M_, FH_, D_);
  gemm_k<<<dim3(FH_ / BN, M_ / BM), blk256, 0, stream>>>(h2, W3, (const float*)nullptr, a3, M_, FH_, D_);
  const int n4 = (M_ * FH_) / 4;
  silumul_k<<<dim3((n4 + 255) / 256), blk256, 0, stream>>>((const float4*)a1, (const float4*)a3, (float4*)a1, n4);
  gemm_k<<<dim3(D_ / BN, M_ / BM), blk256, 0, stream>>>(a1, W2, y1, out, M_, D_, FH_);
}

// Round 3
// 2100.320 us; speedup vs baseline: 1.2280x; 1.0880x over previous
//
#include <hip/hip_runtime.h>
#include <hip/hip_bf16.h>
#include <math.h>

// Problem constants
#define B_  2
#define T_  1024
#define D_  1024
#define H_  16
#define DK_ 64
#define DV_ 128
#define FH_ 2816
#define M_  (B_ * T_)   // 2048 tokens
#define C_  64          // chunk length
#define NCH (T_ / C_)   // 16 chunks

// ---------------------------------------------------------------------------
__global__ __launch_bounds__(256) void rmsnorm_k(
    const float* __restrict__ x, const float* __restrict__ w,
    float* __restrict__ out, int D, float eps) {
  const int row = blockIdx.x;
  const float* xr = x + (size_t)row * D;
  float ss = 0.f;
  for (int i = threadIdx.x; i < D; i += blockDim.x) { float v = xr[i]; ss += v * v; }
  for (int off = 32; off > 0; off >>= 1) ss += __shfl_xor(ss, off, 64);
  __shared__ float wsum[4];
  __shared__ float s_scale;
  const int lane = threadIdx.x & 63, wid = threadIdx.x >> 6;
  if (lane == 0) wsum[wid] = ss;
  __syncthreads();
  if (threadIdx.x == 0) {
    float tot = 0.f;
    const int nw = blockDim.x >> 6;
    for (int i = 0; i < nw; ++i) tot += wsum[i];
    s_scale = rsqrtf(tot / (float)D + eps);
  }
  __syncthreads();
  const float sc = s_scale;
  for (int i = threadIdx.x; i < D; i += blockDim.x)
    out[(size_t)row * D + i] = xr[i] * sc * w[i];
}

// ---------------------------------------------------------------------------
// fp32 SIMT GEMM: C[M,N] = A[M,K] @ Bw[K,N] (+ res). 64x64 tile, BK=16.
#define BM 64
#define BN 64
#define BK 16
__global__ __launch_bounds__(256) void gemm_k(
    const float* __restrict__ A, const float* __restrict__ Bw,
    const float* __restrict__ res, float* __restrict__ C,
    int M, int N, int K) {
  __shared__ float As[BK][68];
  __shared__ float Bs[BK][BN];
  const int tid = threadIdx.x;
  const int bx = blockIdx.x, by = blockIdx.y;
  const int tx = tid & 15, ty = tid >> 4;
  const int arow = tid >> 2;
  const int akc  = (tid & 3) * 4;
  const int bcol = (tid & 15) * 4;
  const int brow = tid >> 4;
  const float* Ab = A + (size_t)(by * BM + arow) * K + akc;
  const float* Bb = Bw + (size_t)brow * N + (size_t)bx * BN + bcol;
  float acc[4][4] = {};
  for (int k0 = 0; k0 < K; k0 += BK) {
    const float4 av = *(const float4*)(Ab + k0);
    const float4 bv = *(const float4*)(Bb + (size_t)k0 * N);
    As[akc + 0][arow] = av.x; As[akc + 1][arow] = av.y;
    As[akc + 2][arow] = av.z; As[akc + 3][arow] = av.w;
    *(float4*)&Bs[brow][bcol] = bv;
    __syncthreads();
#pragma unroll
    for (int kk = 0; kk < BK; ++kk) {
      const float4 a = *(const float4*)&As[kk][ty * 4];
      const float4 b = *(const float4*)&Bs[kk][tx * 4];
      const float ar[4] = {a.x, a.y, a.z, a.w};
      const float br[4] = {b.x, b.y, b.z, b.w};
#pragma unroll
      for (int i = 0; i < 4; ++i)
#pragma unroll
        for (int j = 0; j < 4; ++j) acc[i][j] += ar[i] * br[j];
    }
    __syncthreads();
  }
  const int crow = by * BM + ty * 4, ccol = bx * BN + tx * 4;
#pragma unroll
  for (int i = 0; i < 4; ++i) {
    const size_t off = (size_t)(crow + i) * N + ccol;
    float4 r = make_float4(acc[i][0], acc[i][1], acc[i][2], acc[i][3]);
    if (res) {
      const float4 rv = *(const float4*)(res + off);
      r.x += rv.x; r.y += rv.y; r.z += rv.z; r.w += rv.w;
    }
    *(float4*)(C + off) = r;
  }
}

// ---------------------------------------------------------------------------
__global__ __launch_bounds__(256) void skinny_k(
    const float* __restrict__ h, const float* __restrict__ Wa,
    const float* __restrict__ Wb, float* __restrict__ pa,
    float* __restrict__ pb, int K) {
  __shared__ float hl[D_];
  const int row = blockIdx.x;
  for (int i = threadIdx.x; i < K; i += blockDim.x) hl[i] = h[(size_t)row * K + i];
  __syncthreads();
  const int t = threadIdx.x;
  if (t < 32) {
    const float* W = (t < 16) ? Wa : Wb;
    const int col = t & 15;
    float s = 0.f;
    for (int k = 0; k < K; ++k) s += hl[k] * W[k * H_ + col];
    if (t < 16) pa[(size_t)row * H_ + col] = s;
    else        pb[(size_t)row * H_ + col] = s;
  }
}

// ---------------------------------------------------------------------------
__global__ __launch_bounds__(256) void conv_silu_k(
    const float* __restrict__ src, const float* __restrict__ w,
    float* __restrict__ dst, int C) {
  const int bt = blockIdx.x;
  const int b = bt / T_, t = bt % T_;
  const float* s = src + (size_t)b * T_ * C;
  for (int c = threadIdx.x; c < C; c += blockDim.x) {
    const float w0 = w[c * 4 + 0], w1 = w[c * 4 + 1],
                w2 = w[c * 4 + 2], w3 = w[c * 4 + 3];
    float acc = s[(size_t)t * C + c] * w3;
    if (t >= 1) acc += s[(size_t)(t - 1) * C + c] * w2;
    if (t >= 2) acc += s[(size_t)(t - 2) * C + c] * w1;
    if (t >= 3) acc += s[(size_t)(t - 3) * C + c] * w0;
    dst[(size_t)bt * C + c] = acc * (1.f / (1.f + __expf(-acc)));
  }
}

// ---------------------------------------------------------------------------
__global__ void beta_g_k(const float* __restrict__ pa, const float* __restrict__ pb,
                         const float* __restrict__ dtb, const float* __restrict__ Alog,
                         float* __restrict__ g, float* __restrict__ beta, int n) {
  const int i = blockIdx.x * blockDim.x + threadIdx.x;
  if (i >= n) return;
  const int h = i & (H_ - 1);
  const float xx = pa[i] + dtb[h];
  const float sp = (xx > 20.f) ? xx : log1pf(expf(xx));
  g[i] = -expf(Alog[h]) * sp;
  beta[i] = 1.f / (1.f + expf(-pb[i]));
}

// ---------------------------------------------------------------------------
__global__ __launch_bounds__(64) void l2norm_k(float* __restrict__ q, float scale) {
  const size_t row = blockIdx.x;
  const int lane = threadIdx.x;
  const float v = q[row * 64 + lane];
  float ss = v * v;
  for (int off = 32; off > 0; off >>= 1) ss += __shfl_xor(ss, off, 64);
  q[row * 64 + lane] = v * rsqrtf(ss + 1e-6f) * scale;
}

// ---------------------------------------------------------------------------
// Chunked gated delta rule, phase A (parallel over 512 (bh,chunk) tasks).
// Builds Ā (β-folded strict-lower decay Gram), QKd = (q·k)decay (->pq),
// KdT[dk][s] = k_s e^{bC-bs} (->pk), γ (->gam), then forward-substitution
// solves (I+Ā)X = RHS for u = M^{-1}βV (in place over vb) and
// W = M^{-1}β diag(γ)K (in place over kb). All decay exponents <= 0.
__global__ __launch_bounds__(256) void chunk_prep_k(
    const float* __restrict__ q, float* __restrict__ k, float* __restrict__ v,
    const float* __restrict__ g, const float* __restrict__ beta,
    float* __restrict__ qkd, float* __restrict__ kdt, float* __restrict__ gam) {
  const int task = blockIdx.x;
  const int bh = task >> 4, n = task & (NCH - 1);
  const int b = bh >> 4, h = bh & 15;
  const int t0 = n * C_;
  const int tid = threadIdx.x;
  __shared__ float lk[C_][68];     // k rows, padded (272B, 16B-aligned)
  __shared__ float Ab[C_][C_];     // β-folded strict-lower Ā (zeros elsewhere)
  __shared__ float lb[C_], lgam[C_], lbeta[C_];
  // stage k chunk: thread -> (row = tid>>2, 16 floats at (tid&3)*16)
  {
    const int r = tid >> 2, cq = (tid & 3) * 16;
    const float* src = k + (((size_t)b * T_ + t0 + r) * H_ + h) * DK_ + cq;
#pragma unroll
    for (int i = 0; i < 4; ++i)
      *(float4*)&lk[r][cq + 4 * i] = ((const float4*)src)[i];
  }
  // g cumsum (wave 0), γ, β
  if (tid < 64) {
    const size_t gi = ((size_t)b * T_ + t0 + tid) * H_ + h;
    float x = g[gi];
    lbeta[tid] = beta[gi];
#pragma unroll
    for (int off = 1; off < 64; off <<= 1) {
      float y = __shfl_up(x, off, 64);
      if (tid >= off) x += y;
    }
    lb[tid] = x;
    lgam[tid] = __expf(x);
  }
  __syncthreads();
  // build Ā and QKd (4x4 tiles per thread)
  {
    const int tt = (tid >> 4) * 4;
    const int ss = (tid & 15) * 4;
    const float* qg = q + (((size_t)b * T_ + t0) * H_ + h) * DK_;
    float accA[4][4] = {};
    float accQ[4][4] = {};
    for (int d = 0; d < 64; d += 4) {
      float4 kt[4], ks[4], qt[4];
#pragma unroll
      for (int i = 0; i < 4; ++i) kt[i] = *(const float4*)&lk[tt + i][d];
#pragma unroll
      for (int j = 0; j < 4; ++j) ks[j] = *(const float4*)&lk[ss + j][d];
#pragma unroll
      for (int i = 0; i < 4; ++i) qt[i] = *(const float4*)(qg + (size_t)(tt + i) * (H_ * DK_) + d);
#pragma unroll
      for (int i = 0; i < 4; ++i)
#pragma unroll
        for (int j = 0; j < 4; ++j) {
          accA[i][j] += kt[i].x * ks[j].x + kt[i].y * ks[j].y + kt[i].z * ks[j].z + kt[i].w * ks[j].w;
          accQ[i][j] += qt[i].x * ks[j].x + qt[i].y * ks[j].y + qt[i].z * ks[j].z + qt[i].w * ks[j].w;
        }
    }
    float* qo = qkd + (size_t)task * 4096;
#pragma unroll
    for (int i = 0; i < 4; ++i)
#pragma unroll
      for (int j = 0; j < 4; ++j) {
        const int t = tt + i, s = ss + j;
        const float dec = (s <= t) ? __expf(lb[t] - lb[s]) : 0.f;
        Ab[t][s] = (t > s) ? lbeta[t] * accA[i][j] * dec : 0.f;
        qo[t * 64 + s] = accQ[i][j] * dec;   // s>t -> 0
      }
  }
  // KdT and γ
  {
    const int dk = tid >> 2, s0 = (tid & 3) * 16;
    const float bC = lb[63];
    float* dst = kdt + (size_t)task * 4096 + dk * 64 + s0;
#pragma unroll
    for (int j = 0; j < 16; ++j)
      dst[j] = lk[s0 + j][dk] * __expf(bC - lb[s0 + j]);
  }
  if (tid < 64) gam[(size_t)task * 64 + tid] = lgam[tid];
  __syncthreads();
  // forward substitution: cols 0..127 -> v (u), cols 128..191 -> k (W)
  if (tid < 192) {
    float X[64];
    const int c = tid;
    if (c < 128) {
#pragma unroll
      for (int s = 0; s < 64; ++s)
        X[s] = lbeta[s] * v[(((size_t)b * T_ + t0 + s) * H_ + h) * DV_ + c];
    } else {
      const int cc = c - 128;
#pragma unroll
      for (int s = 0; s < 64; ++s)
        X[s] = lbeta[s] * lgam[s] * lk[s][cc];
    }
#pragma unroll
    for (int t = 1; t < 64; ++t) {
      float sum = 0.f;
      const int nb = (t + 3) >> 2;
#pragma unroll
      for (int s4 = 0; s4 < nb; ++s4) {
        const float4 a = *(const float4*)&Ab[t][s4 * 4];
        sum += a.x * X[s4 * 4] + a.y * X[s4 * 4 + 1] + a.z * X[s4 * 4 + 2] + a.w * X[s4 * 4 + 3];
      }
      X[t] -= sum;   // coeffs for s>=t are 0, so reading stale X there is safe
    }
    if (c < 128) {
#pragma unroll
      for (int s = 0; s < 64; ++s)
        v[(((size_t)b * T_ + t0 + s) * H_ + h) * DV_ + c] = X[s];
    } else {
      const int cc = c - 128;
#pragma unroll
      for (int s = 0; s < 64; ++s)
        k[(((size_t)b * T_ + t0 + s) * H_ + h) * DK_ + cc] = X[s];
    }
  }
}

// ---------------------------------------------------------------------------
// Chunked gated delta rule, phase B (sequential over chunks).
// Grid = 32 bh x 4 col-groups (32 DV cols each); 256 threads.
// Per chunk: P = [γQ; W] @ S  (phase1: Preg = γQS0; Û = u - WS0),
// then [QKd; KdT] @ Û (phase2: O = Preg + QKd·Û; S = γC·S + KdT·Û).
__global__ __launch_bounds__(256) void chunk_scan_k(
    const float* __restrict__ q, const float* __restrict__ W,
    const float* __restrict__ u, const float* __restrict__ qkd,
    const float* __restrict__ kdt, const float* __restrict__ gam,
    float* __restrict__ o) {
  const int bh = blockIdx.x >> 2, cgp = blockIdx.x & 3;
  const int b = bh >> 4, h = bh & 15;
  const int tid = threadIdx.x;
  __shared__ float STG[128][68];   // staged [128x64] operand (padded)
  __shared__ float St[32][68];     // S transposed: St[c][dk]
  __shared__ float Ubt[32][68];    // Û transposed: Ubt[c][t]
  __shared__ float lgam[64];
  for (int i = tid; i < 32 * 68; i += 256) { (&St[0][0])[i] = 0.f; }
  const int c4 = (tid & 7) * 4;    // local col tile base (0..28)
  const int rg = tid >> 3;         // row-group 0..31
  const int r4 = rg * 4;           // row tile base (0..124)
  const int srow = tid >> 1, shalf = tid & 1;   // staging map
  float Preg[4][4];
  for (int n = 0; n < NCH; ++n) {
    const int task = bh * NCH + n;
    const int t0 = n * C_;
    __syncthreads();               // prev-chunk phase2 done (St, STG, lgam free)
    if (tid < 64) lgam[tid] = gam[(size_t)task * 64 + tid];
    __syncthreads();
    // stage WQ: rows 0..63 = γ_t q_t, rows 64..127 = W
    {
      float scale = 1.f;
      const float* src;
      if (srow < 64) { src = q + (((size_t)b * T_ + t0 + srow) * H_ + h) * DK_; scale = lgam[srow]; }
      else           { src = W + (((size_t)b * T_ + t0 + srow - 64) * H_ + h) * DK_; }
      const float* s2 = src + shalf * 32;
      float* dst = &STG[srow][shalf * 32];
#pragma unroll
      for (int i = 0; i < 8; ++i) {
        float4 x = ((const float4*)s2)[i];
        x.x *= scale; x.y *= scale; x.z *= scale; x.w *= scale;
        ((float4*)dst)[i] = x;
      }
    }
    __syncthreads();
    // phase 1: acc = STG[r4..][:] @ S[:, c4..]
    {
      float acc[4][4] = {};
      for (int d = 0; d < 64; d += 4) {
        float4 wv[4], sv[4];
#pragma unroll
        for (int j = 0; j < 4; ++j) wv[j] = *(const float4*)&STG[r4 + j][d];
#pragma unroll
        for (int i = 0; i < 4; ++i) sv[i] = *(const float4*)&St[c4 + i][d];
#pragma unroll
        for (int j = 0; j < 4; ++j)
#pragma unroll
          for (int i = 0; i < 4; ++i)
            acc[j][i] += wv[j].x * sv[i].x + wv[j].y * sv[i].y + wv[j].z * sv[i].z + wv[j].w * sv[i].w;
      }
      if (rg < 16) {
#pragma unroll
        for (int j = 0; j < 4; ++j)
#pragma unroll
          for (int i = 0; i < 4; ++i) Preg[j][i] = acc[j][i];
      } else {
#pragma unroll
        for (int j = 0; j < 4; ++j) {
          const int t = r4 + j - 64;
          const size_t ubase = (((size_t)b * T_ + t0 + t) * H_ + h) * DV_ + cgp * 32;
#pragma unroll
          for (int i = 0; i < 4; ++i)
            Ubt[c4 + i][t] = u[ubase + c4 + i] - acc[j][i];
        }
      }
    }
    __syncthreads();
    // stage KK: rows 0..63 = QKd, rows 64..127 = KdT
    {
      const float* src = (srow < 64)
          ? qkd + (size_t)task * 4096 + srow * 64
          : kdt + (size_t)task * 4096 + (srow - 64) * 64;
      const float* s2 = src + shalf * 32;
      float* dst = &STG[srow][shalf * 32];
#pragma unroll
      for (int i = 0; i < 8; ++i) ((float4*)dst)[i] = ((const float4*)s2)[i];
    }
    __syncthreads();
    // phase 2: acc2 = STG[r4..][:] @ Û[:, c4..]
    {
      float acc2[4][4] = {};
      for (int s = 0; s < 64; s += 4) {
        float4 kv[4], uv[4];
#pragma unroll
        for (int j = 0; j < 4; ++j) kv[j] = *(const float4*)&STG[r4 + j][s];
#pragma unroll
        for (int i = 0; i < 4; ++i) uv[i] = *(const float4*)&Ubt[c4 + i][s];
#pragma unroll
        for (int j = 0; j < 4; ++j)
#pragma unroll
          for (int i = 0; i < 4; ++i)
            acc2[j][i] += kv[j].x * uv[i].x + kv[j].y * uv[i].y + kv[j].z * uv[i].z + kv[j].w * uv[i].w;
      }
      if (rg < 16) {
#pragma unroll
        for (int j = 0; j < 4; ++j) {
          const int t = r4 + j;
          const size_t obase = (((size_t)b * T_ + t0 + t) * H_ + h) * DV_ + cgp * 32;
#pragma unroll
          for (int i = 0; i < 4; ++i)
            o[obase + c4 + i] = Preg[j][i] + acc2[j][i];
        }
      } else {
        const float gC = lgam[63];
#pragma unroll
        for (int j = 0; j < 4; ++j) {
          const int dk = r4 + j - 64;
#pragma unroll
          for (int i = 0; i < 4; ++i)
            St[c4 + i][dk] = gC * St[c4 + i][dk] + acc2[j][i];
        }
      }
    }
  }
}

// ---------------------------------------------------------------------------
__global__ __launch_bounds__(128) void gatenorm_k(
    const float* __restrict__ o, const float* __restrict__ onw,
    const float* __restrict__ gate, float* __restrict__ go) {
  const size_t row = blockIdx.x;
  const int i = threadIdx.x;
  const float x = o[row * DV_ + i];
  float ss = x * x;
  for (int off = 32; off > 0; off >>= 1) ss += __shfl_xor(ss, off, 64);
  __shared__ float w2[2];
  if ((i & 63) == 0) w2[i >> 6] = ss;
  __syncthreads();
  const float r = rsqrtf((w2[0] + w2[1]) / (float)DV_ + 1e-5f);
  const float gg = gate[row * DV_ + i];
  go[row * DV_ + i] = x * r * onw[i] * gg * (1.f / (1.f + __expf(-gg)));
}

// ---------------------------------------------------------------------------
__global__ void silumul_k(const float4* a1, const float4* a3, float4* outp, int n4) {
  const int i = blockIdx.x * blockDim.x + threadIdx.x;
  if (i >= n4) return;
  const float4 a = a1[i], c = a3[i];
  float4 r;
  r.x = a.x * (1.f / (1.f + __expf(-a.x))) * c.x;
  r.y = a.y * (1.f / (1.f + __expf(-a.y))) * c.y;
  r.z = a.z * (1.f / (1.f + __expf(-a.z))) * c.z;
  r.w = a.w * (1.f / (1.f + __expf(-a.w))) * c.w;
  outp[i] = r;
}

// ---------------------------------------------------------------------------
extern "C" void kernel_launch(void* const* d_in, const int* in_sizes, int n_in,
                              void* d_out, int out_size, void* d_ws, size_t ws_size,
                              hipStream_t stream) {
  const float* x    = (const float*)d_in[0];
  const float* n1w  = (const float*)d_in[1];
  const float* n2w  = (const float*)d_in[2];
  const float* Wq   = (const float*)d_in[3];
  const float* Wk   = (const float*)d_in[4];
  const float* Wv   = (const float*)d_in[5];
  const float* cq   = (const float*)d_in[6];
  const float* ck   = (const float*)d_in[7];
  const float* cv   = (const float*)d_in[8];
  const float* Wa   = (const float*)d_in[9];
  const float* Wb   = (const float*)d_in[10];
  const float* dtb  = (const float*)d_in[11];
  const float* Alog = (const float*)d_in[12];
  const float* Wg   = (const float*)d_in[13];
  const float* onw  = (const float*)d_in[14];
  const float* Wo   = (const float*)d_in[15];
  const float* W1   = (const float*)d_in[16];
  const float* W3   = (const float*)d_in[17];
  const float* W2   = (const float*)d_in[18];
  float* out = (float*)d_out;
  float* ws  = (float*)d_ws;

  const size_t SZ_MD = (size_t)M_ * D_;          // 2M floats
  const size_t SZ_MV = (size_t)M_ * H_ * DV_;    // 4M floats
  float* h    = ws;                               // [0,2M)
  float* pq   = ws + SZ_MD;                       // [2M,4M)   later: QKd, then y1
  float* pk   = ws + 2 * SZ_MD;                   // [4M,6M)   later: KdT, then h2
  float* pv   = ws + 3 * SZ_MD;                   // [6M,10M)  later: o, then a1
  float* gate = ws + 3 * SZ_MD + SZ_MV;           // [10M,14M)
  float* qb   = ws + 3 * SZ_MD + 2 * SZ_MV;       // [14M,16M) later: a3
  float* kb   = ws + 4 * SZ_MD + 2 * SZ_MV;       // [16M,18M) in-place W
  float* vb   = ws + 5 * SZ_MD + 2 * SZ_MV;       // [18M,22M) in-place u, then go
  float* ob   = pv;
  float* go   = vb;
  float* y1   = pq;
  float* h2   = pk;
  float* a1   = pv;
  float* a3   = qb;
  float* smalls = ws + 5 * SZ_MD + 3 * SZ_MV;     // 22M
  float* pa  = smalls;
  float* pb  = pa + (size_t)M_ * H_;
  float* gv  = pb + (size_t)M_ * H_;
  float* bv  = gv + (size_t)M_ * H_;
  float* gam = bv + (size_t)M_ * H_;              // 512*64 floats

  const dim3 blk256(256);

  rmsnorm_k<<<dim3(M_), blk256, 0, stream>>>(x, n1w, h, D_, 1e-6f);
  gemm_k<<<dim3(D_ / BN, M_ / BM), blk256, 0, stream>>>(h, Wq, (const float*)nullptr, pq, M_, D_, D_);
  gemm_k<<<dim3(D_ / BN, M_ / BM), blk256, 0, stream>>>(h, Wk, (const float*)nullptr, pk, M_, D_, D_);
  gemm_k<<<dim3((H_ * DV_) / BN, M_ / BM), blk256, 0, stream>>>(h, Wv, (const float*)nullptr, pv, M_, H_ * DV_, D_);
  gemm_k<<<dim3((H_ * DV_) / BN, M_ / BM), blk256, 0, stream>>>(h, Wg, (const float*)nullptr, gate, M_, H_ * DV_, D_);
  skinny_k<<<dim3(M_), blk256, 0, stream>>>(h, Wa, Wb, pa, pb, D_);
  conv_silu_k<<<dim3(M_), blk256, 0, stream>>>(pq, cq, qb, H_ * DK_);
  conv_silu_k<<<dim3(M_), blk256, 0, stream>>>(pk, ck, kb, H_ * DK_);
  conv_silu_k<<<dim3(M_), blk256, 0, stream>>>(pv, cv, vb, H_ * DV_);
  beta_g_k<<<dim3((M_ * H_ + 255) / 256), blk256, 0, stream>>>(pa, pb, dtb, Alog, gv, bv, M_ * H_);
  l2norm_k<<<dim3(M_ * H_), dim3(64), 0, stream>>>(qb, 0.125f);
  l2norm_k<<<dim3(M_ * H_), dim3(64), 0, stream>>>(kb, 1.0f);
  // chunked gated delta rule: prep (parallel) + scan (sequential over chunks)
  chunk_prep_k<<<dim3(32 * NCH), blk256, 0, stream>>>(qb, kb, vb, gv, bv, pq, pk, gam);
  chunk_scan_k<<<dim3(32 * 4), blk256, 0, stream>>>(qb, kb, vb, pq, pk, gam, ob);
  gatenorm_k<<<dim3(M_ * H_), dim3(128), 0, stream>>>(ob, onw, gate, go);
  gemm_k<<<dim3(D_ / BN, M_ / BM), blk256, 0, stream>>>(go, Wo, x, y1, M_, D_, H_ * DV_);
  rmsnorm_k<<<dim3(M_), blk256, 0, stream>>>(y1, n2w, h2, D_, 1e-6f);
  gemm_k<<<dim3(FH_ / BN, M_ / BM), blk256, 0, stream>>>(h2, W1, (const float*)nullptr, a1, M_, FH_, D_);
  gemm_k<<<dim3(FH_ / BN, M_ / BM), blk256, 0, stream>>>(h2, W3, (const float*)nullptr, a3, M_, FH_, D_);
  const int n4 = (M_ * FH_) / 4;
  silumul_k<<<dim3((n4 + 255) / 256), blk256, 0, stream>>>((const float4*)a1, (const float4*)a3, (float4*)a1, n4);
  gemm_k<<<dim3(D_ / BN, M_ / BM), blk256, 0, stream>>>(a1, W2, y1, out, M_, D_, FH_);
}

// Round 4
// 1535.411 us; speedup vs baseline: 1.6798x; 1.3679x over previous
//
#include <hip/hip_runtime.h>
#include <hip/hip_bf16.h>
#include <math.h>

// Problem constants
#define B_  2
#define T_  1024
#define D_  1024
#define H_  16
#define DK_ 64
#define DV_ 128
#define FH_ 2816
#define M_  (B_ * T_)   // 2048 tokens
#define C_  64          // chunk length
#define NCH (T_ / C_)   // 16 chunks

// ---------------------------------------------------------------------------
__global__ __launch_bounds__(256) void rmsnorm_k(
    const float* __restrict__ x, const float* __restrict__ w,
    float* __restrict__ out, int D, float eps) {
  const int row = blockIdx.x;
  const float* xr = x + (size_t)row * D;
  float ss = 0.f;
  for (int i = threadIdx.x; i < D; i += blockDim.x) { float v = xr[i]; ss += v * v; }
  for (int off = 32; off > 0; off >>= 1) ss += __shfl_xor(ss, off, 64);
  __shared__ float wsum[4];
  __shared__ float s_scale;
  const int lane = threadIdx.x & 63, wid = threadIdx.x >> 6;
  if (lane == 0) wsum[wid] = ss;
  __syncthreads();
  if (threadIdx.x == 0) {
    float tot = 0.f;
    const int nw = blockDim.x >> 6;
    for (int i = 0; i < nw; ++i) tot += wsum[i];
    s_scale = rsqrtf(tot / (float)D + eps);
  }
  __syncthreads();
  const float sc = s_scale;
  for (int i = threadIdx.x; i < D; i += blockDim.x)
    out[(size_t)row * D + i] = xr[i] * sc * w[i];
}

// ---------------------------------------------------------------------------
// fp32 SIMT GEMM: C[M,N] = A[M,K] @ Bw[K,N] (+ res). 64x64 tile, BK=16.
#define BM 64
#define BN 64
#define BK 16
__global__ __launch_bounds__(256) void gemm_k(
    const float* __restrict__ A, const float* __restrict__ Bw,
    const float* __restrict__ res, float* __restrict__ C,
    int M, int N, int K) {
  __shared__ float As[BK][68];
  __shared__ float Bs[BK][BN];
  const int tid = threadIdx.x;
  const int bx = blockIdx.x, by = blockIdx.y;
  const int tx = tid & 15, ty = tid >> 4;
  const int arow = tid >> 2;
  const int akc  = (tid & 3) * 4;
  const int bcol = (tid & 15) * 4;
  const int brow = tid >> 4;
  const float* Ab = A + (size_t)(by * BM + arow) * K + akc;
  const float* Bb = Bw + (size_t)brow * N + (size_t)bx * BN + bcol;
  float acc[4][4] = {};
  for (int k0 = 0; k0 < K; k0 += BK) {
    const float4 av = *(const float4*)(Ab + k0);
    const float4 bv = *(const float4*)(Bb + (size_t)k0 * N);
    As[akc + 0][arow] = av.x; As[akc + 1][arow] = av.y;
    As[akc + 2][arow] = av.z; As[akc + 3][arow] = av.w;
    *(float4*)&Bs[brow][bcol] = bv;
    __syncthreads();
#pragma unroll
    for (int kk = 0; kk < BK; ++kk) {
      const float4 a = *(const float4*)&As[kk][ty * 4];
      const float4 b = *(const float4*)&Bs[kk][tx * 4];
      const float ar[4] = {a.x, a.y, a.z, a.w};
      const float br[4] = {b.x, b.y, b.z, b.w};
#pragma unroll
      for (int i = 0; i < 4; ++i)
#pragma unroll
        for (int j = 0; j < 4; ++j) acc[i][j] += ar[i] * br[j];
    }
    __syncthreads();
  }
  const int crow = by * BM + ty * 4, ccol = bx * BN + tx * 4;
#pragma unroll
  for (int i = 0; i < 4; ++i) {
    const size_t off = (size_t)(crow + i) * N + ccol;
    float4 r = make_float4(acc[i][0], acc[i][1], acc[i][2], acc[i][3]);
    if (res) {
      const float4 rv = *(const float4*)(res + off);
      r.x += rv.x; r.y += rv.y; r.z += rv.z; r.w += rv.w;
    }
    *(float4*)(C + off) = r;
  }
}

// ---------------------------------------------------------------------------
__global__ __launch_bounds__(256) void skinny_k(
    const float* __restrict__ h, const float* __restrict__ Wa,
    const float* __restrict__ Wb, float* __restrict__ pa,
    float* __restrict__ pb, int K) {
  __shared__ float hl[D_];
  const int row = blockIdx.x;
  for (int i = threadIdx.x; i < K; i += blockDim.x) hl[i] = h[(size_t)row * K + i];
  __syncthreads();
  const int t = threadIdx.x;
  if (t < 32) {
    const float* W = (t < 16) ? Wa : Wb;
    const int col = t & 15;
    float s = 0.f;
    for (int k = 0; k < K; ++k) s += hl[k] * W[k * H_ + col];
    if (t < 16) pa[(size_t)row * H_ + col] = s;
    else        pb[(size_t)row * H_ + col] = s;
  }
}

// ---------------------------------------------------------------------------
__global__ __launch_bounds__(256) void conv_silu_k(
    const float* __restrict__ src, const float* __restrict__ w,
    float* __restrict__ dst, int C) {
  const int bt = blockIdx.x;
  const int b = bt / T_, t = bt % T_;
  const float* s = src + (size_t)b * T_ * C;
  for (int c = threadIdx.x; c < C; c += blockDim.x) {
    const float w0 = w[c * 4 + 0], w1 = w[c * 4 + 1],
                w2 = w[c * 4 + 2], w3 = w[c * 4 + 3];
    float acc = s[(size_t)t * C + c] * w3;
    if (t >= 1) acc += s[(size_t)(t - 1) * C + c] * w2;
    if (t >= 2) acc += s[(size_t)(t - 2) * C + c] * w1;
    if (t >= 3) acc += s[(size_t)(t - 3) * C + c] * w0;
    dst[(size_t)bt * C + c] = acc * (1.f / (1.f + __expf(-acc)));
  }
}

// ---------------------------------------------------------------------------
__global__ void beta_g_k(const float* __restrict__ pa, const float* __restrict__ pb,
                         const float* __restrict__ dtb, const float* __restrict__ Alog,
                         float* __restrict__ g, float* __restrict__ beta, int n) {
  const int i = blockIdx.x * blockDim.x + threadIdx.x;
  if (i >= n) return;
  const int h = i & (H_ - 1);
  const float xx = pa[i] + dtb[h];
  const float sp = (xx > 20.f) ? xx : log1pf(expf(xx));
  g[i] = -expf(Alog[h]) * sp;
  beta[i] = 1.f / (1.f + expf(-pb[i]));
}

// ---------------------------------------------------------------------------
__global__ __launch_bounds__(64) void l2norm_k(float* __restrict__ q, float scale) {
  const size_t row = blockIdx.x;
  const int lane = threadIdx.x;
  const float v = q[row * 64 + lane];
  float ss = v * v;
  for (int off = 32; off > 0; off >>= 1) ss += __shfl_xor(ss, off, 64);
  q[row * 64 + lane] = v * rsqrtf(ss + 1e-6f) * scale;
}

// ---------------------------------------------------------------------------
// Chunked gated delta rule, phase A v2 (parallel over 512 (bh,chunk) tasks).
// Builds Ā (β-folded strict-lower decay Gram), QKd (->qkd), KdT (->kdt), γ.
// Then computes T = (I+Ā)^{-1} via Neumann doubling on L=-Ā (strictly lower,
// L^64=0):  T = (I+L)(I+L^2)(I+L^4)(I+L^8)(I+L^16)(I+L^32)
// — 10 dense 64^3 LDS matmuls, 4x4 register tiles, NO per-thread deep arrays
// (the round-3 forward substitution spilled X[64]/thread -> 1.1 GB scratch
// traffic, 627 us). Finally u = T@(βV) (in place over v) and
// W = T@(β γ K) (in place over k) as dense matmuls.
__global__ __launch_bounds__(256) void chunk_prep_k(
    const float* __restrict__ q, float* __restrict__ k, float* __restrict__ v,
    const float* __restrict__ g, const float* __restrict__ beta,
    float* __restrict__ qkd, float* __restrict__ kdt, float* __restrict__ gam) {
  const int task = blockIdx.x;
  const int bh = task >> 4, n = task & (NCH - 1);
  const int b = bh >> 4, h = bh & 15;
  const int t0 = n * C_;
  const int tid = threadIdx.x;
  __shared__ float lk[C_][68];        // k rows (padded)
  __shared__ float bufs[3][C_][68];   // ping-pong: L-powers / T
  __shared__ float lb[C_], lgam[C_], lbeta[C_], lbg[C_];
  // stage k chunk
  {
    const int r = tid >> 2, cq = (tid & 3) * 16;
    const float* src = k + (((size_t)b * T_ + t0 + r) * H_ + h) * DK_ + cq;
#pragma unroll
    for (int i = 0; i < 4; ++i)
      *(float4*)&lk[r][cq + 4 * i] = ((const float4*)src)[i];
  }
  // g cumsum (wave 0), γ, β, βγ
  if (tid < 64) {
    const size_t gi = ((size_t)b * T_ + t0 + tid) * H_ + h;
    float xx = g[gi];
    const float bb = beta[gi];
    lbeta[tid] = bb;
#pragma unroll
    for (int off = 1; off < 64; off <<= 1) {
      float y = __shfl_up(xx, off, 64);
      if (tid >= off) xx += y;
    }
    lb[tid] = xx;
    const float gm = __expf(xx);
    lgam[tid] = gm;
    lbg[tid] = bb * gm;
  }
  __syncthreads();
  const int r4 = (tid >> 4) * 4;   // output row tile base (16 groups)
  const int sl = tid & 15;         // col lane
  const int c4 = sl * 4;           // contiguous col tile base
  // Gram: accA = K K^T, accQ = Q K^T; rows r4+i, cols sl+16*j (conflict-free)
  {
    const float* qg = q + (((size_t)b * T_ + t0) * H_ + h) * DK_;
    float accA[4][4] = {};
    float accQ[4][4] = {};
    for (int d = 0; d < 64; d += 4) {
      float4 kt[4], ks[4], qt[4];
#pragma unroll
      for (int i = 0; i < 4; ++i) kt[i] = *(const float4*)&lk[r4 + i][d];
#pragma unroll
      for (int j = 0; j < 4; ++j) ks[j] = *(const float4*)&lk[sl + 16 * j][d];
#pragma unroll
      for (int i = 0; i < 4; ++i) qt[i] = *(const float4*)(qg + (size_t)(r4 + i) * (H_ * DK_) + d);
#pragma unroll
      for (int i = 0; i < 4; ++i)
#pragma unroll
        for (int j = 0; j < 4; ++j) {
          accA[i][j] += kt[i].x * ks[j].x + kt[i].y * ks[j].y + kt[i].z * ks[j].z + kt[i].w * ks[j].w;
          accQ[i][j] += qt[i].x * ks[j].x + qt[i].y * ks[j].y + qt[i].z * ks[j].z + qt[i].w * ks[j].w;
        }
    }
    float (*L0)[68] = bufs[0];
    float (*T0)[68] = bufs[2];
    float* qo = qkd + (size_t)task * 4096;
#pragma unroll
    for (int i = 0; i < 4; ++i)
#pragma unroll
      for (int j = 0; j < 4; ++j) {
        const int t = r4 + i, s = sl + 16 * j;
        const float dec = (s <= t) ? __expf(lb[t] - lb[s]) : 0.f;
        const float Lts = (t > s) ? -(lbeta[t] * accA[i][j] * dec) : 0.f;
        L0[t][s] = Lts;
        T0[t][s] = (t == s) ? 1.f : Lts;
        qo[t * 64 + s] = accQ[i][j] * dec;
      }
  }
  // KdT and γ out
  {
    const int dk = tid >> 2, s0 = (tid & 3) * 16;
    const float bC = lb[63];
    float* dst = kdt + (size_t)task * 4096 + dk * 64 + s0;
#pragma unroll
    for (int j = 0; j < 16; ++j)
      dst[j] = lk[s0 + j][dk] * __expf(bC - lb[s0 + j]);
  }
  if (tid < 64) gam[(size_t)task * 64 + tid] = lgam[tid];
  __syncthreads();
  // Neumann doubling: T = Π (I + L^{2^k})
  float (*Lp)[68] = bufs[0];
  float (*Tm)[68] = bufs[2];
  float (*Fr)[68] = bufs[1];
  for (int it = 0; it < 5; ++it) {
    // Fr = Lp @ Lp
    {
      float acc[4][4] = {};
      for (int d = 0; d < 64; d += 4) {
        const float4 bv0 = *(const float4*)&Lp[d + 0][c4];
        const float4 bv1 = *(const float4*)&Lp[d + 1][c4];
        const float4 bv2 = *(const float4*)&Lp[d + 2][c4];
        const float4 bv3 = *(const float4*)&Lp[d + 3][c4];
#pragma unroll
        for (int j = 0; j < 4; ++j) {
          const float4 a = *(const float4*)&Lp[r4 + j][d];
          acc[j][0] += a.x * bv0.x + a.y * bv1.x + a.z * bv2.x + a.w * bv3.x;
          acc[j][1] += a.x * bv0.y + a.y * bv1.y + a.z * bv2.y + a.w * bv3.y;
          acc[j][2] += a.x * bv0.z + a.y * bv1.z + a.z * bv2.z + a.w * bv3.z;
          acc[j][3] += a.x * bv0.w + a.y * bv1.w + a.z * bv2.w + a.w * bv3.w;
        }
      }
#pragma unroll
      for (int j = 0; j < 4; ++j)
        *(float4*)&Fr[r4 + j][c4] = make_float4(acc[j][0], acc[j][1], acc[j][2], acc[j][3]);
    }
    __syncthreads();
    // dst(old Lp buf) = Tm + Tm @ Fr
    {
      float acc[4][4] = {};
      for (int d = 0; d < 64; d += 4) {
        const float4 bv0 = *(const float4*)&Fr[d + 0][c4];
        const float4 bv1 = *(const float4*)&Fr[d + 1][c4];
        const float4 bv2 = *(const float4*)&Fr[d + 2][c4];
        const float4 bv3 = *(const float4*)&Fr[d + 3][c4];
#pragma unroll
        for (int j = 0; j < 4; ++j) {
          const float4 a = *(const float4*)&Tm[r4 + j][d];
          acc[j][0] += a.x * bv0.x + a.y * bv1.x + a.z * bv2.x + a.w * bv3.x;
          acc[j][1] += a.x * bv0.y + a.y * bv1.y + a.z * bv2.y + a.w * bv3.y;
          acc[j][2] += a.x * bv0.z + a.y * bv1.z + a.z * bv2.z + a.w * bv3.z;
          acc[j][3] += a.x * bv0.w + a.y * bv1.w + a.z * bv2.w + a.w * bv3.w;
        }
      }
#pragma unroll
      for (int j = 0; j < 4; ++j) {
        const float4 told = *(const float4*)&Tm[r4 + j][c4];
        *(float4*)&Lp[r4 + j][c4] = make_float4(
            told.x + acc[j][0], told.y + acc[j][1],
            told.z + acc[j][2], told.w + acc[j][3]);
      }
    }
    __syncthreads();
    float (*oldT)[68] = Tm;
    Tm = Lp;      // new T lives in old Lp buffer
    Lp = Fr;      // new L-power
    Fr = oldT;    // old T buffer is free
  }
  // u = T @ (βV), two 64-col halves, in place over v
  for (int hv = 0; hv < 2; ++hv) {
    float acc[4][4] = {};
    for (int d = 0; d < 64; d += 4) {
      float4 bv[4];
#pragma unroll
      for (int s = 0; s < 4; ++s) {
        const float sc = lbeta[d + s];
        float4 x = *(const float4*)(v + (((size_t)b * T_ + t0 + d + s) * H_ + h) * DV_ + hv * 64 + c4);
        x.x *= sc; x.y *= sc; x.z *= sc; x.w *= sc;
        bv[s] = x;
      }
#pragma unroll
      for (int j = 0; j < 4; ++j) {
        const float4 a = *(const float4*)&Tm[r4 + j][d];
        acc[j][0] += a.x * bv[0].x + a.y * bv[1].x + a.z * bv[2].x + a.w * bv[3].x;
        acc[j][1] += a.x * bv[0].y + a.y * bv[1].y + a.z * bv[2].y + a.w * bv[3].y;
        acc[j][2] += a.x * bv[0].z + a.y * bv[1].z + a.z * bv[2].z + a.w * bv[3].z;
        acc[j][3] += a.x * bv[0].w + a.y * bv[1].w + a.z * bv[2].w + a.w * bv[3].w;
      }
    }
    __syncthreads();  // all reads of this v-half done before any overwrite
#pragma unroll
    for (int j = 0; j < 4; ++j)
      *(float4*)(v + (((size_t)b * T_ + t0 + r4 + j) * H_ + h) * DV_ + hv * 64 + c4) =
          make_float4(acc[j][0], acc[j][1], acc[j][2], acc[j][3]);
  }
  // W = T @ (β γ K) (B operand from LDS lk), in place over k
  {
    float acc[4][4] = {};
    for (int d = 0; d < 64; d += 4) {
      float4 bv[4];
#pragma unroll
      for (int s = 0; s < 4; ++s) {
        const float sc = lbg[d + s];
        float4 x = *(const float4*)&lk[d + s][c4];
        x.x *= sc; x.y *= sc; x.z *= sc; x.w *= sc;
        bv[s] = x;
      }
#pragma unroll
      for (int j = 0; j < 4; ++j) {
        const float4 a = *(const float4*)&Tm[r4 + j][d];
        acc[j][0] += a.x * bv[0].x + a.y * bv[1].x + a.z * bv[2].x + a.w * bv[3].x;
        acc[j][1] += a.x * bv[0].y + a.y * bv[1].y + a.z * bv[2].y + a.w * bv[3].y;
        acc[j][2] += a.x * bv[0].z + a.y * bv[1].z + a.z * bv[2].z + a.w * bv[3].z;
        acc[j][3] += a.x * bv[0].w + a.y * bv[1].w + a.z * bv[2].w + a.w * bv[3].w;
      }
    }
#pragma unroll
    for (int j = 0; j < 4; ++j)
      *(float4*)(k + (((size_t)b * T_ + t0 + r4 + j) * H_ + h) * DK_ + c4) =
          make_float4(acc[j][0], acc[j][1], acc[j][2], acc[j][3]);
  }
}

// ---------------------------------------------------------------------------
// Chunked gated delta rule, phase B (sequential over chunks).
__global__ __launch_bounds__(256) void chunk_scan_k(
    const float* __restrict__ q, const float* __restrict__ W,
    const float* __restrict__ u, const float* __restrict__ qkd,
    const float* __restrict__ kdt, const float* __restrict__ gam,
    float* __restrict__ o) {
  const int bh = blockIdx.x >> 2, cgp = blockIdx.x & 3;
  const int b = bh >> 4, h = bh & 15;
  const int tid = threadIdx.x;
  __shared__ float STG[128][68];   // staged [128x64] operand (padded)
  __shared__ float St[32][68];     // S transposed: St[c][dk]
  __shared__ float Ubt[32][68];    // Û transposed: Ubt[c][t]
  __shared__ float lgam[64];
  for (int i = tid; i < 32 * 68; i += 256) { (&St[0][0])[i] = 0.f; }
  const int c4 = (tid & 7) * 4;
  const int rg = tid >> 3;
  const int r4 = rg * 4;
  const int srow = tid >> 1, shalf = tid & 1;
  float Preg[4][4];
  for (int n = 0; n < NCH; ++n) {
    const int task = bh * NCH + n;
    const int t0 = n * C_;
    __syncthreads();
    if (tid < 64) lgam[tid] = gam[(size_t)task * 64 + tid];
    __syncthreads();
    // stage WQ: rows 0..63 = γ_t q_t, rows 64..127 = W
    {
      float scale = 1.f;
      const float* src;
      if (srow < 64) { src = q + (((size_t)b * T_ + t0 + srow) * H_ + h) * DK_; scale = lgam[srow]; }
      else           { src = W + (((size_t)b * T_ + t0 + srow - 64) * H_ + h) * DK_; }
      const float* s2 = src + shalf * 32;
      float* dst = &STG[srow][shalf * 32];
#pragma unroll
      for (int i = 0; i < 8; ++i) {
        float4 x = ((const float4*)s2)[i];
        x.x *= scale; x.y *= scale; x.z *= scale; x.w *= scale;
        ((float4*)dst)[i] = x;
      }
    }
    __syncthreads();
    // phase 1: acc = STG[r4..][:] @ S[:, c4..]
    {
      float acc[4][4] = {};
      for (int d = 0; d < 64; d += 4) {
        float4 wv[4], sv[4];
#pragma unroll
        for (int j = 0; j < 4; ++j) wv[j] = *(const float4*)&STG[r4 + j][d];
#pragma unroll
        for (int i = 0; i < 4; ++i) sv[i] = *(const float4*)&St[c4 + i][d];
#pragma unroll
        for (int j = 0; j < 4; ++j)
#pragma unroll
          for (int i = 0; i < 4; ++i)
            acc[j][i] += wv[j].x * sv[i].x + wv[j].y * sv[i].y + wv[j].z * sv[i].z + wv[j].w * sv[i].w;
      }
      if (rg < 16) {
#pragma unroll
        for (int j = 0; j < 4; ++j)
#pragma unroll
          for (int i = 0; i < 4; ++i) Preg[j][i] = acc[j][i];
      } else {
#pragma unroll
        for (int j = 0; j < 4; ++j) {
          const int t = r4 + j - 64;
          const size_t ubase = (((size_t)b * T_ + t0 + t) * H_ + h) * DV_ + cgp * 32;
#pragma unroll
          for (int i = 0; i < 4; ++i)
            Ubt[c4 + i][t] = u[ubase + c4 + i] - acc[j][i];
        }
      }
    }
    __syncthreads();
    // stage KK: rows 0..63 = QKd, rows 64..127 = KdT
    {
      const float* src = (srow < 64)
          ? qkd + (size_t)task * 4096 + srow * 64
          : kdt + (size_t)task * 4096 + (srow - 64) * 64;
      const float* s2 = src + shalf * 32;
      float* dst = &STG[srow][shalf * 32];
#pragma unroll
      for (int i = 0; i < 8; ++i) ((float4*)dst)[i] = ((const float4*)s2)[i];
    }
    __syncthreads();
    // phase 2: acc2 = STG[r4..][:] @ Û[:, c4..]
    {
      float acc2[4][4] = {};
      for (int s = 0; s < 64; s += 4) {
        float4 kv[4], uv[4];
#pragma unroll
        for (int j = 0; j < 4; ++j) kv[j] = *(const float4*)&STG[r4 + j][s];
#pragma unroll
        for (int i = 0; i < 4; ++i) uv[i] = *(const float4*)&Ubt[c4 + i][s];
#pragma unroll
        for (int j = 0; j < 4; ++j)
#pragma unroll
          for (int i = 0; i < 4; ++i)
            acc2[j][i] += kv[j].x * uv[i].x + kv[j].y * uv[i].y + kv[j].z * uv[i].z + kv[j].w * uv[i].w;
      }
      if (rg < 16) {
#pragma unroll
        for (int j = 0; j < 4; ++j) {
          const int t = r4 + j;
          const size_t obase = (((size_t)b * T_ + t0 + t) * H_ + h) * DV_ + cgp * 32;
#pragma unroll
          for (int i = 0; i < 4; ++i)
            o[obase + c4 + i] = Preg[j][i] + acc2[j][i];
        }
      } else {
        const float gC = lgam[63];
#pragma unroll
        for (int j = 0; j < 4; ++j) {
          const int dk = r4 + j - 64;
#pragma unroll
          for (int i = 0; i < 4; ++i)
            St[c4 + i][dk] = gC * St[c4 + i][dk] + acc2[j][i];
        }
      }
    }
  }
}

// ---------------------------------------------------------------------------
__global__ __launch_bounds__(128) void gatenorm_k(
    const float* __restrict__ o, const float* __restrict__ onw,
    const float* __restrict__ gate, float* __restrict__ go) {
  const size_t row = blockIdx.x;
  const int i = threadIdx.x;
  const float x = o[row * DV_ + i];
  float ss = x * x;
  for (int off = 32; off > 0; off >>= 1) ss += __shfl_xor(ss, off, 64);
  __shared__ float w2[2];
  if ((i & 63) == 0) w2[i >> 6] = ss;
  __syncthreads();
  const float r = rsqrtf((w2[0] + w2[1]) / (float)DV_ + 1e-5f);
  const float gg = gate[row * DV_ + i];
  go[row * DV_ + i] = x * r * onw[i] * gg * (1.f / (1.f + __expf(-gg)));
}

// ---------------------------------------------------------------------------
__global__ void silumul_k(const float4* a1, const float4* a3, float4* outp, int n4) {
  const int i = blockIdx.x * blockDim.x + threadIdx.x;
  if (i >= n4) return;
  const float4 a = a1[i], c = a3[i];
  float4 r;
  r.x = a.x * (1.f / (1.f + __expf(-a.x))) * c.x;
  r.y = a.y * (1.f / (1.f + __expf(-a.y))) * c.y;
  r.z = a.z * (1.f / (1.f + __expf(-a.z))) * c.z;
  r.w = a.w * (1.f / (1.f + __expf(-a.w))) * c.w;
  outp[i] = r;
}

// ---------------------------------------------------------------------------
extern "C" void kernel_launch(void* const* d_in, const int* in_sizes, int n_in,
                              void* d_out, int out_size, void* d_ws, size_t ws_size,
                              hipStream_t stream) {
  const float* x    = (const float*)d_in[0];
  const float* n1w  = (const float*)d_in[1];
  const float* n2w  = (const float*)d_in[2];
  const float* Wq   = (const float*)d_in[3];
  const float* Wk   = (const float*)d_in[4];
  const float* Wv   = (const float*)d_in[5];
  const float* cq   = (const float*)d_in[6];
  const float* ck   = (const float*)d_in[7];
  const float* cv   = (const float*)d_in[8];
  const float* Wa   = (const float*)d_in[9];
  const float* Wb   = (const float*)d_in[10];
  const float* dtb  = (const float*)d_in[11];
  const float* Alog = (const float*)d_in[12];
  const float* Wg   = (const float*)d_in[13];
  const float* onw  = (const float*)d_in[14];
  const float* Wo   = (const float*)d_in[15];
  const float* W1   = (const float*)d_in[16];
  const float* W3   = (const float*)d_in[17];
  const float* W2   = (const float*)d_in[18];
  float* out = (float*)d_out;
  float* ws  = (float*)d_ws;

  const size_t SZ_MD = (size_t)M_ * D_;          // 2M floats
  const size_t SZ_MV = (size_t)M_ * H_ * DV_;    // 4M floats
  float* h    = ws;                               // [0,2M)
  float* pq   = ws + SZ_MD;                       // [2M,4M)   later: QKd, then y1
  float* pk   = ws + 2 * SZ_MD;                   // [4M,6M)   later: KdT, then h2
  float* pv   = ws + 3 * SZ_MD;                   // [6M,10M)  later: o, then a1
  float* gate = ws + 3 * SZ_MD + SZ_MV;           // [10M,14M)
  float* qb   = ws + 3 * SZ_MD + 2 * SZ_MV;       // [14M,16M) later: a3
  float* kb   = ws + 4 * SZ_MD + 2 * SZ_MV;       // [16M,18M) in-place W
  float* vb   = ws + 5 * SZ_MD + 2 * SZ_MV;       // [18M,22M) in-place u, then go
  float* ob   = pv;
  float* go   = vb;
  float* y1   = pq;
  float* h2   = pk;
  float* a1   = pv;
  float* a3   = qb;
  float* smalls = ws + 5 * SZ_MD + 3 * SZ_MV;     // 22M
  float* pa  = smalls;
  float* pb  = pa + (size_t)M_ * H_;
  float* gv  = pb + (size_t)M_ * H_;
  float* bv  = gv + (size_t)M_ * H_;
  float* gam = bv + (size_t)M_ * H_;              // 512*64 floats

  const dim3 blk256(256);

  rmsnorm_k<<<dim3(M_), blk256, 0, stream>>>(x, n1w, h, D_, 1e-6f);
  gemm_k<<<dim3(D_ / BN, M_ / BM), blk256, 0, stream>>>(h, Wq, (const float*)nullptr, pq, M_, D_, D_);
  gemm_k<<<dim3(D_ / BN, M_ / BM), blk256, 0, stream>>>(h, Wk, (const float*)nullptr, pk, M_, D_, D_);
  gemm_k<<<dim3((H_ * DV_) / BN, M_ / BM), blk256, 0, stream>>>(h, Wv, (const float*)nullptr, pv, M_, H_ * DV_, D_);
  gemm_k<<<dim3((H_ * DV_) / BN, M_ / BM), blk256, 0, stream>>>(h, Wg, (const float*)nullptr, gate, M_, H_ * DV_, D_);
  skinny_k<<<dim3(M_), blk256, 0, stream>>>(h, Wa, Wb, pa, pb, D_);
  conv_silu_k<<<dim3(M_), blk256, 0, stream>>>(pq, cq, qb, H_ * DK_);
  conv_silu_k<<<dim3(M_), blk256, 0, stream>>>(pk, ck, kb, H_ * DK_);
  conv_silu_k<<<dim3(M_), blk256, 0, stream>>>(pv, cv, vb, H_ * DV_);
  beta_g_k<<<dim3((M_ * H_ + 255) / 256), blk256, 0, stream>>>(pa, pb, dtb, Alog, gv, bv, M_ * H_);
  l2norm_k<<<dim3(M_ * H_), dim3(64), 0, stream>>>(qb, 0.125f);
  l2norm_k<<<dim3(M_ * H_), dim3(64), 0, stream>>>(kb, 1.0f);
  chunk_prep_k<<<dim3(32 * NCH), blk256, 0, stream>>>(qb, kb, vb, gv, bv, pq, pk, gam);
  chunk_scan_k<<<dim3(32 * 4), blk256, 0, stream>>>(qb, kb, vb, pq, pk, gam, ob);
  gatenorm_k<<<dim3(M_ * H_), dim3(128), 0, stream>>>(ob, onw, gate, go);
  gemm_k<<<dim3(D_ / BN, M_ / BM), blk256, 0, stream>>>(go, Wo, x, y1, M_, D_, H_ * DV_);
  rmsnorm_k<<<dim3(M_), blk256, 0, stream>>>(y1, n2w, h2, D_, 1e-6f);
  gemm_k<<<dim3(FH_ / BN, M_ / BM), blk256, 0, stream>>>(h2, W1, (const float*)nullptr, a1, M_, FH_, D_);
  gemm_k<<<dim3(FH_ / BN, M_ / BM), blk256, 0, stream>>>(h2, W3, (const float*)nullptr, a3, M_, FH_, D_);
  const int n4 = (M_ * FH_) / 4;
  silumul_k<<<dim3((n4 + 255) / 256), blk256, 0, stream>>>((const float4*)a1, (const float4*)a3, (float4*)a1, n4);
  gemm_k<<<dim3(D_ / BN, M_ / BM), blk256, 0, stream>>>(a1, W2, y1, out, M_, D_, FH_);
}

// Round 5
// 901.865 us; speedup vs baseline: 2.8599x; 1.7025x over previous
//
#include <hip/hip_runtime.h>
#include <hip/hip_bf16.h>
#include <math.h>

// Problem constants
#define B_  2
#define T_  1024
#define D_  1024
#define H_  16
#define DK_ 64
#define DV_ 128
#define FH_ 2816
#define M_  (B_ * T_)   // 2048 tokens
#define C_  64          // chunk length
#define NCH (T_ / C_)   // 16 chunks

typedef __attribute__((ext_vector_type(8))) short bf16x8;
typedef __attribute__((ext_vector_type(4))) float f32x4;

// ---------------------------------------------------------------------------
// rmsnorm with fp32 and/or bf16 outputs (either may be null)
__global__ __launch_bounds__(256) void rmsnorm_k(
    const float* __restrict__ x, const float* __restrict__ w,
    float* __restrict__ outf, __hip_bfloat16* __restrict__ outb,
    int D, float eps) {
  const int row = blockIdx.x;
  const float* xr = x + (size_t)row * D;
  float ss = 0.f;
  for (int i = threadIdx.x; i < D; i += blockDim.x) { float v = xr[i]; ss += v * v; }
  for (int off = 32; off > 0; off >>= 1) ss += __shfl_xor(ss, off, 64);
  __shared__ float wsum[4];
  __shared__ float s_scale;
  const int lane = threadIdx.x & 63, wid = threadIdx.x >> 6;
  if (lane == 0) wsum[wid] = ss;
  __syncthreads();
  if (threadIdx.x == 0) {
    float tot = 0.f;
    const int nw = blockDim.x >> 6;
    for (int i = 0; i < nw; ++i) tot += wsum[i];
    s_scale = rsqrtf(tot / (float)D + eps);
  }
  __syncthreads();
  const float sc = s_scale;
  for (int i = threadIdx.x; i < D; i += blockDim.x) {
    const float v = xr[i] * sc * w[i];
    if (outf) outf[(size_t)row * D + i] = v;
    if (outb) outb[(size_t)row * D + i] = __float2bfloat16(v);
  }
}

// ---------------------------------------------------------------------------
// Tiled transpose + fp32->bf16 convert: W[K,N] -> Wt[N,K]
__global__ __launch_bounds__(256) void transpose_bf16_k(
    const float* __restrict__ W, __hip_bfloat16* __restrict__ Wt, int K, int N) {
  __shared__ float t[32][33];
  const int k0 = blockIdx.y * 32, n0 = blockIdx.x * 32;
  const int c = threadIdx.x & 31, r = threadIdx.x >> 5;  // r in 0..7
#pragma unroll
  for (int i = 0; i < 4; ++i)
    t[r + 8 * i][c] = W[(size_t)(k0 + r + 8 * i) * N + n0 + c];
  __syncthreads();
#pragma unroll
  for (int i = 0; i < 4; ++i)
    Wt[(size_t)(n0 + r + 8 * i) * K + k0 + c] = __float2bfloat16(t[c][r + 8 * i]);
}

// ---------------------------------------------------------------------------
__device__ __forceinline__ void gload_lds16(const void* g, void* l) {
  __builtin_amdgcn_global_load_lds(
      (const __attribute__((address_space(1))) void*)g,
      (__attribute__((address_space(3))) void*)l, 16, 0, 0);
}

// bf16 MFMA GEMM (m97 structure): C[M,N] = A[M,K] @ Bt[N,K]^T.
// 128x128 tile, BK=32, 256 threads = 4 waves (2x2 of 64x64), 16x16x32 MFMA.
// mode 0: C = acc (fp32); mode 1: C = acc + res (fp32);
// mode 2: Cbf16 = silu(res) * acc   (fused SwiGLU epilogue)
__global__ __launch_bounds__(256) void mfma_gemm_k(
    const __hip_bfloat16* __restrict__ A, const __hip_bfloat16* __restrict__ Bt,
    const float* __restrict__ res, void* __restrict__ Cout,
    int M, int N, int K, int mode) {
  __shared__ __hip_bfloat16 As[128 * 32];
  __shared__ __hip_bfloat16 Bs[128 * 32];
  const int tid = threadIdx.x;
  const int lane = tid & 63;
  const int wv = tid >> 6;
  const int wm = (wv >> 1) * 64, wn = (wv & 1) * 64;
  const int bm = blockIdx.y * 128, bn = blockIdx.x * 128;
  const int l15 = lane & 15, lq8 = (lane >> 4) * 8;
  const int ar = tid >> 2;           // staging row 0..63 (+64 second issue)
  const int ac = (tid & 3) * 8;      // staging k-offset 0/8/16/24
  const size_t Abase = (size_t)(bm + ar) * K + ac;
  const size_t Bbase = (size_t)(bn + ar) * K + ac;
  f32x4 acc[4][4];
#pragma unroll
  for (int i = 0; i < 4; ++i)
#pragma unroll
    for (int j = 0; j < 4; ++j) acc[i][j] = (f32x4){0.f, 0.f, 0.f, 0.f};
  for (int k0 = 0; k0 < K; k0 += 32) {
    gload_lds16(A + Abase + k0, (char*)As + tid * 16);
    gload_lds16(A + Abase + (size_t)64 * K + k0, (char*)As + tid * 16 + 4096);
    gload_lds16(Bt + Bbase + k0, (char*)Bs + tid * 16);
    gload_lds16(Bt + Bbase + (size_t)64 * K + k0, (char*)Bs + tid * 16 + 4096);
    __syncthreads();
    bf16x8 af[4], bfr[4];
#pragma unroll
    for (int i = 0; i < 4; ++i)
      af[i] = *(const bf16x8*)(As + (wm + i * 16 + l15) * 32 + lq8);
#pragma unroll
    for (int j = 0; j < 4; ++j)
      bfr[j] = *(const bf16x8*)(Bs + (wn + j * 16 + l15) * 32 + lq8);
#pragma unroll
    for (int i = 0; i < 4; ++i)
#pragma unroll
      for (int j = 0; j < 4; ++j)
        acc[i][j] = __builtin_amdgcn_mfma_f32_16x16x32_bf16(af[i], bfr[j], acc[i][j], 0, 0, 0);
    __syncthreads();
  }
  const int r0 = (lane >> 4) * 4;   // C/D layout: col=lane&15, row=(lane>>4)*4+reg
#pragma unroll
  for (int i = 0; i < 4; ++i) {
#pragma unroll
    for (int j = 0; j < 4; ++j) {
      const int row = bm + wm + i * 16 + r0;
      const int col = bn + wn + j * 16 + l15;
#pragma unroll
      for (int r = 0; r < 4; ++r) {
        const size_t idx = (size_t)(row + r) * N + col;
        const float a = acc[i][j][r];
        if (mode == 0) ((float*)Cout)[idx] = a;
        else if (mode == 1) ((float*)Cout)[idx] = a + res[idx];
        else {
          const float s = res[idx];
          ((__hip_bfloat16*)Cout)[idx] =
              __float2bfloat16(s * (1.f / (1.f + __expf(-s))) * a);
        }
      }
    }
  }
}

// ---------------------------------------------------------------------------
__global__ __launch_bounds__(256) void skinny_k(
    const float* __restrict__ h, const float* __restrict__ Wa,
    const float* __restrict__ Wb, float* __restrict__ pa,
    float* __restrict__ pb, int K) {
  __shared__ float hl[D_];
  const int row = blockIdx.x;
  for (int i = threadIdx.x; i < K; i += blockDim.x) hl[i] = h[(size_t)row * K + i];
  __syncthreads();
  const int t = threadIdx.x;
  if (t < 32) {
    const float* W = (t < 16) ? Wa : Wb;
    const int col = t & 15;
    float s = 0.f;
    for (int k = 0; k < K; ++k) s += hl[k] * W[k * H_ + col];
    if (t < 16) pa[(size_t)row * H_ + col] = s;
    else        pb[(size_t)row * H_ + col] = s;
  }
}

// ---------------------------------------------------------------------------
__global__ __launch_bounds__(256) void conv_silu_k(
    const float* __restrict__ src, const float* __restrict__ w,
    float* __restrict__ dst, int C) {
  const int bt = blockIdx.x;
  const int b = bt / T_, t = bt % T_;
  const float* s = src + (size_t)b * T_ * C;
  for (int c = threadIdx.x; c < C; c += blockDim.x) {
    const float w0 = w[c * 4 + 0], w1 = w[c * 4 + 1],
                w2 = w[c * 4 + 2], w3 = w[c * 4 + 3];
    float acc = s[(size_t)t * C + c] * w3;
    if (t >= 1) acc += s[(size_t)(t - 1) * C + c] * w2;
    if (t >= 2) acc += s[(size_t)(t - 2) * C + c] * w1;
    if (t >= 3) acc += s[(size_t)(t - 3) * C + c] * w0;
    dst[(size_t)bt * C + c] = acc * (1.f / (1.f + __expf(-acc)));
  }
}

// ---------------------------------------------------------------------------
__global__ void beta_g_k(const float* __restrict__ pa, const float* __restrict__ pb,
                         const float* __restrict__ dtb, const float* __restrict__ Alog,
                         float* __restrict__ g, float* __restrict__ beta, int n) {
  const int i = blockIdx.x * blockDim.x + threadIdx.x;
  if (i >= n) return;
  const int h = i & (H_ - 1);
  const float xx = pa[i] + dtb[h];
  const float sp = (xx > 20.f) ? xx : log1pf(expf(xx));
  g[i] = -expf(Alog[h]) * sp;
  beta[i] = 1.f / (1.f + expf(-pb[i]));
}

// ---------------------------------------------------------------------------
__global__ __launch_bounds__(64) void l2norm_k(float* __restrict__ q, float scale) {
  const size_t row = blockIdx.x;
  const int lane = threadIdx.x;
  const float v = q[row * 64 + lane];
  float ss = v * v;
  for (int off = 32; off > 0; off >>= 1) ss += __shfl_xor(ss, off, 64);
  q[row * 64 + lane] = v * rsqrtf(ss + 1e-6f) * scale;
}

// ---------------------------------------------------------------------------
// Chunked gated delta rule, phase A (unchanged from round 4 — 512 tasks,
// Neumann-doubling triangular inverse, no spills).
__global__ __launch_bounds__(256) void chunk_prep_k(
    const float* __restrict__ q, float* __restrict__ k, float* __restrict__ v,
    const float* __restrict__ g, const float* __restrict__ beta,
    float* __restrict__ qkd, float* __restrict__ kdt, float* __restrict__ gam) {
  const int task = blockIdx.x;
  const int bh = task >> 4, n = task & (NCH - 1);
  const int b = bh >> 4, h = bh & 15;
  const int t0 = n * C_;
  const int tid = threadIdx.x;
  __shared__ float lk[C_][68];
  __shared__ float bufs[3][C_][68];
  __shared__ float lb[C_], lgam[C_], lbeta[C_], lbg[C_];
  {
    const int r = tid >> 2, cq = (tid & 3) * 16;
    const float* src = k + (((size_t)b * T_ + t0 + r) * H_ + h) * DK_ + cq;
#pragma unroll
    for (int i = 0; i < 4; ++i)
      *(float4*)&lk[r][cq + 4 * i] = ((const float4*)src)[i];
  }
  if (tid < 64) {
    const size_t gi = ((size_t)b * T_ + t0 + tid) * H_ + h;
    float xx = g[gi];
    const float bb = beta[gi];
    lbeta[tid] = bb;
#pragma unroll
    for (int off = 1; off < 64; off <<= 1) {
      float y = __shfl_up(xx, off, 64);
      if (tid >= off) xx += y;
    }
    lb[tid] = xx;
    const float gm = __expf(xx);
    lgam[tid] = gm;
    lbg[tid] = bb * gm;
  }
  __syncthreads();
  const int r4 = (tid >> 4) * 4;
  const int sl = tid & 15;
  const int c4 = sl * 4;
  {
    const float* qg = q + (((size_t)b * T_ + t0) * H_ + h) * DK_;
    float accA[4][4] = {};
    float accQ[4][4] = {};
    for (int d = 0; d < 64; d += 4) {
      float4 kt[4], ks[4], qt[4];
#pragma unroll
      for (int i = 0; i < 4; ++i) kt[i] = *(const float4*)&lk[r4 + i][d];
#pragma unroll
      for (int j = 0; j < 4; ++j) ks[j] = *(const float4*)&lk[sl + 16 * j][d];
#pragma unroll
      for (int i = 0; i < 4; ++i) qt[i] = *(const float4*)(qg + (size_t)(r4 + i) * (H_ * DK_) + d);
#pragma unroll
      for (int i = 0; i < 4; ++i)
#pragma unroll
        for (int j = 0; j < 4; ++j) {
          accA[i][j] += kt[i].x * ks[j].x + kt[i].y * ks[j].y + kt[i].z * ks[j].z + kt[i].w * ks[j].w;
          accQ[i][j] += qt[i].x * ks[j].x + qt[i].y * ks[j].y + qt[i].z * ks[j].z + qt[i].w * ks[j].w;
        }
    }
    float (*L0)[68] = bufs[0];
    float (*T0)[68] = bufs[2];
    float* qo = qkd + (size_t)task * 4096;
#pragma unroll
    for (int i = 0; i < 4; ++i)
#pragma unroll
      for (int j = 0; j < 4; ++j) {
        const int t = r4 + i, s = sl + 16 * j;
        const float dec = (s <= t) ? __expf(lb[t] - lb[s]) : 0.f;
        const float Lts = (t > s) ? -(lbeta[t] * accA[i][j] * dec) : 0.f;
        L0[t][s] = Lts;
        T0[t][s] = (t == s) ? 1.f : Lts;
        qo[t * 64 + s] = accQ[i][j] * dec;
      }
  }
  {
    const int dk = tid >> 2, s0 = (tid & 3) * 16;
    const float bC = lb[63];
    float* dst = kdt + (size_t)task * 4096 + dk * 64 + s0;
#pragma unroll
    for (int j = 0; j < 16; ++j)
      dst[j] = lk[s0 + j][dk] * __expf(bC - lb[s0 + j]);
  }
  if (tid < 64) gam[(size_t)task * 64 + tid] = lgam[tid];
  __syncthreads();
  float (*Lp)[68] = bufs[0];
  float (*Tm)[68] = bufs[2];
  float (*Fr)[68] = bufs[1];
  for (int it = 0; it < 5; ++it) {
    {
      float acc[4][4] = {};
      for (int d = 0; d < 64; d += 4) {
        const float4 bv0 = *(const float4*)&Lp[d + 0][c4];
        const float4 bv1 = *(const float4*)&Lp[d + 1][c4];
        const float4 bv2 = *(const float4*)&Lp[d + 2][c4];
        const float4 bv3 = *(const float4*)&Lp[d + 3][c4];
#pragma unroll
        for (int j = 0; j < 4; ++j) {
          const float4 a = *(const float4*)&Lp[r4 + j][d];
          acc[j][0] += a.x * bv0.x + a.y * bv1.x + a.z * bv2.x + a.w * bv3.x;
          acc[j][1] += a.x * bv0.y + a.y * bv1.y + a.z * bv2.y + a.w * bv3.y;
          acc[j][2] += a.x * bv0.z + a.y * bv1.z + a.z * bv2.z + a.w * bv3.z;
          acc[j][3] += a.x * bv0.w + a.y * bv1.w + a.z * bv2.w + a.w * bv3.w;
        }
      }
#pragma unroll
      for (int j = 0; j < 4; ++j)
        *(float4*)&Fr[r4 + j][c4] = make_float4(acc[j][0], acc[j][1], acc[j][2], acc[j][3]);
    }
    __syncthreads();
    {
      float acc[4][4] = {};
      for (int d = 0; d < 64; d += 4) {
        const float4 bv0 = *(const float4*)&Fr[d + 0][c4];
        const float4 bv1 = *(const float4*)&Fr[d + 1][c4];
        const float4 bv2 = *(const float4*)&Fr[d + 2][c4];
        const float4 bv3 = *(const float4*)&Fr[d + 3][c4];
#pragma unroll
        for (int j = 0; j < 4; ++j) {
          const float4 a = *(const float4*)&Tm[r4 + j][d];
          acc[j][0] += a.x * bv0.x + a.y * bv1.x + a.z * bv2.x + a.w * bv3.x;
          acc[j][1] += a.x * bv0.y + a.y * bv1.y + a.z * bv2.y + a.w * bv3.y;
          acc[j][2] += a.x * bv0.z + a.y * bv1.z + a.z * bv2.z + a.w * bv3.z;
          acc[j][3] += a.x * bv0.w + a.y * bv1.w + a.z * bv2.w + a.w * bv3.w;
        }
      }
#pragma unroll
      for (int j = 0; j < 4; ++j) {
        const float4 told = *(const float4*)&Tm[r4 + j][c4];
        *(float4*)&Lp[r4 + j][c4] = make_float4(
            told.x + acc[j][0], told.y + acc[j][1],
            told.z + acc[j][2], told.w + acc[j][3]);
      }
    }
    __syncthreads();
    float (*oldT)[68] = Tm;
    Tm = Lp; Lp = Fr; Fr = oldT;
  }
  for (int hv = 0; hv < 2; ++hv) {
    float acc[4][4] = {};
    for (int d = 0; d < 64; d += 4) {
      float4 bv[4];
#pragma unroll
      for (int s = 0; s < 4; ++s) {
        const float sc = lbeta[d + s];
        float4 x = *(const float4*)(v + (((size_t)b * T_ + t0 + d + s) * H_ + h) * DV_ + hv * 64 + c4);
        x.x *= sc; x.y *= sc; x.z *= sc; x.w *= sc;
        bv[s] = x;
      }
#pragma unroll
      for (int j = 0; j < 4; ++j) {
        const float4 a = *(const float4*)&Tm[r4 + j][d];
        acc[j][0] += a.x * bv[0].x + a.y * bv[1].x + a.z * bv[2].x + a.w * bv[3].x;
        acc[j][1] += a.x * bv[0].y + a.y * bv[1].y + a.z * bv[2].y + a.w * bv[3].y;
        acc[j][2] += a.x * bv[0].z + a.y * bv[1].z + a.z * bv[2].z + a.w * bv[3].z;
        acc[j][3] += a.x * bv[0].w + a.y * bv[1].w + a.z * bv[2].w + a.w * bv[3].w;
      }
    }
    __syncthreads();
#pragma unroll
    for (int j = 0; j < 4; ++j)
      *(float4*)(v + (((size_t)b * T_ + t0 + r4 + j) * H_ + h) * DV_ + hv * 64 + c4) =
          make_float4(acc[j][0], acc[j][1], acc[j][2], acc[j][3]);
  }
  {
    float acc[4][4] = {};
    for (int d = 0; d < 64; d += 4) {
      float4 bv[4];
#pragma unroll
      for (int s = 0; s < 4; ++s) {
        const float sc = lbg[d + s];
        float4 x = *(const float4*)&lk[d + s][c4];
        x.x *= sc; x.y *= sc; x.z *= sc; x.w *= sc;
        bv[s] = x;
      }
#pragma unroll
      for (int j = 0; j < 4; ++j) {
        const float4 a = *(const float4*)&Tm[r4 + j][d];
        acc[j][0] += a.x * bv[0].x + a.y * bv[1].x + a.z * bv[2].x + a.w * bv[3].x;
        acc[j][1] += a.x * bv[0].y + a.y * bv[1].y + a.z * bv[2].y + a.w * bv[3].y;
        acc[j][2] += a.x * bv[0].z + a.y * bv[1].z + a.z * bv[2].z + a.w * bv[3].z;
        acc[j][3] += a.x * bv[0].w + a.y * bv[1].w + a.z * bv[2].w + a.w * bv[3].w;
      }
    }
#pragma unroll
    for (int j = 0; j < 4; ++j)
      *(float4*)(k + (((size_t)b * T_ + t0 + r4 + j) * H_ + h) * DK_ + c4) =
          make_float4(acc[j][0], acc[j][1], acc[j][2], acc[j][3]);
  }
}

// ---------------------------------------------------------------------------
// Chunked gated delta rule, phase B (unchanged from round 4).
__global__ __launch_bounds__(256) void chunk_scan_k(
    const float* __restrict__ q, const float* __restrict__ W,
    const float* __restrict__ u, const float* __restrict__ qkd,
    const float* __restrict__ kdt, const float* __restrict__ gam,
    float* __restrict__ o) {
  const int bh = blockIdx.x >> 2, cgp = blockIdx.x & 3;
  const int b = bh >> 4, h = bh & 15;
  const int tid = threadIdx.x;
  __shared__ float STG[128][68];
  __shared__ float St[32][68];
  __shared__ float Ubt[32][68];
  __shared__ float lgam[64];
  for (int i = tid; i < 32 * 68; i += 256) { (&St[0][0])[i] = 0.f; }
  const int c4 = (tid & 7) * 4;
  const int rg = tid >> 3;
  const int r4 = rg * 4;
  const int srow = tid >> 1, shalf = tid & 1;
  float Preg[4][4];
  for (int n = 0; n < NCH; ++n) {
    const int task = bh * NCH + n;
    const int t0 = n * C_;
    __syncthreads();
    if (tid < 64) lgam[tid] = gam[(size_t)task * 64 + tid];
    __syncthreads();
    {
      float scale = 1.f;
      const float* src;
      if (srow < 64) { src = q + (((size_t)b * T_ + t0 + srow) * H_ + h) * DK_; scale = lgam[srow]; }
      else           { src = W + (((size_t)b * T_ + t0 + srow - 64) * H_ + h) * DK_; }
      const float* s2 = src + shalf * 32;
      float* dst = &STG[srow][shalf * 32];
#pragma unroll
      for (int i = 0; i < 8; ++i) {
        float4 x = ((const float4*)s2)[i];
        x.x *= scale; x.y *= scale; x.z *= scale; x.w *= scale;
        ((float4*)dst)[i] = x;
      }
    }
    __syncthreads();
    {
      float acc[4][4] = {};
      for (int d = 0; d < 64; d += 4) {
        float4 wvv[4], sv[4];
#pragma unroll
        for (int j = 0; j < 4; ++j) wvv[j] = *(const float4*)&STG[r4 + j][d];
#pragma unroll
        for (int i = 0; i < 4; ++i) sv[i] = *(const float4*)&St[c4 + i][d];
#pragma unroll
        for (int j = 0; j < 4; ++j)
#pragma unroll
          for (int i = 0; i < 4; ++i)
            acc[j][i] += wvv[j].x * sv[i].x + wvv[j].y * sv[i].y + wvv[j].z * sv[i].z + wvv[j].w * sv[i].w;
      }
      if (rg < 16) {
#pragma unroll
        for (int j = 0; j < 4; ++j)
#pragma unroll
          for (int i = 0; i < 4; ++i) Preg[j][i] = acc[j][i];
      } else {
#pragma unroll
        for (int j = 0; j < 4; ++j) {
          const int t = r4 + j - 64;
          const size_t ubase = (((size_t)b * T_ + t0 + t) * H_ + h) * DV_ + cgp * 32;
#pragma unroll
          for (int i = 0; i < 4; ++i)
            Ubt[c4 + i][t] = u[ubase + c4 + i] - acc[j][i];
        }
      }
    }
    __syncthreads();
    {
      const float* src = (srow < 64)
          ? qkd + (size_t)task * 4096 + srow * 64
          : kdt + (size_t)task * 4096 + (srow - 64) * 64;
      const float* s2 = src + shalf * 32;
      float* dst = &STG[srow][shalf * 32];
#pragma unroll
      for (int i = 0; i < 8; ++i) ((float4*)dst)[i] = ((const float4*)s2)[i];
    }
    __syncthreads();
    {
      float acc2[4][4] = {};
      for (int s = 0; s < 64; s += 4) {
        float4 kv[4], uv[4];
#pragma unroll
        for (int j = 0; j < 4; ++j) kv[j] = *(const float4*)&STG[r4 + j][s];
#pragma unroll
        for (int i = 0; i < 4; ++i) uv[i] = *(const float4*)&Ubt[c4 + i][s];
#pragma unroll
        for (int j = 0; j < 4; ++j)
#pragma unroll
          for (int i = 0; i < 4; ++i)
            acc2[j][i] += kv[j].x * uv[i].x + kv[j].y * uv[i].y + kv[j].z * uv[i].z + kv[j].w * uv[i].w;
      }
      if (rg < 16) {
#pragma unroll
        for (int j = 0; j < 4; ++j) {
          const int t = r4 + j;
          const size_t obase = (((size_t)b * T_ + t0 + t) * H_ + h) * DV_ + cgp * 32;
#pragma unroll
          for (int i = 0; i < 4; ++i)
            o[obase + c4 + i] = Preg[j][i] + acc2[j][i];
        }
      } else {
        const float gC = lgam[63];
#pragma unroll
        for (int j = 0; j < 4; ++j) {
          const int dk = r4 + j - 64;
#pragma unroll
          for (int i = 0; i < 4; ++i)
            St[c4 + i][dk] = gC * St[c4 + i][dk] + acc2[j][i];
        }
      }
    }
  }
}

// ---------------------------------------------------------------------------
// go_bf16 = rmsnorm(o, onw, 1e-5) * silu(gate)
__global__ __launch_bounds__(128) void gatenorm_k(
    const float* __restrict__ o, const float* __restrict__ onw,
    const float* __restrict__ gate, __hip_bfloat16* __restrict__ go) {
  const size_t row = blockIdx.x;
  const int i = threadIdx.x;
  const float x = o[row * DV_ + i];
  float ss = x * x;
  for (int off = 32; off > 0; off >>= 1) ss += __shfl_xor(ss, off, 64);
  __shared__ float w2[2];
  if ((i & 63) == 0) w2[i >> 6] = ss;
  __syncthreads();
  const float r = rsqrtf((w2[0] + w2[1]) / (float)DV_ + 1e-5f);
  const float gg = gate[row * DV_ + i];
  go[row * DV_ + i] = __float2bfloat16(x * r * onw[i] * gg * (1.f / (1.f + __expf(-gg))));
}

// ---------------------------------------------------------------------------
extern "C" void kernel_launch(void* const* d_in, const int* in_sizes, int n_in,
                              void* d_out, int out_size, void* d_ws, size_t ws_size,
                              hipStream_t stream) {
  const float* x    = (const float*)d_in[0];
  const float* n1w  = (const float*)d_in[1];
  const float* n2w  = (const float*)d_in[2];
  const float* Wq   = (const float*)d_in[3];
  const float* Wk   = (const float*)d_in[4];
  const float* Wv   = (const float*)d_in[5];
  const float* cq   = (const float*)d_in[6];
  const float* ck   = (const float*)d_in[7];
  const float* cv   = (const float*)d_in[8];
  const float* Wa   = (const float*)d_in[9];
  const float* Wb   = (const float*)d_in[10];
  const float* dtb  = (const float*)d_in[11];
  const float* Alog = (const float*)d_in[12];
  const float* Wg   = (const float*)d_in[13];
  const float* onw  = (const float*)d_in[14];
  const float* Wo   = (const float*)d_in[15];
  const float* W1   = (const float*)d_in[16];
  const float* W3   = (const float*)d_in[17];
  const float* W2   = (const float*)d_in[18];
  float* out = (float*)d_out;
  float* ws  = (float*)d_ws;

  const size_t SZ_MD = (size_t)M_ * D_;          // 2M floats
  const size_t SZ_MV = (size_t)M_ * H_ * DV_;    // 4M floats
  // fp32 regions (same 88.6 MB footprint as round 4)
  float* h    = ws;                               // [0,2M)
  float* pq   = ws + SZ_MD;                       // [2M,4M)  -> QKd -> y1
  float* pk   = ws + 2 * SZ_MD;                   // [4M,6M)  -> KdT
  float* pv   = ws + 3 * SZ_MD;                   // [6M,10M) -> o -> a1 (spans into gate)
  float* gate = ws + 3 * SZ_MD + SZ_MV;           // [10M,14M)
  float* qb   = ws + 3 * SZ_MD + 2 * SZ_MV;       // [14M,16M)
  float* kb   = ws + 4 * SZ_MD + 2 * SZ_MV;       // [16M,18M) in-place W
  float* vb   = ws + 5 * SZ_MD + 2 * SZ_MV;       // [18M,22M) in-place u
  float* ob   = pv;
  float* y1   = pq;
  float* a1   = pv;                               // [6M,11.77M): pv+gate free then
  float* smalls = ws + 5 * SZ_MD + 3 * SZ_MV;     // 22M
  float* pa  = smalls;
  float* pb  = pa + (size_t)M_ * H_;
  float* gv  = pb + (size_t)M_ * H_;
  float* bv  = gv + (size_t)M_ * H_;
  float* gam = bv + (size_t)M_ * H_;
  // bf16 aliases (liveness-checked against the fp32 schedule):
  __hip_bfloat16* h_bf  = (__hip_bfloat16*)vb;   // dead before conv_v writes vb
  __hip_bfloat16* wb1   = (__hip_bfloat16*)kb;   // phase-1 weights; dead before conv_k
  __hip_bfloat16* wb2   = (__hip_bfloat16*)vb;   // phase-2 weights; vb dead after scan
  __hip_bfloat16* go_bf = (__hip_bfloat16*)h;    // h dead after projections+skinny
  __hip_bfloat16* h2_bf = (__hip_bfloat16*)h;    // go_bf dead after Wo GEMM
  __hip_bfloat16* a1b   = (__hip_bfloat16*)qb;   // qb dead after chunk_scan

  const dim3 blk256(256);
  const dim3 g_tr1024_1024(1024 / 32, 1024 / 32);
  const dim3 g_tr1024_2048(2048 / 32, 1024 / 32);
  const dim3 g_tr2048_1024(1024 / 32, 2048 / 32);
  const dim3 g_tr1024_2816(2816 / 32, 1024 / 32);
  const dim3 g_tr2816_1024(1024 / 32, 2816 / 32);

  // 1) h = rmsnorm(x) -> fp32 + bf16
  rmsnorm_k<<<dim3(M_), blk256, 0, stream>>>(x, n1w, h, h_bf, D_, 1e-6f);
  // 2) projections (bf16 MFMA; weights transposed+converted per use)
  transpose_bf16_k<<<g_tr1024_1024, blk256, 0, stream>>>(Wq, wb1, D_, 1024);
  mfma_gemm_k<<<dim3(1024 / 128, M_ / 128), blk256, 0, stream>>>(h_bf, wb1, nullptr, pq, M_, 1024, D_, 0);
  transpose_bf16_k<<<g_tr1024_1024, blk256, 0, stream>>>(Wk, wb1, D_, 1024);
  mfma_gemm_k<<<dim3(1024 / 128, M_ / 128), blk256, 0, stream>>>(h_bf, wb1, nullptr, pk, M_, 1024, D_, 0);
  transpose_bf16_k<<<g_tr1024_2048, blk256, 0, stream>>>(Wv, wb1, D_, 2048);
  mfma_gemm_k<<<dim3(2048 / 128, M_ / 128), blk256, 0, stream>>>(h_bf, wb1, nullptr, pv, M_, 2048, D_, 0);
  transpose_bf16_k<<<g_tr1024_2048, blk256, 0, stream>>>(Wg, wb1, D_, 2048);
  mfma_gemm_k<<<dim3(2048 / 128, M_ / 128), blk256, 0, stream>>>(h_bf, wb1, nullptr, gate, M_, 2048, D_, 0);
  skinny_k<<<dim3(M_), blk256, 0, stream>>>(h, Wa, Wb, pa, pb, D_);
  // 3) short conv + silu (fp32)
  conv_silu_k<<<dim3(M_), blk256, 0, stream>>>(pq, cq, qb, H_ * DK_);
  conv_silu_k<<<dim3(M_), blk256, 0, stream>>>(pk, ck, kb, H_ * DK_);
  conv_silu_k<<<dim3(M_), blk256, 0, stream>>>(pv, cv, vb, H_ * DV_);
  // 4) beta, g ; 5) l2norm
  beta_g_k<<<dim3((M_ * H_ + 255) / 256), blk256, 0, stream>>>(pa, pb, dtb, Alog, gv, bv, M_ * H_);
  l2norm_k<<<dim3(M_ * H_), dim3(64), 0, stream>>>(qb, 0.125f);
  l2norm_k<<<dim3(M_ * H_), dim3(64), 0, stream>>>(kb, 1.0f);
  // 6) chunked delta rule
  chunk_prep_k<<<dim3(32 * NCH), blk256, 0, stream>>>(qb, kb, vb, gv, bv, pq, pk, gam);
  chunk_scan_k<<<dim3(32 * 4), blk256, 0, stream>>>(qb, kb, vb, pq, pk, gam, ob);
  // 7) gated RMSNorm -> bf16
  gatenorm_k<<<dim3(M_ * H_), dim3(128), 0, stream>>>(ob, onw, gate, go_bf);
  // 8) y1 = x + go @ Wo
  transpose_bf16_k<<<g_tr2048_1024, blk256, 0, stream>>>(Wo, wb2, H_ * DV_, 1024);
  mfma_gemm_k<<<dim3(1024 / 128, M_ / 128), blk256, 0, stream>>>(go_bf, wb2, x, y1, M_, 1024, H_ * DV_, 1);
  // 9) h2 = rmsnorm(y1) -> bf16 only
  rmsnorm_k<<<dim3(M_), blk256, 0, stream>>>(y1, n2w, nullptr, h2_bf, D_, 1e-6f);
  // 10) FFN: a1 = h2@W1 ; a1b = silu(a1) * (h2@W3) fused into W3 epilogue
  transpose_bf16_k<<<g_tr1024_2816, blk256, 0, stream>>>(W1, wb2, D_, FH_);
  mfma_gemm_k<<<dim3(FH_ / 128, M_ / 128), blk256, 0, stream>>>(h2_bf, wb2, nullptr, a1, M_, FH_, D_, 0);
  transpose_bf16_k<<<g_tr1024_2816, blk256, 0, stream>>>(W3, wb2, D_, FH_);
  mfma_gemm_k<<<dim3(FH_ / 128, M_ / 128), blk256, 0, stream>>>(h2_bf, wb2, a1, a1b, M_, FH_, D_, 2);
  // 11) out = y1 + a1b @ W2
  transpose_bf16_k<<<g_tr2816_1024, blk256, 0, stream>>>(W2, wb2, FH_, 1024);
  mfma_gemm_k<<<dim3(1024 / 128, M_ / 128), blk256, 0, stream>>>(a1b, wb2, y1, out, M_, 1024, FH_, 1);
}

// Round 6
// 837.612 us; speedup vs baseline: 3.0792x; 1.0767x over previous
//
#include <hip/hip_runtime.h>
#include <hip/hip_bf16.h>
#include <math.h>

// Problem constants
#define B_  2
#define T_  1024
#define D_  1024
#define H_  16
#define DK_ 64
#define DV_ 128
#define FH_ 2816
#define M_  (B_ * T_)   // 2048 tokens
#define C_  64          // chunk length
#define NCH (T_ / C_)   // 16 chunks

typedef __attribute__((ext_vector_type(8))) short bf16x8;
typedef __attribute__((ext_vector_type(4))) float f32x4;

// ---------------------------------------------------------------------------
// rmsnorm with fp32 and/or bf16 outputs (either may be null)
__global__ __launch_bounds__(256) void rmsnorm_k(
    const float* __restrict__ x, const float* __restrict__ w,
    float* __restrict__ outf, __hip_bfloat16* __restrict__ outb,
    int D, float eps) {
  const int row = blockIdx.x;
  const float* xr = x + (size_t)row * D;
  float ss = 0.f;
  for (int i = threadIdx.x; i < D; i += blockDim.x) { float v = xr[i]; ss += v * v; }
  for (int off = 32; off > 0; off >>= 1) ss += __shfl_xor(ss, off, 64);
  __shared__ float wsum[4];
  __shared__ float s_scale;
  const int lane = threadIdx.x & 63, wid = threadIdx.x >> 6;
  if (lane == 0) wsum[wid] = ss;
  __syncthreads();
  if (threadIdx.x == 0) {
    float tot = 0.f;
    const int nw = blockDim.x >> 6;
    for (int i = 0; i < nw; ++i) tot += wsum[i];
    s_scale = rsqrtf(tot / (float)D + eps);
  }
  __syncthreads();
  const float sc = s_scale;
  for (int i = threadIdx.x; i < D; i += blockDim.x) {
    const float v = xr[i] * sc * w[i];
    if (outf) outf[(size_t)row * D + i] = v;
    if (outb) outb[(size_t)row * D + i] = __float2bfloat16(v);
  }
}

// ---------------------------------------------------------------------------
// Tiled transpose + fp32->bf16 convert: W[K,N] -> Wt[N,K]
__global__ __launch_bounds__(256) void transpose_bf16_k(
    const float* __restrict__ W, __hip_bfloat16* __restrict__ Wt, int K, int N) {
  __shared__ float t[32][33];
  const int k0 = blockIdx.y * 32, n0 = blockIdx.x * 32;
  const int c = threadIdx.x & 31, r = threadIdx.x >> 5;  // r in 0..7
#pragma unroll
  for (int i = 0; i < 4; ++i)
    t[r + 8 * i][c] = W[(size_t)(k0 + r + 8 * i) * N + n0 + c];
  __syncthreads();
#pragma unroll
  for (int i = 0; i < 4; ++i)
    Wt[(size_t)(n0 + r + 8 * i) * K + k0 + c] = __float2bfloat16(t[c][r + 8 * i]);
}

// ---------------------------------------------------------------------------
__device__ __forceinline__ void gload_lds16(const void* g, void* l) {
  __builtin_amdgcn_global_load_lds(
      (const __attribute__((address_space(1))) void*)g,
      (__attribute__((address_space(3))) void*)l, 16, 0, 0);
}

// bf16 MFMA GEMM (m97 structure): C[M,N] = A[M,K] @ Bt[N,K]^T.
// mode 0: C = acc (fp32); mode 1: C = acc + res (fp32);
// mode 2: Cbf16 = silu(res) * acc   (fused SwiGLU epilogue)
__global__ __launch_bounds__(256) void mfma_gemm_k(
    const __hip_bfloat16* __restrict__ A, const __hip_bfloat16* __restrict__ Bt,
    const float* __restrict__ res, void* __restrict__ Cout,
    int M, int N, int K, int mode) {
  __shared__ __hip_bfloat16 As[128 * 32];
  __shared__ __hip_bfloat16 Bs[128 * 32];
  const int tid = threadIdx.x;
  const int lane = tid & 63;
  const int wv = tid >> 6;
  const int wm = (wv >> 1) * 64, wn = (wv & 1) * 64;
  const int bm = blockIdx.y * 128, bn = blockIdx.x * 128;
  const int l15 = lane & 15, lq8 = (lane >> 4) * 8;
  const int ar = tid >> 2;
  const int ac = (tid & 3) * 8;
  const size_t Abase = (size_t)(bm + ar) * K + ac;
  const size_t Bbase = (size_t)(bn + ar) * K + ac;
  f32x4 acc[4][4];
#pragma unroll
  for (int i = 0; i < 4; ++i)
#pragma unroll
    for (int j = 0; j < 4; ++j) acc[i][j] = (f32x4){0.f, 0.f, 0.f, 0.f};
  for (int k0 = 0; k0 < K; k0 += 32) {
    gload_lds16(A + Abase + k0, (char*)As + tid * 16);
    gload_lds16(A + Abase + (size_t)64 * K + k0, (char*)As + tid * 16 + 4096);
    gload_lds16(Bt + Bbase + k0, (char*)Bs + tid * 16);
    gload_lds16(Bt + Bbase + (size_t)64 * K + k0, (char*)Bs + tid * 16 + 4096);
    __syncthreads();
    bf16x8 af[4], bfr[4];
#pragma unroll
    for (int i = 0; i < 4; ++i)
      af[i] = *(const bf16x8*)(As + (wm + i * 16 + l15) * 32 + lq8);
#pragma unroll
    for (int j = 0; j < 4; ++j)
      bfr[j] = *(const bf16x8*)(Bs + (wn + j * 16 + l15) * 32 + lq8);
#pragma unroll
    for (int i = 0; i < 4; ++i)
#pragma unroll
      for (int j = 0; j < 4; ++j)
        acc[i][j] = __builtin_amdgcn_mfma_f32_16x16x32_bf16(af[i], bfr[j], acc[i][j], 0, 0, 0);
    __syncthreads();
  }
  const int r0 = (lane >> 4) * 4;
#pragma unroll
  for (int i = 0; i < 4; ++i) {
#pragma unroll
    for (int j = 0; j < 4; ++j) {
      const int row = bm + wm + i * 16 + r0;
      const int col = bn + wn + j * 16 + l15;
#pragma unroll
      for (int r = 0; r < 4; ++r) {
        const size_t idx = (size_t)(row + r) * N + col;
        const float a = acc[i][j][r];
        if (mode == 0) ((float*)Cout)[idx] = a;
        else if (mode == 1) ((float*)Cout)[idx] = a + res[idx];
        else {
          const float s = res[idx];
          ((__hip_bfloat16*)Cout)[idx] =
              __float2bfloat16(s * (1.f / (1.f + __expf(-s))) * a);
        }
      }
    }
  }
}

// ---------------------------------------------------------------------------
// pa/pb = h @ [Wa|Wb] — v2: all 256 threads active (8-way K-split + reduce).
__global__ __launch_bounds__(256) void skinny_k(
    const float* __restrict__ h, const float* __restrict__ Wa,
    const float* __restrict__ Wb, float* __restrict__ pa,
    float* __restrict__ pb, int K) {
  __shared__ float hl[D_];
  __shared__ float red[8][32];
  const int row = blockIdx.x;
  const int tid = threadIdx.x;
  {
    const float4* src = (const float4*)(h + (size_t)row * K);
    ((float4*)hl)[tid] = src[tid];   // 256*4 = 1024 = D_
  }
  __syncthreads();
  const int col = tid & 31, sub = tid >> 5;    // 8 subs x 128 k each
  const float* W = (col < 16) ? Wa : Wb;
  const int cc = col & 15;
  float s = 0.f;
  const int kk0 = sub * 128;
  for (int k = kk0; k < kk0 + 128; ++k) s += hl[k] * W[k * H_ + cc];
  red[sub][col] = s;
  __syncthreads();
  if (tid < 32) {
    float t = 0.f;
#pragma unroll
    for (int i = 0; i < 8; ++i) t += red[i][tid];
    if (tid < 16) pa[(size_t)row * H_ + tid] = t;
    else          pb[(size_t)row * H_ + tid - 16] = t;
  }
}

// ---------------------------------------------------------------------------
__global__ __launch_bounds__(256) void conv_silu_k(
    const float* __restrict__ src, const float* __restrict__ w,
    float* __restrict__ dst, int C) {
  const int bt = blockIdx.x;
  const int b = bt / T_, t = bt % T_;
  const float* s = src + (size_t)b * T_ * C;
  for (int c = threadIdx.x; c < C; c += blockDim.x) {
    const float w0 = w[c * 4 + 0], w1 = w[c * 4 + 1],
                w2 = w[c * 4 + 2], w3 = w[c * 4 + 3];
    float acc = s[(size_t)t * C + c] * w3;
    if (t >= 1) acc += s[(size_t)(t - 1) * C + c] * w2;
    if (t >= 2) acc += s[(size_t)(t - 2) * C + c] * w1;
    if (t >= 3) acc += s[(size_t)(t - 3) * C + c] * w0;
    dst[(size_t)bt * C + c] = acc * (1.f / (1.f + __expf(-acc)));
  }
}

// ---------------------------------------------------------------------------
__global__ void beta_g_k(const float* __restrict__ pa, const float* __restrict__ pb,
                         const float* __restrict__ dtb, const float* __restrict__ Alog,
                         float* __restrict__ g, float* __restrict__ beta, int n) {
  const int i = blockIdx.x * blockDim.x + threadIdx.x;
  if (i >= n) return;
  const int h = i & (H_ - 1);
  const float xx = pa[i] + dtb[h];
  const float sp = (xx > 20.f) ? xx : log1pf(expf(xx));
  g[i] = -expf(Alog[h]) * sp;
  beta[i] = 1.f / (1.f + expf(-pb[i]));
}

// ---------------------------------------------------------------------------
__global__ __launch_bounds__(64) void l2norm_k(float* __restrict__ q, float scale) {
  const size_t row = blockIdx.x;
  const int lane = threadIdx.x;
  const float v = q[row * 64 + lane];
  float ss = v * v;
  for (int off = 32; off > 0; off >>= 1) ss += __shfl_xor(ss, off, 64);
  q[row * 64 + lane] = v * rsqrtf(ss + 1e-6f) * scale;
}

// ---------------------------------------------------------------------------
// Chunked gated delta rule, phase A (unchanged from round 4/5).
__global__ __launch_bounds__(256) void chunk_prep_k(
    const float* __restrict__ q, float* __restrict__ k, float* __restrict__ v,
    const float* __restrict__ g, const float* __restrict__ beta,
    float* __restrict__ qkd, float* __restrict__ kdt, float* __restrict__ gam) {
  const int task = blockIdx.x;
  const int bh = task >> 4, n = task & (NCH - 1);
  const int b = bh >> 4, h = bh & 15;
  const int t0 = n * C_;
  const int tid = threadIdx.x;
  __shared__ float lk[C_][68];
  __shared__ float bufs[3][C_][68];
  __shared__ float lb[C_], lgam[C_], lbeta[C_], lbg[C_];
  {
    const int r = tid >> 2, cq = (tid & 3) * 16;
    const float* src = k + (((size_t)b * T_ + t0 + r) * H_ + h) * DK_ + cq;
#pragma unroll
    for (int i = 0; i < 4; ++i)
      *(float4*)&lk[r][cq + 4 * i] = ((const float4*)src)[i];
  }
  if (tid < 64) {
    const size_t gi = ((size_t)b * T_ + t0 + tid) * H_ + h;
    float xx = g[gi];
    const float bb = beta[gi];
    lbeta[tid] = bb;
#pragma unroll
    for (int off = 1; off < 64; off <<= 1) {
      float y = __shfl_up(xx, off, 64);
      if (tid >= off) xx += y;
    }
    lb[tid] = xx;
    const float gm = __expf(xx);
    lgam[tid] = gm;
    lbg[tid] = bb * gm;
  }
  __syncthreads();
  const int r4 = (tid >> 4) * 4;
  const int sl = tid & 15;
  const int c4 = sl * 4;
  {
    const float* qg = q + (((size_t)b * T_ + t0) * H_ + h) * DK_;
    float accA[4][4] = {};
    float accQ[4][4] = {};
    for (int d = 0; d < 64; d += 4) {
      float4 kt[4], ks[4], qt[4];
#pragma unroll
      for (int i = 0; i < 4; ++i) kt[i] = *(const float4*)&lk[r4 + i][d];
#pragma unroll
      for (int j = 0; j < 4; ++j) ks[j] = *(const float4*)&lk[sl + 16 * j][d];
#pragma unroll
      for (int i = 0; i < 4; ++i) qt[i] = *(const float4*)(qg + (size_t)(r4 + i) * (H_ * DK_) + d);
#pragma unroll
      for (int i = 0; i < 4; ++i)
#pragma unroll
        for (int j = 0; j < 4; ++j) {
          accA[i][j] += kt[i].x * ks[j].x + kt[i].y * ks[j].y + kt[i].z * ks[j].z + kt[i].w * ks[j].w;
          accQ[i][j] += qt[i].x * ks[j].x + qt[i].y * ks[j].y + qt[i].z * ks[j].z + qt[i].w * ks[j].w;
        }
    }
    float (*L0)[68] = bufs[0];
    float (*T0)[68] = bufs[2];
    float* qo = qkd + (size_t)task * 4096;
#pragma unroll
    for (int i = 0; i < 4; ++i)
#pragma unroll
      for (int j = 0; j < 4; ++j) {
        const int t = r4 + i, s = sl + 16 * j;
        const float dec = (s <= t) ? __expf(lb[t] - lb[s]) : 0.f;
        const float Lts = (t > s) ? -(lbeta[t] * accA[i][j] * dec) : 0.f;
        L0[t][s] = Lts;
        T0[t][s] = (t == s) ? 1.f : Lts;
        qo[t * 64 + s] = accQ[i][j] * dec;
      }
  }
  {
    const int dk = tid >> 2, s0 = (tid & 3) * 16;
    const float bC = lb[63];
    float* dst = kdt + (size_t)task * 4096 + dk * 64 + s0;
#pragma unroll
    for (int j = 0; j < 16; ++j)
      dst[j] = lk[s0 + j][dk] * __expf(bC - lb[s0 + j]);
  }
  if (tid < 64) gam[(size_t)task * 64 + tid] = lgam[tid];
  __syncthreads();
  float (*Lp)[68] = bufs[0];
  float (*Tm)[68] = bufs[2];
  float (*Fr)[68] = bufs[1];
  for (int it = 0; it < 5; ++it) {
    {
      float acc[4][4] = {};
      for (int d = 0; d < 64; d += 4) {
        const float4 bv0 = *(const float4*)&Lp[d + 0][c4];
        const float4 bv1 = *(const float4*)&Lp[d + 1][c4];
        const float4 bv2 = *(const float4*)&Lp[d + 2][c4];
        const float4 bv3 = *(const float4*)&Lp[d + 3][c4];
#pragma unroll
        for (int j = 0; j < 4; ++j) {
          const float4 a = *(const float4*)&Lp[r4 + j][d];
          acc[j][0] += a.x * bv0.x + a.y * bv1.x + a.z * bv2.x + a.w * bv3.x;
          acc[j][1] += a.x * bv0.y + a.y * bv1.y + a.z * bv2.y + a.w * bv3.y;
          acc[j][2] += a.x * bv0.z + a.y * bv1.z + a.z * bv2.z + a.w * bv3.z;
          acc[j][3] += a.x * bv0.w + a.y * bv1.w + a.z * bv2.w + a.w * bv3.w;
        }
      }
#pragma unroll
      for (int j = 0; j < 4; ++j)
        *(float4*)&Fr[r4 + j][c4] = make_float4(acc[j][0], acc[j][1], acc[j][2], acc[j][3]);
    }
    __syncthreads();
    {
      float acc[4][4] = {};
      for (int d = 0; d < 64; d += 4) {
        const float4 bv0 = *(const float4*)&Fr[d + 0][c4];
        const float4 bv1 = *(const float4*)&Fr[d + 1][c4];
        const float4 bv2 = *(const float4*)&Fr[d + 2][c4];
        const float4 bv3 = *(const float4*)&Fr[d + 3][c4];
#pragma unroll
        for (int j = 0; j < 4; ++j) {
          const float4 a = *(const float4*)&Tm[r4 + j][d];
          acc[j][0] += a.x * bv0.x + a.y * bv1.x + a.z * bv2.x + a.w * bv3.x;
          acc[j][1] += a.x * bv0.y + a.y * bv1.y + a.z * bv2.y + a.w * bv3.y;
          acc[j][2] += a.x * bv0.z + a.y * bv1.z + a.z * bv2.z + a.w * bv3.z;
          acc[j][3] += a.x * bv0.w + a.y * bv1.w + a.z * bv2.w + a.w * bv3.w;
        }
      }
#pragma unroll
      for (int j = 0; j < 4; ++j) {
        const float4 told = *(const float4*)&Tm[r4 + j][c4];
        *(float4*)&Lp[r4 + j][c4] = make_float4(
            told.x + acc[j][0], told.y + acc[j][1],
            told.z + acc[j][2], told.w + acc[j][3]);
      }
    }
    __syncthreads();
    float (*oldT)[68] = Tm;
    Tm = Lp; Lp = Fr; Fr = oldT;
  }
  for (int hv = 0; hv < 2; ++hv) {
    float acc[4][4] = {};
    for (int d = 0; d < 64; d += 4) {
      float4 bv[4];
#pragma unroll
      for (int s = 0; s < 4; ++s) {
        const float sc = lbeta[d + s];
        float4 x = *(const float4*)(v + (((size_t)b * T_ + t0 + d + s) * H_ + h) * DV_ + hv * 64 + c4);
        x.x *= sc; x.y *= sc; x.z *= sc; x.w *= sc;
        bv[s] = x;
      }
#pragma unroll
      for (int j = 0; j < 4; ++j) {
        const float4 a = *(const float4*)&Tm[r4 + j][d];
        acc[j][0] += a.x * bv[0].x + a.y * bv[1].x + a.z * bv[2].x + a.w * bv[3].x;
        acc[j][1] += a.x * bv[0].y + a.y * bv[1].y + a.z * bv[2].y + a.w * bv[3].y;
        acc[j][2] += a.x * bv[0].z + a.y * bv[1].z + a.z * bv[2].z + a.w * bv[3].z;
        acc[j][3] += a.x * bv[0].w + a.y * bv[1].w + a.z * bv[2].w + a.w * bv[3].w;
      }
    }
    __syncthreads();
#pragma unroll
    for (int j = 0; j < 4; ++j)
      *(float4*)(v + (((size_t)b * T_ + t0 + r4 + j) * H_ + h) * DV_ + hv * 64 + c4) =
          make_float4(acc[j][0], acc[j][1], acc[j][2], acc[j][3]);
  }
  {
    float acc[4][4] = {};
    for (int d = 0; d < 64; d += 4) {
      float4 bv[4];
#pragma unroll
      for (int s = 0; s < 4; ++s) {
        const float sc = lbg[d + s];
        float4 x = *(const float4*)&lk[d + s][c4];
        x.x *= sc; x.y *= sc; x.z *= sc; x.w *= sc;
        bv[s] = x;
      }
#pragma unroll
      for (int j = 0; j < 4; ++j) {
        const float4 a = *(const float4*)&Tm[r4 + j][d];
        acc[j][0] += a.x * bv[0].x + a.y * bv[1].x + a.z * bv[2].x + a.w * bv[3].x;
        acc[j][1] += a.x * bv[0].y + a.y * bv[1].y + a.z * bv[2].y + a.w * bv[3].y;
        acc[j][2] += a.x * bv[0].z + a.y * bv[1].z + a.z * bv[2].z + a.w * bv[3].z;
        acc[j][3] += a.x * bv[0].w + a.y * bv[1].w + a.z * bv[2].w + a.w * bv[3].w;
      }
    }
#pragma unroll
    for (int j = 0; j < 4; ++j)
      *(float4*)(k + (((size_t)b * T_ + t0 + r4 + j) * H_ + h) * DK_ + c4) =
          make_float4(acc[j][0], acc[j][1], acc[j][2], acc[j][3]);
  }
}

// ---------------------------------------------------------------------------
// Serial recurrence only: per (bh, 16-col group), one wave, S tile in regs.
// Per chunk: dump S -> S_store; Û = u - W·S (in-place over u); S = γC·S + KdT·Û.
// A-operands staged TRANSPOSED in LDS (conflict-free b128 reads); no barriers.
__global__ __launch_bounds__(64) void chunk_rec_k(
    const float* __restrict__ W, float* __restrict__ u,
    const float* __restrict__ kdt, const float* __restrict__ gam,
    float* __restrict__ Sst) {
  const int bh = blockIdx.x >> 3, cg = blockIdx.x & 7;
  const int b = bh >> 4, h = bh & 15;
  const int c0 = cg * 16;
  const int lane = threadIdx.x;
  const int r4 = (lane & 15) * 4;   // output row tile
  const int cl = (lane >> 4) * 4;   // local col tile (0,4,8,12)
  __shared__ float Wt[64][68];      // Wt[dk][t] = W[t][dk]
  __shared__ float Kt[64][68];      // Kt[s][dk] = KdT[dk][s]
  __shared__ float Ss[64][20];      // S[dk][c]
  __shared__ float Ub[64][20];      // Û[t][c]
  float Sr[4][4];
#pragma unroll
  for (int i = 0; i < 4; ++i)
#pragma unroll
    for (int j = 0; j < 4; ++j) Sr[i][j] = 0.f;
  for (int i = lane; i < 64 * 20; i += 64) (&Ss[0][0])[i] = 0.f;
  for (int n = 0; n < NCH; ++n) {
    const int task = bh * NCH + n;
    const int t0 = n * C_;
    // dump chunk-start S
#pragma unroll
    for (int i = 0; i < 4; ++i)
      *(float4*)(Sst + (size_t)task * 8192 + (r4 + i) * 128 + c0 + cl) =
          make_float4(Sr[i][0], Sr[i][1], Sr[i][2], Sr[i][3]);
    // stage W transposed: thread reads row t=lane
    {
      const float* src = W + (((size_t)b * T_ + t0 + lane) * H_ + h) * DK_;
#pragma unroll
      for (int d4 = 0; d4 < 16; ++d4) {
        const float4 wv = ((const float4*)src)[d4];
        Wt[4 * d4 + 0][lane] = wv.x; Wt[4 * d4 + 1][lane] = wv.y;
        Wt[4 * d4 + 2][lane] = wv.z; Wt[4 * d4 + 3][lane] = wv.w;
      }
    }
    // stage KdT transposed: thread reads row dk=lane
    {
      const float* src = kdt + (size_t)task * 4096 + lane * 64;
#pragma unroll
      for (int s4 = 0; s4 < 16; ++s4) {
        const float4 kv = ((const float4*)src)[s4];
        Kt[4 * s4 + 0][lane] = kv.x; Kt[4 * s4 + 1][lane] = kv.y;
        Kt[4 * s4 + 2][lane] = kv.z; Kt[4 * s4 + 3][lane] = kv.w;
      }
    }
    // phase A: acc = u - W·S
    float acc[4][4];
#pragma unroll
    for (int i = 0; i < 4; ++i) {
      const float4 uv = *(const float4*)(u + (((size_t)b * T_ + t0 + r4 + i) * H_ + h) * DV_ + c0 + cl);
      acc[i][0] = uv.x; acc[i][1] = uv.y; acc[i][2] = uv.z; acc[i][3] = uv.w;
    }
    for (int kb = 0; kb < 64; kb += 4) {
#pragma unroll
      for (int j = 0; j < 4; ++j) {
        const float4 a = *(const float4*)&Wt[kb + j][r4];
        const float4 bb = *(const float4*)&Ss[kb + j][cl];
        const float av[4] = {a.x, a.y, a.z, a.w};
        const float bv[4] = {bb.x, bb.y, bb.z, bb.w};
#pragma unroll
        for (int i = 0; i < 4; ++i)
#pragma unroll
          for (int c = 0; c < 4; ++c) acc[i][c] -= av[i] * bv[c];
      }
    }
    // write Û to LDS + global (in place over u)
#pragma unroll
    for (int i = 0; i < 4; ++i) {
      *(float4*)&Ub[r4 + i][cl] = make_float4(acc[i][0], acc[i][1], acc[i][2], acc[i][3]);
      *(float4*)(u + (((size_t)b * T_ + t0 + r4 + i) * H_ + h) * DV_ + c0 + cl) =
          make_float4(acc[i][0], acc[i][1], acc[i][2], acc[i][3]);
    }
    // phase B: S = γC·S + KdT·Û
    float acc2[4][4] = {};
    for (int sb = 0; sb < 64; sb += 4) {
#pragma unroll
      for (int j = 0; j < 4; ++j) {
        const float4 a = *(const float4*)&Kt[sb + j][r4];
        const float4 bb = *(const float4*)&Ub[sb + j][cl];
        const float av[4] = {a.x, a.y, a.z, a.w};
        const float bv[4] = {bb.x, bb.y, bb.z, bb.w};
#pragma unroll
        for (int i = 0; i < 4; ++i)
#pragma unroll
          for (int c = 0; c < 4; ++c) acc2[i][c] += av[i] * bv[c];
      }
    }
    const float gC = gam[(size_t)task * 64 + 63];
#pragma unroll
    for (int i = 0; i < 4; ++i)
#pragma unroll
      for (int c = 0; c < 4; ++c) Sr[i][c] = gC * Sr[i][c] + acc2[i][c];
#pragma unroll
    for (int i = 0; i < 4; ++i)
      *(float4*)&Ss[r4 + i][cl] = make_float4(Sr[i][0], Sr[i][1], Sr[i][2], Sr[i][3]);
  }
}

// ---------------------------------------------------------------------------
// Parallel O: o = γ_t Q·S_n + QKd·Û_n, with gatenorm+silu fused in epilogue.
// Grid = 512 tasks, 128 threads, 8x8 register tiles.
__global__ __launch_bounds__(128) void chunk_o_k(
    const float* __restrict__ q, const float* __restrict__ qkd,
    const float* __restrict__ ub, const float* __restrict__ Sst,
    const float* __restrict__ gam, const float* __restrict__ gate,
    const float* __restrict__ onw, __hip_bfloat16* __restrict__ go) {
  const int task = blockIdx.x;
  const int bh = task >> 4, n = task & 15;
  const int b = bh >> 4, h = bh & 15;
  const int t0 = n * C_;
  const int tid = threadIdx.x;
  const int rowg = tid >> 4, colg = tid & 15;
  const int r8 = rowg * 8, c4 = colg * 4;
  __shared__ float At[64][68];   // transposed A operand (γQ or QKd)
  __shared__ float Bs[64][132];  // B operand (S or Û)
  __shared__ float lgam[64];
  if (tid < 64) lgam[tid] = gam[(size_t)task * 64 + tid];
  __syncthreads();
  const int t2 = tid >> 1, dh = (tid & 1) * 32;
  // stage At = (γ_t q_t)^T
  {
    const float* src = q + (((size_t)b * T_ + t0 + t2) * H_ + h) * DK_ + dh;
    const float sc = lgam[t2];
#pragma unroll
    for (int i = 0; i < 8; ++i) {
      const float4 v = ((const float4*)src)[i];
      At[dh + 4 * i + 0][t2] = v.x * sc; At[dh + 4 * i + 1][t2] = v.y * sc;
      At[dh + 4 * i + 2][t2] = v.z * sc; At[dh + 4 * i + 3][t2] = v.w * sc;
    }
  }
  // stage Bs = S_store[task]
  {
    const float* src = Sst + (size_t)task * 8192 + t2 * 128 + (tid & 1) * 64;
    float* dst = &Bs[t2][(tid & 1) * 64];
#pragma unroll
    for (int i = 0; i < 16; ++i) ((float4*)dst)[i] = ((const float4*)src)[i];
  }
  __syncthreads();
  float acc[8][8];
#pragma unroll
  for (int i = 0; i < 8; ++i)
#pragma unroll
    for (int c = 0; c < 8; ++c) acc[i][c] = 0.f;
#pragma unroll 1
  for (int ph = 0; ph < 2; ++ph) {
    for (int kb = 0; kb < 64; kb += 4) {
#pragma unroll
      for (int j = 0; j < 4; ++j) {
        const float4 alo = *(const float4*)&At[kb + j][r8];
        const float4 ahi = *(const float4*)&At[kb + j][r8 + 4];
        const float4 blo = *(const float4*)&Bs[kb + j][c4];
        const float4 bhi = *(const float4*)&Bs[kb + j][c4 + 64];
        const float av[8] = {alo.x, alo.y, alo.z, alo.w, ahi.x, ahi.y, ahi.z, ahi.w};
        const float bv[8] = {blo.x, blo.y, blo.z, blo.w, bhi.x, bhi.y, bhi.z, bhi.w};
#pragma unroll
        for (int i = 0; i < 8; ++i)
#pragma unroll
          for (int c = 0; c < 8; ++c) acc[i][c] += av[i] * bv[c];
      }
    }
    if (ph == 0) {
      __syncthreads();
      // restage At = QKd^T, Bs = Û
      {
        const float* src = qkd + (size_t)task * 4096 + t2 * 64 + dh;
#pragma unroll
        for (int i = 0; i < 8; ++i) {
          const float4 v = ((const float4*)src)[i];
          At[dh + 4 * i + 0][t2] = v.x; At[dh + 4 * i + 1][t2] = v.y;
          At[dh + 4 * i + 2][t2] = v.z; At[dh + 4 * i + 3][t2] = v.w;
        }
      }
      {
        const float* src = ub + (((size_t)b * T_ + t0 + t2) * H_ + h) * DV_ + (tid & 1) * 64;
        float* dst = &Bs[t2][(tid & 1) * 64];
#pragma unroll
        for (int i = 0; i < 16; ++i) ((float4*)dst)[i] = ((const float4*)src)[i];
      }
      __syncthreads();
    }
  }
  // epilogue: fused gated RMSNorm -> bf16
#pragma unroll
  for (int i = 0; i < 8; ++i) {
    float pr = 0.f;
#pragma unroll
    for (int c = 0; c < 8; ++c) pr += acc[i][c] * acc[i][c];
    pr += __shfl_xor(pr, 1, 64);
    pr += __shfl_xor(pr, 2, 64);
    pr += __shfl_xor(pr, 4, 64);
    pr += __shfl_xor(pr, 8, 64);
    const float rms = rsqrtf(pr / (float)DV_ + 1e-5f);
    const size_t rb = (((size_t)b * T_ + t0 + r8 + i) * H_ + h) * DV_;
    const float4 glo = *(const float4*)(gate + rb + c4);
    const float4 ghi = *(const float4*)(gate + rb + c4 + 64);
    const float gv[8] = {glo.x, glo.y, glo.z, glo.w, ghi.x, ghi.y, ghi.z, ghi.w};
    unsigned short outv[8];
#pragma unroll
    for (int c = 0; c < 8; ++c) {
      const int col = (c < 4) ? c4 + c : c4 + 60 + c;   // c4+64+(c-4)
      const float gg = gv[c];
      const float val = acc[i][c] * rms * onw[col] * gg * (1.f / (1.f + __expf(-gg)));
      const __hip_bfloat16 bfv = __float2bfloat16(val);
      outv[c] = *(const unsigned short*)&bfv;
    }
    *(ushort4*)((unsigned short*)go + rb + c4) =
        make_ushort4(outv[0], outv[1], outv[2], outv[3]);
    *(ushort4*)((unsigned short*)go + rb + c4 + 64) =
        make_ushort4(outv[4], outv[5], outv[6], outv[7]);
  }
}

// ---------------------------------------------------------------------------
extern "C" void kernel_launch(void* const* d_in, const int* in_sizes, int n_in,
                              void* d_out, int out_size, void* d_ws, size_t ws_size,
                              hipStream_t stream) {
  const float* x    = (const float*)d_in[0];
  const float* n1w  = (const float*)d_in[1];
  const float* n2w  = (const float*)d_in[2];
  const float* Wq   = (const float*)d_in[3];
  const float* Wk   = (const float*)d_in[4];
  const float* Wv   = (const float*)d_in[5];
  const float* cq   = (const float*)d_in[6];
  const float* ck   = (const float*)d_in[7];
  const float* cv   = (const float*)d_in[8];
  const float* Wa   = (const float*)d_in[9];
  const float* Wb   = (const float*)d_in[10];
  const float* dtb  = (const float*)d_in[11];
  const float* Alog = (const float*)d_in[12];
  const float* Wg   = (const float*)d_in[13];
  const float* onw  = (const float*)d_in[14];
  const float* Wo   = (const float*)d_in[15];
  const float* W1   = (const float*)d_in[16];
  const float* W3   = (const float*)d_in[17];
  const float* W2   = (const float*)d_in[18];
  float* out = (float*)d_out;
  float* ws  = (float*)d_ws;

  const size_t SZ_MD = (size_t)M_ * D_;          // 2M floats
  const size_t SZ_MV = (size_t)M_ * H_ * DV_;    // 4M floats
  float* h    = ws;                               // [0,2M)
  float* pq   = ws + SZ_MD;                       // [2M,4M)  -> QKd -> y1
  float* pk   = ws + 2 * SZ_MD;                   // [4M,6M)  -> KdT
  float* pv   = ws + 3 * SZ_MD;                   // [6M,10M) -> S_store -> a1
  float* gate = ws + 3 * SZ_MD + SZ_MV;           // [10M,14M)
  float* qb   = ws + 3 * SZ_MD + 2 * SZ_MV;       // [14M,16M)
  float* kb   = ws + 4 * SZ_MD + 2 * SZ_MV;       // [16M,18M) in-place W
  float* vb   = ws + 5 * SZ_MD + 2 * SZ_MV;       // [18M,22M) in-place u -> Û
  float* Sst  = pv;
  float* y1   = pq;
  float* a1   = pv;
  float* smalls = ws + 5 * SZ_MD + 3 * SZ_MV;     // 22M
  float* pa  = smalls;
  float* pb  = pa + (size_t)M_ * H_;
  float* gv  = pb + (size_t)M_ * H_;
  float* bv  = gv + (size_t)M_ * H_;
  float* gam = bv + (size_t)M_ * H_;
  // bf16 aliases (liveness-checked):
  __hip_bfloat16* h_bf  = (__hip_bfloat16*)vb;   // dead before conv_v writes vb
  __hip_bfloat16* wb1   = (__hip_bfloat16*)kb;   // dead before conv_k
  __hip_bfloat16* wb2   = (__hip_bfloat16*)vb;   // Û dead after chunk_o
  __hip_bfloat16* go_bf = (__hip_bfloat16*)h;    // h dead after skinny
  __hip_bfloat16* h2_bf = (__hip_bfloat16*)h;    // go_bf dead after Wo GEMM
  __hip_bfloat16* a1b   = (__hip_bfloat16*)qb;   // q dead after chunk_o

  const dim3 blk256(256);
  const dim3 g_tr1024_1024(1024 / 32, 1024 / 32);
  const dim3 g_tr1024_2048(2048 / 32, 1024 / 32);
  const dim3 g_tr2048_1024(1024 / 32, 2048 / 32);
  const dim3 g_tr1024_2816(2816 / 32, 1024 / 32);
  const dim3 g_tr2816_1024(1024 / 32, 2816 / 32);

  rmsnorm_k<<<dim3(M_), blk256, 0, stream>>>(x, n1w, h, h_bf, D_, 1e-6f);
  transpose_bf16_k<<<g_tr1024_1024, blk256, 0, stream>>>(Wq, wb1, D_, 1024);
  mfma_gemm_k<<<dim3(1024 / 128, M_ / 128), blk256, 0, stream>>>(h_bf, wb1, nullptr, pq, M_, 1024, D_, 0);
  transpose_bf16_k<<<g_tr1024_1024, blk256, 0, stream>>>(Wk, wb1, D_, 1024);
  mfma_gemm_k<<<dim3(1024 / 128, M_ / 128), blk256, 0, stream>>>(h_bf, wb1, nullptr, pk, M_, 1024, D_, 0);
  transpose_bf16_k<<<g_tr1024_2048, blk256, 0, stream>>>(Wv, wb1, D_, 2048);
  mfma_gemm_k<<<dim3(2048 / 128, M_ / 128), blk256, 0, stream>>>(h_bf, wb1, nullptr, pv, M_, 2048, D_, 0);
  transpose_bf16_k<<<g_tr1024_2048, blk256, 0, stream>>>(Wg, wb1, D_, 2048);
  mfma_gemm_k<<<dim3(2048 / 128, M_ / 128), blk256, 0, stream>>>(h_bf, wb1, nullptr, gate, M_, 2048, D_, 0);
  skinny_k<<<dim3(M_), blk256, 0, stream>>>(h, Wa, Wb, pa, pb, D_);
  conv_silu_k<<<dim3(M_), blk256, 0, stream>>>(pq, cq, qb, H_ * DK_);
  conv_silu_k<<<dim3(M_), blk256, 0, stream>>>(pk, ck, kb, H_ * DK_);
  conv_silu_k<<<dim3(M_), blk256, 0, stream>>>(pv, cv, vb, H_ * DV_);
  beta_g_k<<<dim3((M_ * H_ + 255) / 256), blk256, 0, stream>>>(pa, pb, dtb, Alog, gv, bv, M_ * H_);
  l2norm_k<<<dim3(M_ * H_), dim3(64), 0, stream>>>(qb, 0.125f);
  l2norm_k<<<dim3(M_ * H_), dim3(64), 0, stream>>>(kb, 1.0f);
  // chunked delta rule: prep -> serial recurrence -> parallel O (+gatenorm)
  chunk_prep_k<<<dim3(32 * NCH), blk256, 0, stream>>>(qb, kb, vb, gv, bv, pq, pk, gam);
  chunk_rec_k<<<dim3(32 * 8), dim3(64), 0, stream>>>(kb, vb, pk, gam, Sst);
  chunk_o_k<<<dim3(32 * NCH), dim3(128), 0, stream>>>(qb, pq, vb, Sst, gam, gate, onw, go_bf);
  // y1 = x + go @ Wo
  transpose_bf16_k<<<g_tr2048_1024, blk256, 0, stream>>>(Wo, wb2, H_ * DV_, 1024);
  mfma_gemm_k<<<dim3(1024 / 128, M_ / 128), blk256, 0, stream>>>(go_bf, wb2, x, y1, M_, 1024, H_ * DV_, 1);
  rmsnorm_k<<<dim3(M_), blk256, 0, stream>>>(y1, n2w, nullptr, h2_bf, D_, 1e-6f);
  transpose_bf16_k<<<g_tr1024_2816, blk256, 0, stream>>>(W1, wb2, D_, FH_);
  mfma_gemm_k<<<dim3(FH_ / 128, M_ / 128), blk256, 0, stream>>>(h2_bf, wb2, nullptr, a1, M_, FH_, D_, 0);
  transpose_bf16_k<<<g_tr1024_2816, blk256, 0, stream>>>(W3, wb2, D_, FH_);
  mfma_gemm_k<<<dim3(FH_ / 128, M_ / 128), blk256, 0, stream>>>(h2_bf, wb2, a1, a1b, M_, FH_, D_, 2);
  transpose_bf16_k<<<g_tr2816_1024, blk256, 0, stream>>>(W2, wb2, FH_, 1024);
  mfma_gemm_k<<<dim3(1024 / 128, M_ / 128), blk256, 0, stream>>>(a1b, wb2, y1, out, M_, 1024, FH_, 1);
}

// Round 7
// 713.230 us; speedup vs baseline: 3.6162x; 1.1744x over previous
//
#include <hip/hip_runtime.h>
#include <hip/hip_bf16.h>
#include <math.h>

// Problem constants
#define B_  2
#define T_  1024
#define D_  1024
#define H_  16
#define DK_ 64
#define DV_ 128
#define FH_ 2816
#define M_  (B_ * T_)   // 2048 tokens
#define C_  64          // chunk length
#define NCH (T_ / C_)   // 16 chunks

typedef __attribute__((ext_vector_type(8))) short bf16x8;
typedef __attribute__((ext_vector_type(4))) float f32x4;

// ---------------------------------------------------------------------------
// rmsnorm with fp32 and/or bf16 outputs (either may be null)
__global__ __launch_bounds__(256) void rmsnorm_k(
    const float* __restrict__ x, const float* __restrict__ w,
    float* __restrict__ outf, __hip_bfloat16* __restrict__ outb,
    int D, float eps) {
  const int row = blockIdx.x;
  const float* xr = x + (size_t)row * D;
  float ss = 0.f;
  for (int i = threadIdx.x; i < D; i += blockDim.x) { float v = xr[i]; ss += v * v; }
  for (int off = 32; off > 0; off >>= 1) ss += __shfl_xor(ss, off, 64);
  __shared__ float wsum[4];
  __shared__ float s_scale;
  const int lane = threadIdx.x & 63, wid = threadIdx.x >> 6;
  if (lane == 0) wsum[wid] = ss;
  __syncthreads();
  if (threadIdx.x == 0) {
    float tot = 0.f;
    const int nw = blockDim.x >> 6;
    for (int i = 0; i < nw; ++i) tot += wsum[i];
    s_scale = rsqrtf(tot / (float)D + eps);
  }
  __syncthreads();
  const float sc = s_scale;
  for (int i = threadIdx.x; i < D; i += blockDim.x) {
    const float v = xr[i] * sc * w[i];
    if (outf) outf[(size_t)row * D + i] = v;
    if (outb) outb[(size_t)row * D + i] = __float2bfloat16(v);
  }
}

// ---------------------------------------------------------------------------
// Tiled transpose + fp32->bf16 convert: W[K,N] -> Wt[N,K]
__global__ __launch_bounds__(256) void transpose_bf16_k(
    const float* __restrict__ W, __hip_bfloat16* __restrict__ Wt, int K, int N) {
  __shared__ float t[32][33];
  const int k0 = blockIdx.y * 32, n0 = blockIdx.x * 32;
  const int c = threadIdx.x & 31, r = threadIdx.x >> 5;  // r in 0..7
#pragma unroll
  for (int i = 0; i < 4; ++i)
    t[r + 8 * i][c] = W[(size_t)(k0 + r + 8 * i) * N + n0 + c];
  __syncthreads();
#pragma unroll
  for (int i = 0; i < 4; ++i)
    Wt[(size_t)(n0 + r + 8 * i) * K + k0 + c] = __float2bfloat16(t[c][r + 8 * i]);
}

// ---------------------------------------------------------------------------
__device__ __forceinline__ void gload_lds16(const void* g, void* l) {
  __builtin_amdgcn_global_load_lds(
      (const __attribute__((address_space(1))) void*)g,
      (__attribute__((address_space(3))) void*)l, 16, 0, 0);
}

// bf16 MFMA GEMM: C[M,N] = A[M,K] @ Bt[N,K]^T.  Tile 128 x BN (BN=128 or 64).
// BN=64 doubles the grid for N=1024 shapes (128 WGs only covered half the CUs).
// mode 0: C = acc (fp32); mode 1: C = acc + res (fp32);
// mode 2: Cbf16 = silu(res) * acc   (fused SwiGLU epilogue)
template<int BN>
__global__ __launch_bounds__(256) void mfma_gemm_k(
    const __hip_bfloat16* __restrict__ A, const __hip_bfloat16* __restrict__ Bt,
    const float* __restrict__ res, void* __restrict__ Cout,
    int M, int N, int K, int mode) {
  __shared__ __hip_bfloat16 As[128 * 32];
  __shared__ __hip_bfloat16 Bs[BN * 32];
  constexpr int NF = BN / 32;        // b-frags per wave (4 or 2)
  const int tid = threadIdx.x;
  const int lane = tid & 63;
  const int wv = tid >> 6;
  const int wm = (wv >> 1) * 64, wn = (wv & 1) * (BN / 2);
  const int bm = blockIdx.y * 128, bn = blockIdx.x * BN;
  const int l15 = lane & 15, lq8 = (lane >> 4) * 8;
  const int ar = tid >> 2;
  const int ac = (tid & 3) * 8;
  const size_t Abase = (size_t)(bm + ar) * K + ac;
  const size_t Bbase = (size_t)(bn + ar) * K + ac;
  f32x4 acc[4][NF];
#pragma unroll
  for (int i = 0; i < 4; ++i)
#pragma unroll
    for (int j = 0; j < NF; ++j) acc[i][j] = (f32x4){0.f, 0.f, 0.f, 0.f};
  for (int k0 = 0; k0 < K; k0 += 32) {
    gload_lds16(A + Abase + k0, (char*)As + tid * 16);
    gload_lds16(A + Abase + (size_t)64 * K + k0, (char*)As + tid * 16 + 4096);
    gload_lds16(Bt + Bbase + k0, (char*)Bs + tid * 16);
    if (BN == 128)
      gload_lds16(Bt + Bbase + (size_t)64 * K + k0, (char*)Bs + tid * 16 + 4096);
    __syncthreads();
    bf16x8 af[4], bfr[NF];
#pragma unroll
    for (int i = 0; i < 4; ++i)
      af[i] = *(const bf16x8*)(As + (wm + i * 16 + l15) * 32 + lq8);
#pragma unroll
    for (int j = 0; j < NF; ++j)
      bfr[j] = *(const bf16x8*)(Bs + (wn + j * 16 + l15) * 32 + lq8);
#pragma unroll
    for (int i = 0; i < 4; ++i)
#pragma unroll
      for (int j = 0; j < NF; ++j)
        acc[i][j] = __builtin_amdgcn_mfma_f32_16x16x32_bf16(af[i], bfr[j], acc[i][j], 0, 0, 0);
    __syncthreads();
  }
  const int r0 = (lane >> 4) * 4;
#pragma unroll
  for (int i = 0; i < 4; ++i) {
#pragma unroll
    for (int j = 0; j < NF; ++j) {
      const int row = bm + wm + i * 16 + r0;
      const int col = bn + wn + j * 16 + l15;
#pragma unroll
      for (int r = 0; r < 4; ++r) {
        const size_t idx = (size_t)(row + r) * N + col;
        const float a = acc[i][j][r];
        if (mode == 0) ((float*)Cout)[idx] = a;
        else if (mode == 1) ((float*)Cout)[idx] = a + res[idx];
        else {
          const float s = res[idx];
          ((__hip_bfloat16*)Cout)[idx] =
              __float2bfloat16(s * (1.f / (1.f + __expf(-s))) * a);
        }
      }
    }
  }
}

// ---------------------------------------------------------------------------
// pa/pb = h @ [Wa|Wb] — all 256 threads active (8-way K-split + reduce).
__global__ __launch_bounds__(256) void skinny_k(
    const float* __restrict__ h, const float* __restrict__ Wa,
    const float* __restrict__ Wb, float* __restrict__ pa,
    float* __restrict__ pb, int K) {
  __shared__ float hl[D_];
  __shared__ float red[8][32];
  const int row = blockIdx.x;
  const int tid = threadIdx.x;
  {
    const float4* src = (const float4*)(h + (size_t)row * K);
    ((float4*)hl)[tid] = src[tid];
  }
  __syncthreads();
  const int col = tid & 31, sub = tid >> 5;
  const float* W = (col < 16) ? Wa : Wb;
  const int cc = col & 15;
  float s = 0.f;
  const int kk0 = sub * 128;
  for (int k = kk0; k < kk0 + 128; ++k) s += hl[k] * W[k * H_ + cc];
  red[sub][col] = s;
  __syncthreads();
  if (tid < 32) {
    float t = 0.f;
#pragma unroll
    for (int i = 0; i < 8; ++i) t += red[i][tid];
    if (tid < 16) pa[(size_t)row * H_ + tid] = t;
    else          pb[(size_t)row * H_ + tid - 16] = t;
  }
}

// ---------------------------------------------------------------------------
__global__ __launch_bounds__(256) void conv_silu_k(
    const float* __restrict__ src, const float* __restrict__ w,
    float* __restrict__ dst, int C) {
  const int bt = blockIdx.x;
  const int b = bt / T_, t = bt % T_;
  const float* s = src + (size_t)b * T_ * C;
  for (int c = threadIdx.x; c < C; c += blockDim.x) {
    const float w0 = w[c * 4 + 0], w1 = w[c * 4 + 1],
                w2 = w[c * 4 + 2], w3 = w[c * 4 + 3];
    float acc = s[(size_t)t * C + c] * w3;
    if (t >= 1) acc += s[(size_t)(t - 1) * C + c] * w2;
    if (t >= 2) acc += s[(size_t)(t - 2) * C + c] * w1;
    if (t >= 3) acc += s[(size_t)(t - 3) * C + c] * w0;
    dst[(size_t)bt * C + c] = acc * (1.f / (1.f + __expf(-acc)));
  }
}

// ---------------------------------------------------------------------------
__global__ void beta_g_k(const float* __restrict__ pa, const float* __restrict__ pb,
                         const float* __restrict__ dtb, const float* __restrict__ Alog,
                         float* __restrict__ g, float* __restrict__ beta, int n) {
  const int i = blockIdx.x * blockDim.x + threadIdx.x;
  if (i >= n) return;
  const int h = i & (H_ - 1);
  const float xx = pa[i] + dtb[h];
  const float sp = (xx > 20.f) ? xx : log1pf(expf(xx));
  g[i] = -expf(Alog[h]) * sp;
  beta[i] = 1.f / (1.f + expf(-pb[i]));
}

// ---------------------------------------------------------------------------
__global__ __launch_bounds__(64) void l2norm_k(float* __restrict__ q, float scale) {
  const size_t row = blockIdx.x;
  const int lane = threadIdx.x;
  const float v = q[row * 64 + lane];
  float ss = v * v;
  for (int off = 32; off > 0; off >>= 1) ss += __shfl_xor(ss, off, 64);
  q[row * 64 + lane] = v * rsqrtf(ss + 1e-6f) * scale;
}

// ---------------------------------------------------------------------------
// Chunked gated delta rule, phase A v3 (parallel over 512 (bh,chunk) tasks).
// Builds G (β-folded strict-lower decay Gram), QKd (->qkd), KdT (->kdt), γ.
// Then solves (I+G)X = RHS directly via BLOCKED forward substitution:
// 16x16 diagonal-block inverses Td (per-thread register triangles), then a
// 4-stage dense sweep over 96-column halves in LDS. Replaces round-4/6's
// Neumann doubling (10 x 64^3 matmuls -> ~1M MACs total, 4x less VALU).
// Outputs: u = X (in place over v), W = X (in place over k).
__global__ __launch_bounds__(256) void chunk_prep_k(
    const float* __restrict__ q, float* __restrict__ k, float* __restrict__ v,
    const float* __restrict__ g, const float* __restrict__ beta,
    float* __restrict__ qkd, float* __restrict__ kdt, float* __restrict__ gam) {
  const int task = blockIdx.x;
  const int bh = task >> 4, n = task & (NCH - 1);
  const int b = bh >> 4, h = bh & 15;
  const int t0 = n * C_;
  const int tid = threadIdx.x;
  __shared__ float lk[C_][68];     // staged k rows
  __shared__ float Gs[C_][68];     // strict-lower β-folded Gram (zeros above)
  __shared__ float Xs[C_][100];    // 96-column RHS/solution panel
  __shared__ float Td[4][16][17];  // 16x16 diagonal-block inverses
  __shared__ float lb[C_], lgam[C_], lbeta[C_], lbg[C_];
  // stage k chunk
  {
    const int r = tid >> 2, cq = (tid & 3) * 16;
    const float* src = k + (((size_t)b * T_ + t0 + r) * H_ + h) * DK_ + cq;
#pragma unroll
    for (int i = 0; i < 4; ++i)
      *(float4*)&lk[r][cq + 4 * i] = ((const float4*)src)[i];
  }
  // g cumsum (wave 0), γ, β, βγ
  if (tid < 64) {
    const size_t gi = ((size_t)b * T_ + t0 + tid) * H_ + h;
    float xx = g[gi];
    const float bb = beta[gi];
    lbeta[tid] = bb;
#pragma unroll
    for (int off = 1; off < 64; off <<= 1) {
      float y = __shfl_up(xx, off, 64);
      if (tid >= off) xx += y;
    }
    lb[tid] = xx;
    const float gm = __expf(xx);
    lgam[tid] = gm;
    lbg[tid] = bb * gm;
  }
  __syncthreads();
  const int r4g = (tid >> 4) * 4;
  const int sl = tid & 15;
  // Gram: G = β-folded strict-lower K K^T decay; QKd = (Q K^T) decay
  {
    const float* qg = q + (((size_t)b * T_ + t0) * H_ + h) * DK_;
    float accA[4][4] = {};
    float accQ[4][4] = {};
    for (int d = 0; d < 64; d += 4) {
      float4 kt[4], ks[4], qt[4];
#pragma unroll
      for (int i = 0; i < 4; ++i) kt[i] = *(const float4*)&lk[r4g + i][d];
#pragma unroll
      for (int j = 0; j < 4; ++j) ks[j] = *(const float4*)&lk[sl + 16 * j][d];
#pragma unroll
      for (int i = 0; i < 4; ++i) qt[i] = *(const float4*)(qg + (size_t)(r4g + i) * (H_ * DK_) + d);
#pragma unroll
      for (int i = 0; i < 4; ++i)
#pragma unroll
        for (int j = 0; j < 4; ++j) {
          accA[i][j] += kt[i].x * ks[j].x + kt[i].y * ks[j].y + kt[i].z * ks[j].z + kt[i].w * ks[j].w;
          accQ[i][j] += qt[i].x * ks[j].x + qt[i].y * ks[j].y + qt[i].z * ks[j].z + qt[i].w * ks[j].w;
        }
    }
    float* qo = qkd + (size_t)task * 4096;
#pragma unroll
    for (int i = 0; i < 4; ++i)
#pragma unroll
      for (int j = 0; j < 4; ++j) {
        const int t = r4g + i, s = sl + 16 * j;
        const float dec = (s <= t) ? __expf(lb[t] - lb[s]) : 0.f;
        Gs[t][s] = (t > s) ? lbeta[t] * accA[i][j] * dec : 0.f;
        qo[t * 64 + s] = accQ[i][j] * dec;
      }
  }
  // KdT and γ out
  {
    const int dk = tid >> 2, s0 = (tid & 3) * 16;
    const float bC = lb[63];
    float* dst = kdt + (size_t)task * 4096 + dk * 64 + s0;
#pragma unroll
    for (int j = 0; j < 16; ++j)
      dst[j] = lk[s0 + j][dk] * __expf(bC - lb[s0 + j]);
  }
  if (tid < 64) gam[(size_t)task * 64 + tid] = lgam[tid];
  __syncthreads();
  // Td (threads 0..63: 4 blocks x 16 columns, registers only) + RHS0 load
  if (tid < 64) {
    const int blk = tid >> 4, cI = tid & 15;
    float Xc[16];
#pragma unroll
    for (int t = 0; t < 16; ++t) Xc[t] = (t == cI) ? 1.f : 0.f;
#pragma unroll
    for (int t = 1; t < 16; ++t) {
      float acc = 0.f;
#pragma unroll
      for (int s = 0; s < t; ++s)
        acc += Gs[blk * 16 + t][blk * 16 + s] * Xc[s];
      Xc[t] -= acc;
    }
#pragma unroll
    for (int t = 0; t < 16; ++t) Td[blk][t][cI] = Xc[t];
  } else {
    // RHS half 0: βV columns 0..95 (192 threads, 32 cells each)
    for (int idx = tid - 64; idx < 64 * 96; idx += 192) {
      const int t = idx / 96, c = idx % 96;
      Xs[t][c] = lbeta[t] * v[(((size_t)b * T_ + t0 + t) * H_ + h) * DV_ + c];
    }
  }
  __syncthreads();
  const int rt = tid & 15;          // row within block
  const int cg = tid >> 4;          // column group: cols cg*6 .. cg*6+5
#pragma unroll 1
  for (int half = 0; half < 2; ++half) {
    // 4-stage blocked sweep
#pragma unroll
    for (int bi = 0; bi < 4; ++bi) {
      if (bi > 0) {
        float acc[6] = {0.f, 0.f, 0.f, 0.f, 0.f, 0.f};
        for (int kk = 0; kk < 16 * bi; ++kk) {
          const float gvv = Gs[16 * bi + rt][kk];
#pragma unroll
          for (int c = 0; c < 6; ++c) acc[c] += gvv * Xs[kk][cg * 6 + c];
        }
#pragma unroll
        for (int c = 0; c < 6; ++c) Xs[16 * bi + rt][cg * 6 + c] -= acc[c];
      }
      __syncthreads();
      float y[6] = {0.f, 0.f, 0.f, 0.f, 0.f, 0.f};
#pragma unroll
      for (int s = 0; s < 16; ++s) {
        const float tv = Td[bi][rt][s];
#pragma unroll
        for (int c = 0; c < 6; ++c) y[c] += tv * Xs[16 * bi + s][cg * 6 + c];
      }
      __syncthreads();
#pragma unroll
      for (int c = 0; c < 6; ++c) Xs[16 * bi + rt][cg * 6 + c] = y[c];
      __syncthreads();
    }
    // writeback + next RHS
    if (half == 0) {
      for (int idx = tid; idx < 64 * 96; idx += 256) {
        const int t = idx / 96, c = idx % 96;
        v[(((size_t)b * T_ + t0 + t) * H_ + h) * DV_ + c] = Xs[t][c];
      }
      __syncthreads();
      // RHS half 1: cols 0..31 = βV cols 96..127; cols 32..95 = βγ·K cols 0..63
      for (int idx = tid; idx < 64 * 96; idx += 256) {
        const int t = idx / 96, c = idx % 96;
        if (c < 32)
          Xs[t][c] = lbeta[t] * v[(((size_t)b * T_ + t0 + t) * H_ + h) * DV_ + 96 + c];
        else
          Xs[t][c] = lbg[t] * lk[t][c - 32];
      }
      __syncthreads();
    } else {
      for (int idx = tid; idx < 64 * 96; idx += 256) {
        const int t = idx / 96, c = idx % 96;
        if (c < 32)
          v[(((size_t)b * T_ + t0 + t) * H_ + h) * DV_ + 96 + c] = Xs[t][c];
        else
          k[(((size_t)b * T_ + t0 + t) * H_ + h) * DK_ + c - 32] = Xs[t][c];
      }
    }
  }
}

// ---------------------------------------------------------------------------
// Serial recurrence only (unchanged from round 6).
__global__ __launch_bounds__(64) void chunk_rec_k(
    const float* __restrict__ W, float* __restrict__ u,
    const float* __restrict__ kdt, const float* __restrict__ gam,
    float* __restrict__ Sst) {
  const int bh = blockIdx.x >> 3, cg = blockIdx.x & 7;
  const int b = bh >> 4, h = bh & 15;
  const int c0 = cg * 16;
  const int lane = threadIdx.x;
  const int r4 = (lane & 15) * 4;
  const int cl = (lane >> 4) * 4;
  __shared__ float Wt[64][68];
  __shared__ float Kt[64][68];
  __shared__ float Ss[64][20];
  __shared__ float Ub[64][20];
  float Sr[4][4];
#pragma unroll
  for (int i = 0; i < 4; ++i)
#pragma unroll
    for (int j = 0; j < 4; ++j) Sr[i][j] = 0.f;
  for (int i = lane; i < 64 * 20; i += 64) (&Ss[0][0])[i] = 0.f;
  for (int n = 0; n < NCH; ++n) {
    const int task = bh * NCH + n;
    const int t0 = n * C_;
#pragma unroll
    for (int i = 0; i < 4; ++i)
      *(float4*)(Sst + (size_t)task * 8192 + (r4 + i) * 128 + c0 + cl) =
          make_float4(Sr[i][0], Sr[i][1], Sr[i][2], Sr[i][3]);
    {
      const float* src = W + (((size_t)b * T_ + t0 + lane) * H_ + h) * DK_;
#pragma unroll
      for (int d4 = 0; d4 < 16; ++d4) {
        const float4 wv = ((const float4*)src)[d4];
        Wt[4 * d4 + 0][lane] = wv.x; Wt[4 * d4 + 1][lane] = wv.y;
        Wt[4 * d4 + 2][lane] = wv.z; Wt[4 * d4 + 3][lane] = wv.w;
      }
    }
    {
      const float* src = kdt + (size_t)task * 4096 + lane * 64;
#pragma unroll
      for (int s4 = 0; s4 < 16; ++s4) {
        const float4 kv = ((const float4*)src)[s4];
        Kt[4 * s4 + 0][lane] = kv.x; Kt[4 * s4 + 1][lane] = kv.y;
        Kt[4 * s4 + 2][lane] = kv.z; Kt[4 * s4 + 3][lane] = kv.w;
      }
    }
    float acc[4][4];
#pragma unroll
    for (int i = 0; i < 4; ++i) {
      const float4 uv = *(const float4*)(u + (((size_t)b * T_ + t0 + r4 + i) * H_ + h) * DV_ + c0 + cl);
      acc[i][0] = uv.x; acc[i][1] = uv.y; acc[i][2] = uv.z; acc[i][3] = uv.w;
    }
    for (int kb = 0; kb < 64; kb += 4) {
#pragma unroll
      for (int j = 0; j < 4; ++j) {
        const float4 a = *(const float4*)&Wt[kb + j][r4];
        const float4 bb = *(const float4*)&Ss[kb + j][cl];
        const float av[4] = {a.x, a.y, a.z, a.w};
        const float bv[4] = {bb.x, bb.y, bb.z, bb.w};
#pragma unroll
        for (int i = 0; i < 4; ++i)
#pragma unroll
          for (int c = 0; c < 4; ++c) acc[i][c] -= av[i] * bv[c];
      }
    }
#pragma unroll
    for (int i = 0; i < 4; ++i) {
      *(float4*)&Ub[r4 + i][cl] = make_float4(acc[i][0], acc[i][1], acc[i][2], acc[i][3]);
      *(float4*)(u + (((size_t)b * T_ + t0 + r4 + i) * H_ + h) * DV_ + c0 + cl) =
          make_float4(acc[i][0], acc[i][1], acc[i][2], acc[i][3]);
    }
    float acc2[4][4] = {};
    for (int sb = 0; sb < 64; sb += 4) {
#pragma unroll
      for (int j = 0; j < 4; ++j) {
        const float4 a = *(const float4*)&Kt[sb + j][r4];
        const float4 bb = *(const float4*)&Ub[sb + j][cl];
        const float av[4] = {a.x, a.y, a.z, a.w};
        const float bv[4] = {bb.x, bb.y, bb.z, bb.w};
#pragma unroll
        for (int i = 0; i < 4; ++i)
#pragma unroll
          for (int c = 0; c < 4; ++c) acc2[i][c] += av[i] * bv[c];
      }
    }
    const float gC = gam[(size_t)task * 64 + 63];
#pragma unroll
    for (int i = 0; i < 4; ++i)
#pragma unroll
      for (int c = 0; c < 4; ++c) Sr[i][c] = gC * Sr[i][c] + acc2[i][c];
#pragma unroll
    for (int i = 0; i < 4; ++i)
      *(float4*)&Ss[r4 + i][cl] = make_float4(Sr[i][0], Sr[i][1], Sr[i][2], Sr[i][3]);
  }
}

// ---------------------------------------------------------------------------
// Parallel O with fused gatenorm (unchanged from round 6).
__global__ __launch_bounds__(128) void chunk_o_k(
    const float* __restrict__ q, const float* __restrict__ qkd,
    const float* __restrict__ ub, const float* __restrict__ Sst,
    const float* __restrict__ gam, const float* __restrict__ gate,
    const float* __restrict__ onw, __hip_bfloat16* __restrict__ go) {
  const int task = blockIdx.x;
  const int bh = task >> 4, n = task & 15;
  const int b = bh >> 4, h = bh & 15;
  const int t0 = n * C_;
  const int tid = threadIdx.x;
  const int rowg = tid >> 4, colg = tid & 15;
  const int r8 = rowg * 8, c4 = colg * 4;
  __shared__ float At[64][68];
  __shared__ float Bs[64][132];
  __shared__ float lgam[64];
  if (tid < 64) lgam[tid] = gam[(size_t)task * 64 + tid];
  __syncthreads();
  const int t2 = tid >> 1, dh = (tid & 1) * 32;
  {
    const float* src = q + (((size_t)b * T_ + t0 + t2) * H_ + h) * DK_ + dh;
    const float sc = lgam[t2];
#pragma unroll
    for (int i = 0; i < 8; ++i) {
      const float4 v = ((const float4*)src)[i];
      At[dh + 4 * i + 0][t2] = v.x * sc; At[dh + 4 * i + 1][t2] = v.y * sc;
      At[dh + 4 * i + 2][t2] = v.z * sc; At[dh + 4 * i + 3][t2] = v.w * sc;
    }
  }
  {
    const float* src = Sst + (size_t)task * 8192 + t2 * 128 + (tid & 1) * 64;
    float* dst = &Bs[t2][(tid & 1) * 64];
#pragma unroll
    for (int i = 0; i < 16; ++i) ((float4*)dst)[i] = ((const float4*)src)[i];
  }
  __syncthreads();
  float acc[8][8];
#pragma unroll
  for (int i = 0; i < 8; ++i)
#pragma unroll
    for (int c = 0; c < 8; ++c) acc[i][c] = 0.f;
#pragma unroll 1
  for (int ph = 0; ph < 2; ++ph) {
    for (int kb = 0; kb < 64; kb += 4) {
#pragma unroll
      for (int j = 0; j < 4; ++j) {
        const float4 alo = *(const float4*)&At[kb + j][r8];
        const float4 ahi = *(const float4*)&At[kb + j][r8 + 4];
        const float4 blo = *(const float4*)&Bs[kb + j][c4];
        const float4 bhi = *(const float4*)&Bs[kb + j][c4 + 64];
        const float av[8] = {alo.x, alo.y, alo.z, alo.w, ahi.x, ahi.y, ahi.z, ahi.w};
        const float bv[8] = {blo.x, blo.y, blo.z, blo.w, bhi.x, bhi.y, bhi.z, bhi.w};
#pragma unroll
        for (int i = 0; i < 8; ++i)
#pragma unroll
          for (int c = 0; c < 8; ++c) acc[i][c] += av[i] * bv[c];
      }
    }
    if (ph == 0) {
      __syncthreads();
      {
        const float* src = qkd + (size_t)task * 4096 + t2 * 64 + dh;
#pragma unroll
        for (int i = 0; i < 8; ++i) {
          const float4 v = ((const float4*)src)[i];
          At[dh + 4 * i + 0][t2] = v.x; At[dh + 4 * i + 1][t2] = v.y;
          At[dh + 4 * i + 2][t2] = v.z; At[dh + 4 * i + 3][t2] = v.w;
        }
      }
      {
        const float* src = ub + (((size_t)b * T_ + t0 + t2) * H_ + h) * DV_ + (tid & 1) * 64;
        float* dst = &Bs[t2][(tid & 1) * 64];
#pragma unroll
        for (int i = 0; i < 16; ++i) ((float4*)dst)[i] = ((const float4*)src)[i];
      }
      __syncthreads();
    }
  }
#pragma unroll
  for (int i = 0; i < 8; ++i) {
    float pr = 0.f;
#pragma unroll
    for (int c = 0; c < 8; ++c) pr += acc[i][c] * acc[i][c];
    pr += __shfl_xor(pr, 1, 64);
    pr += __shfl_xor(pr, 2, 64);
    pr += __shfl_xor(pr, 4, 64);
    pr += __shfl_xor(pr, 8, 64);
    const float rms = rsqrtf(pr / (float)DV_ + 1e-5f);
    const size_t rb = (((size_t)b * T_ + t0 + r8 + i) * H_ + h) * DV_;
    const float4 glo = *(const float4*)(gate + rb + c4);
    const float4 ghi = *(const float4*)(gate + rb + c4 + 64);
    const float gv[8] = {glo.x, glo.y, glo.z, glo.w, ghi.x, ghi.y, ghi.z, ghi.w};
    unsigned short outv[8];
#pragma unroll
    for (int c = 0; c < 8; ++c) {
      const int col = (c < 4) ? c4 + c : c4 + 60 + c;
      const float gg = gv[c];
      const float val = acc[i][c] * rms * onw[col] * gg * (1.f / (1.f + __expf(-gg)));
      const __hip_bfloat16 bfv = __float2bfloat16(val);
      outv[c] = *(const unsigned short*)&bfv;
    }
    *(ushort4*)((unsigned short*)go + rb + c4) =
        make_ushort4(outv[0], outv[1], outv[2], outv[3]);
    *(ushort4*)((unsigned short*)go + rb + c4 + 64) =
        make_ushort4(outv[4], outv[5], outv[6], outv[7]);
  }
}

// ---------------------------------------------------------------------------
extern "C" void kernel_launch(void* const* d_in, const int* in_sizes, int n_in,
                              void* d_out, int out_size, void* d_ws, size_t ws_size,
                              hipStream_t stream) {
  const float* x    = (const float*)d_in[0];
  const float* n1w  = (const float*)d_in[1];
  const float* n2w  = (const float*)d_in[2];
  const float* Wq   = (const float*)d_in[3];
  const float* Wk   = (const float*)d_in[4];
  const float* Wv   = (const float*)d_in[5];
  const float* cq   = (const float*)d_in[6];
  const float* ck   = (const float*)d_in[7];
  const float* cv   = (const float*)d_in[8];
  const float* Wa   = (const float*)d_in[9];
  const float* Wb   = (const float*)d_in[10];
  const float* dtb  = (const float*)d_in[11];
  const float* Alog = (const float*)d_in[12];
  const float* Wg   = (const float*)d_in[13];
  const float* onw  = (const float*)d_in[14];
  const float* Wo   = (const float*)d_in[15];
  const float* W1   = (const float*)d_in[16];
  const float* W3   = (const float*)d_in[17];
  const float* W2   = (const float*)d_in[18];
  float* out = (float*)d_out;
  float* ws  = (float*)d_ws;

  const size_t SZ_MD = (size_t)M_ * D_;          // 2M floats
  const size_t SZ_MV = (size_t)M_ * H_ * DV_;    // 4M floats
  float* h    = ws;                               // [0,2M)
  float* pq   = ws + SZ_MD;                       // [2M,4M)  -> QKd -> y1
  float* pk   = ws + 2 * SZ_MD;                   // [4M,6M)  -> KdT
  float* pv   = ws + 3 * SZ_MD;                   // [6M,10M) -> S_store -> a1
  float* gate = ws + 3 * SZ_MD + SZ_MV;           // [10M,14M)
  float* qb   = ws + 3 * SZ_MD + 2 * SZ_MV;       // [14M,16M)
  float* kb   = ws + 4 * SZ_MD + 2 * SZ_MV;       // [16M,18M) in-place W
  float* vb   = ws + 5 * SZ_MD + 2 * SZ_MV;       // [18M,22M) in-place u -> Û
  float* Sst  = pv;
  float* y1   = pq;
  float* a1   = pv;
  float* smalls = ws + 5 * SZ_MD + 3 * SZ_MV;     // 22M
  float* pa  = smalls;
  float* pb  = pa + (size_t)M_ * H_;
  float* gv  = pb + (size_t)M_ * H_;
  float* bv  = gv + (size_t)M_ * H_;
  float* gam = bv + (size_t)M_ * H_;
  __hip_bfloat16* h_bf  = (__hip_bfloat16*)vb;
  __hip_bfloat16* wb1   = (__hip_bfloat16*)kb;
  __hip_bfloat16* wb2   = (__hip_bfloat16*)vb;
  __hip_bfloat16* go_bf = (__hip_bfloat16*)h;
  __hip_bfloat16* h2_bf = (__hip_bfloat16*)h;
  __hip_bfloat16* a1b   = (__hip_bfloat16*)qb;

  const dim3 blk256(256);
  const dim3 g_tr1024_1024(1024 / 32, 1024 / 32);
  const dim3 g_tr1024_2048(2048 / 32, 1024 / 32);
  const dim3 g_tr2048_1024(1024 / 32, 2048 / 32);
  const dim3 g_tr1024_2816(2816 / 32, 1024 / 32);
  const dim3 g_tr2816_1024(1024 / 32, 2816 / 32);

  rmsnorm_k<<<dim3(M_), blk256, 0, stream>>>(x, n1w, h, h_bf, D_, 1e-6f);
  transpose_bf16_k<<<g_tr1024_1024, blk256, 0, stream>>>(Wq, wb1, D_, 1024);
  mfma_gemm_k<64><<<dim3(1024 / 64, M_ / 128), blk256, 0, stream>>>(h_bf, wb1, nullptr, pq, M_, 1024, D_, 0);
  transpose_bf16_k<<<g_tr1024_1024, blk256, 0, stream>>>(Wk, wb1, D_, 1024);
  mfma_gemm_k<64><<<dim3(1024 / 64, M_ / 128), blk256, 0, stream>>>(h_bf, wb1, nullptr, pk, M_, 1024, D_, 0);
  transpose_bf16_k<<<g_tr1024_2048, blk256, 0, stream>>>(Wv, wb1, D_, 2048);
  mfma_gemm_k<128><<<dim3(2048 / 128, M_ / 128), blk256, 0, stream>>>(h_bf, wb1, nullptr, pv, M_, 2048, D_, 0);
  transpose_bf16_k<<<g_tr1024_2048, blk256, 0, stream>>>(Wg, wb1, D_, 2048);
  mfma_gemm_k<128><<<dim3(2048 / 128, M_ / 128), blk256, 0, stream>>>(h_bf, wb1, nullptr, gate, M_, 2048, D_, 0);
  skinny_k<<<dim3(M_), blk256, 0, stream>>>(h, Wa, Wb, pa, pb, D_);
  conv_silu_k<<<dim3(M_), blk256, 0, stream>>>(pq, cq, qb, H_ * DK_);
  conv_silu_k<<<dim3(M_), blk256, 0, stream>>>(pk, ck, kb, H_ * DK_);
  conv_silu_k<<<dim3(M_), blk256, 0, stream>>>(pv, cv, vb, H_ * DV_);
  beta_g_k<<<dim3((M_ * H_ + 255) / 256), blk256, 0, stream>>>(pa, pb, dtb, Alog, gv, bv, M_ * H_);
  l2norm_k<<<dim3(M_ * H_), dim3(64), 0, stream>>>(qb, 0.125f);
  l2norm_k<<<dim3(M_ * H_), dim3(64), 0, stream>>>(kb, 1.0f);
  chunk_prep_k<<<dim3(32 * NCH), blk256, 0, stream>>>(qb, kb, vb, gv, bv, pq, pk, gam);
  chunk_rec_k<<<dim3(32 * 8), dim3(64), 0, stream>>>(kb, vb, pk, gam, Sst);
  chunk_o_k<<<dim3(32 * NCH), dim3(128), 0, stream>>>(qb, pq, vb, Sst, gam, gate, onw, go_bf);
  transpose_bf16_k<<<g_tr2048_1024, blk256, 0, stream>>>(Wo, wb2, H_ * DV_, 1024);
  mfma_gemm_k<64><<<dim3(1024 / 64, M_ / 128), blk256, 0, stream>>>(go_bf, wb2, x, y1, M_, 1024, H_ * DV_, 1);
  rmsnorm_k<<<dim3(M_), blk256, 0, stream>>>(y1, n2w, nullptr, h2_bf, D_, 1e-6f);
  transpose_bf16_k<<<g_tr1024_2816, blk256, 0, stream>>>(W1, wb2, D_, FH_);
  mfma_gemm_k<128><<<dim3(FH_ / 128, M_ / 128), blk256, 0, stream>>>(h2_bf, wb2, nullptr, a1, M_, FH_, D_, 0);
  transpose_bf16_k<<<g_tr1024_2816, blk256, 0, stream>>>(W3, wb2, D_, FH_);
  mfma_gemm_k<128><<<dim3(FH_ / 128, M_ / 128), blk256, 0, stream>>>(h2_bf, wb2, a1, a1b, M_, FH_, D_, 2);
  transpose_bf16_k<<<g_tr2816_1024, blk256, 0, stream>>>(W2, wb2, FH_, 1024);
  mfma_gemm_k<64><<<dim3(1024 / 64, M_ / 128), blk256, 0, stream>>>(a1b, wb2, y1, out, M_, 1024, FH_, 1);
}